// Round 3
// baseline (1385.522 us; speedup 1.0000x reference)
//
#include <hip/hip_runtime.h>
#include <hip/hip_bf16.h>
#include <stdint.h>

// ScaleGNN on MI355X (gfx950).
// fp32 inputs / fp32 output (established rounds 0-2: bf16 read of x => NaN;
// bf16 write of out => exact stub error). edge_index int32/int64 auto-detect.
// Random mask reproduces JAX threefry2x32 key(42) bit-exactly.

#define N_NODES 4096
#define C_DIM   128
#define WPR     128        // bitmask words per row (4096/32)
#define HALF_P  8388608u   // N*N/2
#define TOPK    10

__device__ __forceinline__ uint32_t rotl32(uint32_t v, int r) {
    return (v << r) | (v >> (32 - r));
}

__device__ __forceinline__ void threefry2x32(uint32_t k0, uint32_t k1,
                                             uint32_t x0, uint32_t x1,
                                             uint32_t& o0, uint32_t& o1) {
    uint32_t ks2 = k0 ^ k1 ^ 0x1BD11BDAu;
    x0 += k0; x1 += k1;
#define TF_ROUND(r) { x0 += x1; x1 = rotl32(x1, (r)); x1 ^= x0; }
    TF_ROUND(13) TF_ROUND(15) TF_ROUND(26) TF_ROUND(6)
    x0 += k1;  x1 += ks2 + 1u;
    TF_ROUND(17) TF_ROUND(29) TF_ROUND(16) TF_ROUND(24)
    x0 += ks2; x1 += k0 + 2u;
    TF_ROUND(13) TF_ROUND(15) TF_ROUND(26) TF_ROUND(6)
    x0 += k0;  x1 += k1 + 3u;
    TF_ROUND(17) TF_ROUND(29) TF_ROUND(16) TF_ROUND(24)
    x0 += k1;  x1 += ks2 + 4u;
    TF_ROUND(13) TF_ROUND(15) TF_ROUND(26) TF_ROUND(6)
    x0 += ks2; x1 += k0 + 5u;
#undef TF_ROUND
    o0 = x0; o1 = x1;
}

// ---- edge_index dtype detection: flags[0]=1 iff int64 ---------------------
__global__ void detect_kernel(const uint32_t* __restrict__ ew,
                              uint32_t* __restrict__ flags) {
    __shared__ int cnt_oddnz;
    int t = threadIdx.x;   // 256 threads
    if (t == 0) cnt_oddnz = 0;
    __syncthreads();
    if (ew[2 * t + 1] != 0u) atomicAdd(&cnt_oddnz, 1);
    __syncthreads();
    if (t == 0) flags[0] = (cnt_oddnz > 8) ? 0u : 1u;  // int64 => high words 0
}

// ---- scatter edges into adjacency bitmask (dedup via OR) ------------------
__global__ void scatter_kernel(const int* __restrict__ ei, int E,
                               uint32_t* __restrict__ Abits,
                               const uint32_t* __restrict__ flags) {
    int e = blockIdx.x * blockDim.x + threadIdx.x;
    if (e >= E) return;
    int src, dst;
    if (flags[0]) {            // int64 little-endian: value in low word
        src = ei[2 * e];
        dst = ei[2 * (E + e)];
    } else {
        src = ei[e];
        dst = ei[E + e];
    }
    src &= (N_NODES - 1);      // memory safety; values are in [0,4096)
    dst &= (N_NODES - 1);
    atomicOr(&Abits[src * WPR + (dst >> 5)], 1u << (dst & 31));
}

// ---- SpMM: out[i,:] = sum_{j in bits(i)} in[j,:] --------------------------
__global__ void spmm_kernel(const uint32_t* __restrict__ Abits,
                            const float* __restrict__ in,
                            float* __restrict__ out) {
    int i = blockIdx.x;
    int c = threadIdx.x;                 // 128 threads = channels
    __shared__ uint32_t wbits[WPR];
    wbits[c] = Abits[i * WPR + c];
    __syncthreads();
    float acc = 0.f;
    for (int w = 0; w < WPR; ++w) {
        uint32_t bits = wbits[w];
        while (bits) {
            int b = __ffs(bits) - 1;
            bits &= bits - 1;
            int j = w * 32 + b;
            acc += in[j * C_DIM + c];
        }
    }
    out[i * C_DIM + c] = acc;
}

// ---- agg = a0*x + a1*hop1 + a2*hop2 ---------------------------------------
__global__ void agg_kernel(const float* __restrict__ xf,
                           const float* __restrict__ hop1,
                           const float* __restrict__ hop2,
                           const float* __restrict__ alpha,
                           float* __restrict__ agg, int n) {
    int i = blockIdx.x * blockDim.x + threadIdx.x;
    if (i >= n) return;
    agg[i] = alpha[0] * xf[i] + alpha[1] * hop1[i] + alpha[2] * hop2[i];
}

// ---- row-normalize: xn = x / (||x|| + 1e-8) -------------------------------
__global__ void norm_kernel(const float* __restrict__ xf,
                            float* __restrict__ xn) {
    int i = blockIdx.x;
    int c = threadIdx.x;                 // 128 threads = 2 waves
    float v = xf[i * C_DIM + c];
    float sq = v * v;
    #pragma unroll
    for (int off = 32; off >= 1; off >>= 1) sq += __shfl_xor(sq, off);
    __shared__ float ws[2];
    if ((c & 63) == 0) ws[c >> 6] = sq;
    __syncthreads();
    float tot = ws[0] + ws[1];
    xn[i * C_DIM + c] = v / (sqrtf(tot) + 1e-8f);
}

// ---- threefry random keep-mask: bit p set iff uniform[p] < 0.5 ------------
__global__ void mask_kernel(uint32_t* __restrict__ Mbits) {
    uint32_t tid = blockIdx.x * blockDim.x + threadIdx.x;  // < 262144
    uint32_t base = tid * 32u;
    uint32_t w0 = 0u, w1 = 0u;
    for (int k = 0; k < 32; ++k) {
        uint32_t o0, o1;
        threefry2x32(0u, 42u, base + k, HALF_P + base + k, o0, o1);
        w0 |= (uint32_t)((o0 >> 31) ^ 1u) << k;   // u<0.5 <=> top bit 0
        w1 |= (uint32_t)((o1 >> 31) ^ 1u) << k;
    }
    Mbits[tid] = w0;
    Mbits[(HALF_P >> 5) + tid] = w1;
}

// ---- fused sim + top-10, OR indices into mask -----------------------------
__launch_bounds__(256)
__global__ void topk_kernel(const float* __restrict__ xn,
                            uint32_t* __restrict__ Mbits) {
    int i = blockIdx.x;
    int t = threadIdx.x;                 // 256 threads
    __shared__ float4 lx4[32];
    __shared__ float sval[256 * TOPK];
    __shared__ int   sidx[256 * TOPK];
    if (t < 128) ((float*)lx4)[t] = xn[i * C_DIM + t];
    __syncthreads();

    float tv[TOPK]; int ti[TOPK];
    #pragma unroll
    for (int k = 0; k < TOPK; ++k) { tv[k] = -1e30f; ti[k] = 0x7fffffff; }

    for (int j = t; j < N_NODES; j += 256) {
        const float4* xr = (const float4*)(xn + (size_t)j * C_DIM);
        float d = 0.f;
        #pragma unroll 8
        for (int q = 0; q < 32; ++q) {
            float4 a = lx4[q]; float4 b = xr[q];
            d = fmaf(a.x, b.x, d); d = fmaf(a.y, b.y, d);
            d = fmaf(a.z, b.z, d); d = fmaf(a.w, b.w, d);
        }
        // insert (d, j); tie-break: lower index wins (lax.top_k semantics)
        if (d > tv[TOPK-1] || (d == tv[TOPK-1] && j < ti[TOPK-1])) {
            tv[TOPK-1] = d; ti[TOPK-1] = j;
            #pragma unroll
            for (int k = TOPK - 2; k >= 0; --k) {
                bool sw = (tv[k+1] > tv[k]) || (tv[k+1] == tv[k] && ti[k+1] < ti[k]);
                if (sw) {
                    float fv = tv[k]; tv[k] = tv[k+1]; tv[k+1] = fv;
                    int iv = ti[k];  ti[k] = ti[k+1];  ti[k+1] = iv;
                }
            }
        }
    }
    #pragma unroll
    for (int k = 0; k < TOPK; ++k) { sval[t*TOPK+k] = tv[k]; sidx[t*TOPK+k] = ti[k]; }
    __syncthreads();

    // tree-merge 256 sorted top-10 lists
    for (int s = 128; s >= 1; s >>= 1) {
        if (t < s) {
            int a = t, b = t + s;
            float ov[TOPK]; int oi[TOPK];
            int ia = 0, ib = 0;
            #pragma unroll
            for (int k = 0; k < TOPK; ++k) {
                bool takeA;
                if (ib >= TOPK) takeA = true;
                else if (ia >= TOPK) takeA = false;
                else {
                    float va = sval[a*TOPK+ia], vb = sval[b*TOPK+ib];
                    int   xa = sidx[a*TOPK+ia], xb = sidx[b*TOPK+ib];
                    takeA = (va > vb) || (va == vb && xa < xb);
                }
                if (takeA) { ov[k] = sval[a*TOPK+ia]; oi[k] = sidx[a*TOPK+ia]; ++ia; }
                else       { ov[k] = sval[b*TOPK+ib]; oi[k] = sidx[b*TOPK+ib]; ++ib; }
            }
            #pragma unroll
            for (int k = 0; k < TOPK; ++k) { sval[t*TOPK+k] = ov[k]; sidx[t*TOPK+k] = oi[k]; }
        }
        __syncthreads();
    }
    if (t == 0) {
        #pragma unroll
        for (int k = 0; k < TOPK; ++k) {
            int j = sidx[k];
            atomicOr(&Mbits[i * WPR + (j >> 5)], 1u << (j & 31));
        }
    }
}

// ---- masked mean: fused[i,:] = (sum_{j in mask(i)} agg[j,:]) / (cnt+1e-6) -
__global__ void fused_kernel(const uint32_t* __restrict__ Mbits,
                             const float* __restrict__ agg,
                             float* __restrict__ fused) {
    int i = blockIdx.x;
    int c = threadIdx.x;                 // 128
    __shared__ uint32_t wbits[WPR];
    __shared__ int pcnt;
    wbits[c] = Mbits[i * WPR + c];
    if (c == 0) pcnt = 0;
    __syncthreads();
    atomicAdd(&pcnt, __popc(wbits[c]));
    __syncthreads();
    float acc = 0.f;
    for (int w = 0; w < WPR; ++w) {
        uint32_t bits = wbits[w];
        while (bits) {
            int b = __ffs(bits) - 1;
            bits &= bits - 1;
            int j = w * 32 + b;
            acc += agg[j * C_DIM + c];
        }
    }
    fused[i * C_DIM + c] = acc / ((float)pcnt + 1e-6f);
}

// ---- h = [x, fused] @ fusion_W + fusion_b ---------------------------------
__global__ void fusion_gemm(const float* __restrict__ xf,
                            const float* __restrict__ fused,
                            const float* __restrict__ W,
                            const float* __restrict__ b,
                            float* __restrict__ h) {
    int i = blockIdx.x;
    int o = threadIdx.x;                 // 128
    __shared__ float lx[256];
    lx[o]       = xf[i * C_DIM + o];
    lx[128 + o] = fused[i * C_DIM + o];
    __syncthreads();
    float acc = b[o];
    for (int k = 0; k < 256; ++k)
        acc = fmaf(lx[k], W[k * 128 + o], acc);
    h[i * 128 + o] = acc;
}

// ---- h1 = relu(h @ lin0_W + lin0_b) ---------------------------------------
__global__ void lin0_gemm(const float* __restrict__ h,
                          const float* __restrict__ W,
                          const float* __restrict__ b,
                          float* __restrict__ h1) {
    int i = blockIdx.x;
    int o = threadIdx.x;                 // 128
    __shared__ float lx[128];
    lx[o] = h[i * 128 + o];
    __syncthreads();
    float acc = b[o];
    for (int k = 0; k < 128; ++k)
        acc = fmaf(lx[k], W[k * 128 + o], acc);
    h1[i * 128 + o] = fmaxf(acc, 0.f);
}

// ---- out = log_softmax(h1 @ lin1_W + lin1_b); fp32 out; 64 thr = 1 wave ---
__global__ void lin1_lsm(const float* __restrict__ h1,
                         const float* __restrict__ W,
                         const float* __restrict__ b,
                         float* __restrict__ out) {
    int i = blockIdx.x;
    int o = threadIdx.x;                 // 64 threads = 1 wave
    __shared__ float lx[128];
    lx[o]      = h1[i * 128 + o];
    lx[64 + o] = h1[i * 128 + 64 + o];
    __syncthreads();
    float acc = b[o];
    for (int k = 0; k < 128; ++k)
        acc = fmaf(lx[k], W[k * 64 + o], acc);
    float m = acc;
    #pragma unroll
    for (int off = 32; off >= 1; off >>= 1) m = fmaxf(m, __shfl_xor(m, off));
    float e = expf(acc - m);
    float s = e;
    #pragma unroll
    for (int off = 32; off >= 1; off >>= 1) s += __shfl_xor(s, off);
    out[i * 64 + o] = acc - m - logf(s);
}

extern "C" void kernel_launch(void* const* d_in, const int* in_sizes, int n_in,
                              void* d_out, int out_size, void* d_ws, size_t ws_size,
                              hipStream_t stream) {
    const float* xf    = (const float*)d_in[0];
    const int*   ei    = (const int*)d_in[1];
    const float* alpha = (const float*)d_in[2];
    const float* fW    = (const float*)d_in[3];
    const float* fB    = (const float*)d_in[4];
    const float* l0W   = (const float*)d_in[5];
    const float* l0B   = (const float*)d_in[6];
    const float* l1W   = (const float*)d_in[7];
    const float* l1B   = (const float*)d_in[8];
    float* out = (float*)d_out;
    const int E  = in_sizes[1] / 2;     // 65536
    const int NC = N_NODES * C_DIM;     // 524288

    // workspace carve
    char* p = (char*)d_ws;
    uint32_t* flags = (uint32_t*)p; p += 256;
    const size_t SZ = (size_t)NC * 4;   // 2 MB
    uint32_t* Abits = (uint32_t*)p; p += SZ;
    float*    hop1  = (float*)p;    p += SZ;
    float*    hop2  = (float*)p;    p += SZ;
    float*    agg   = (float*)p;    p += SZ;
    float*    xn    = (float*)p;    p += SZ;
    uint32_t* Mbits = (uint32_t*)p; p += SZ;
    float*    fusd  = (float*)p;    p += SZ;
    float*    h     = (float*)p;    p += SZ;
    float*    h1    = (float*)p;    p += SZ;

    hipMemsetAsync(Abits, 0, SZ, stream);
    detect_kernel<<<1, 256, 0, stream>>>((const uint32_t*)ei, flags);
    scatter_kernel<<<(E + 255) / 256, 256, 0, stream>>>(ei, E, Abits, flags);
    spmm_kernel<<<N_NODES, 128, 0, stream>>>(Abits, xf, hop1);
    spmm_kernel<<<N_NODES, 128, 0, stream>>>(Abits, hop1, hop2);
    agg_kernel<<<(NC + 255) / 256, 256, 0, stream>>>(xf, hop1, hop2, alpha, agg, NC);
    norm_kernel<<<N_NODES, 128, 0, stream>>>(xf, xn);
    mask_kernel<<<(HALF_P >> 5) / 256, 256, 0, stream>>>(Mbits);
    topk_kernel<<<N_NODES, 256, 0, stream>>>(xn, Mbits);
    fused_kernel<<<N_NODES, 128, 0, stream>>>(Mbits, agg, fusd);
    fusion_gemm<<<N_NODES, 128, 0, stream>>>(xf, fusd, fW, fB, h);
    lin0_gemm<<<N_NODES, 128, 0, stream>>>(h, l0W, l0B, h1);
    lin1_lsm<<<N_NODES, 64, 0, stream>>>(h1, l1W, l1B, out);
}

// Round 4
// 752.772 us; speedup vs baseline: 1.8406x; 1.8406x over previous
//
#include <hip/hip_runtime.h>
#include <hip/hip_bf16.h>
#include <stdint.h>

// ScaleGNN on MI355X (gfx950). fp32 in / fp32 out. edge_index int32/int64
// auto-detect. Random mask reproduces JAX threefry2x32 key(42) bit-exactly.
// R3: topk + fused rewritten with 16-row i-tiling (16x less L2 traffic,
//     ILP-4 dot products, padded LDS strides).

#define N_NODES 4096
#define C_DIM   128
#define WPR     128        // bitmask words per row (4096/32)
#define HALF_P  8388608u   // N*N/2
#define TOPK    10
#define IT      16         // i-rows per block (topk & fused)

__device__ __forceinline__ uint32_t rotl32(uint32_t v, int r) {
    return (v << r) | (v >> (32 - r));
}

__device__ __forceinline__ void threefry2x32(uint32_t k0, uint32_t k1,
                                             uint32_t x0, uint32_t x1,
                                             uint32_t& o0, uint32_t& o1) {
    uint32_t ks2 = k0 ^ k1 ^ 0x1BD11BDAu;
    x0 += k0; x1 += k1;
#define TF_ROUND(r) { x0 += x1; x1 = rotl32(x1, (r)); x1 ^= x0; }
    TF_ROUND(13) TF_ROUND(15) TF_ROUND(26) TF_ROUND(6)
    x0 += k1;  x1 += ks2 + 1u;
    TF_ROUND(17) TF_ROUND(29) TF_ROUND(16) TF_ROUND(24)
    x0 += ks2; x1 += k0 + 2u;
    TF_ROUND(13) TF_ROUND(15) TF_ROUND(26) TF_ROUND(6)
    x0 += k0;  x1 += k1 + 3u;
    TF_ROUND(17) TF_ROUND(29) TF_ROUND(16) TF_ROUND(24)
    x0 += k1;  x1 += ks2 + 4u;
    TF_ROUND(13) TF_ROUND(15) TF_ROUND(26) TF_ROUND(6)
    x0 += ks2; x1 += k0 + 5u;
#undef TF_ROUND
    o0 = x0; o1 = x1;
}

// ---- edge_index dtype detection: flags[0]=1 iff int64 ---------------------
__global__ void detect_kernel(const uint32_t* __restrict__ ew,
                              uint32_t* __restrict__ flags) {
    __shared__ int cnt_oddnz;
    int t = threadIdx.x;   // 256 threads
    if (t == 0) cnt_oddnz = 0;
    __syncthreads();
    if (ew[2 * t + 1] != 0u) atomicAdd(&cnt_oddnz, 1);
    __syncthreads();
    if (t == 0) flags[0] = (cnt_oddnz > 8) ? 0u : 1u;  // int64 => high words 0
}

// ---- scatter edges into adjacency bitmask (dedup via OR) ------------------
__global__ void scatter_kernel(const int* __restrict__ ei, int E,
                               uint32_t* __restrict__ Abits,
                               const uint32_t* __restrict__ flags) {
    int e = blockIdx.x * blockDim.x + threadIdx.x;
    if (e >= E) return;
    int src, dst;
    if (flags[0]) {            // int64 little-endian: value in low word
        src = ei[2 * e];
        dst = ei[2 * (E + e)];
    } else {
        src = ei[e];
        dst = ei[E + e];
    }
    src &= (N_NODES - 1);
    dst &= (N_NODES - 1);
    atomicOr(&Abits[src * WPR + (dst >> 5)], 1u << (dst & 31));
}

// ---- SpMM: out[i,:] = sum_{j in bits(i)} in[j,:]; avg degree ~16 ----------
__global__ void spmm_kernel(const uint32_t* __restrict__ Abits,
                            const float* __restrict__ in,
                            float* __restrict__ out) {
    int i = blockIdx.x;
    int c = threadIdx.x;                 // 128 threads = channels
    __shared__ uint32_t wbits[WPR];
    wbits[c] = Abits[i * WPR + c];
    __syncthreads();
    float acc = 0.f;
    for (int w = 0; w < WPR; ++w) {
        uint32_t bits = wbits[w];
        while (bits) {
            int b = __ffs(bits) - 1;
            bits &= bits - 1;
            int j = w * 32 + b;
            acc += in[j * C_DIM + c];
        }
    }
    out[i * C_DIM + c] = acc;
}

// ---- agg = a0*x + a1*hop1 + a2*hop2 ---------------------------------------
__global__ void agg_kernel(const float* __restrict__ xf,
                           const float* __restrict__ hop1,
                           const float* __restrict__ hop2,
                           const float* __restrict__ alpha,
                           float* __restrict__ agg, int n) {
    int i = blockIdx.x * blockDim.x + threadIdx.x;
    if (i >= n) return;
    agg[i] = alpha[0] * xf[i] + alpha[1] * hop1[i] + alpha[2] * hop2[i];
}

// ---- row-normalize: xn = x / (||x|| + 1e-8) -------------------------------
__global__ void norm_kernel(const float* __restrict__ xf,
                            float* __restrict__ xn) {
    int i = blockIdx.x;
    int c = threadIdx.x;                 // 128 threads = 2 waves
    float v = xf[i * C_DIM + c];
    float sq = v * v;
    #pragma unroll
    for (int off = 32; off >= 1; off >>= 1) sq += __shfl_xor(sq, off);
    __shared__ float ws[2];
    if ((c & 63) == 0) ws[c >> 6] = sq;
    __syncthreads();
    float tot = ws[0] + ws[1];
    xn[i * C_DIM + c] = v / (sqrtf(tot) + 1e-8f);
}

// ---- threefry random keep-mask: bit p set iff uniform[p] < 0.5 ------------
__global__ void mask_kernel(uint32_t* __restrict__ Mbits) {
    uint32_t tid = blockIdx.x * blockDim.x + threadIdx.x;  // < 262144
    uint32_t base = tid * 32u;
    uint32_t w0 = 0u, w1 = 0u;
    for (int k = 0; k < 32; ++k) {
        uint32_t o0, o1;
        threefry2x32(0u, 42u, base + k, HALF_P + base + k, o0, o1);
        w0 |= (uint32_t)((o0 >> 31) ^ 1u) << k;   // u<0.5 <=> top bit 0
        w1 |= (uint32_t)((o1 >> 31) ^ 1u) << k;
    }
    Mbits[tid] = w0;
    Mbits[(HALF_P >> 5) + tid] = w1;
}

// ---- fused sim + top-10 (16 i-rows per block, 512 threads) ----------------
// thread t: il = t&15 (which i-row), jl = t>>4 (0..31, j-stripe)
__launch_bounds__(512)
__global__ void topk_kernel(const float* __restrict__ xn,
                            uint32_t* __restrict__ Mbits) {
    int i0 = blockIdx.x * IT;
    int t  = threadIdx.x;
    int il = t & 15;
    int jl = t >> 4;                      // 0..31
    __shared__ float lx[IT][132];         // padded stride: bank spread
    __shared__ float sval[IT * 32 * TOPK];
    __shared__ int   sidx[IT * 32 * TOPK];
    for (int r = t; r < IT * C_DIM; r += 512) {
        lx[r >> 7][r & 127] = xn[(size_t)(i0 + (r >> 7)) * C_DIM + (r & 127)];
    }
    __syncthreads();

    float tv[TOPK]; int ti[TOPK];
    #pragma unroll
    for (int k = 0; k < TOPK; ++k) { tv[k] = -1e30f; ti[k] = 0x7fffffff; }

    const float* lrow = lx[il];
    for (int j = jl; j < N_NODES; j += 32) {
        const float4* xr = (const float4*)(xn + (size_t)j * C_DIM);
        float d0 = 0.f, d1 = 0.f, d2 = 0.f, d3 = 0.f;
        #pragma unroll 8
        for (int q = 0; q < 32; ++q) {
            float4 b = xr[q];
            float4 a = *(const float4*)&lrow[4 * q];
            d0 = fmaf(a.x, b.x, d0); d1 = fmaf(a.y, b.y, d1);
            d2 = fmaf(a.z, b.z, d2); d3 = fmaf(a.w, b.w, d3);
        }
        float d = (d0 + d1) + (d2 + d3);
        // ascending-j scan; tie-break lower index (lax.top_k semantics)
        if (d > tv[TOPK-1]) {
            tv[TOPK-1] = d; ti[TOPK-1] = j;
            #pragma unroll
            for (int k = TOPK - 2; k >= 0; --k) {
                bool sw = (tv[k+1] > tv[k]);
                if (sw) {
                    float fv = tv[k]; tv[k] = tv[k+1]; tv[k+1] = fv;
                    int iv = ti[k];  ti[k] = ti[k+1];  ti[k+1] = iv;
                }
            }
        }
    }
    int base = (il * 32 + jl) * TOPK;
    #pragma unroll
    for (int k = 0; k < TOPK; ++k) { sval[base+k] = tv[k]; sidx[base+k] = ti[k]; }

    // tree-merge 32 sorted lists per i-row
    for (int s = 16; s >= 1; s >>= 1) {
        __syncthreads();
        if (jl < s) {
            int la = (il * 32 + jl) * TOPK;
            int lb = (il * 32 + jl + s) * TOPK;
            float ov[TOPK]; int oi[TOPK];
            int ia = 0, ib = 0;
            #pragma unroll
            for (int k = 0; k < TOPK; ++k) {
                float va = sval[la+ia], vb = sval[lb+ib];
                int   xa = sidx[la+ia], xb = sidx[lb+ib];
                bool takeA = (va > vb) || (va == vb && xa < xb);
                if (takeA) { ov[k] = va; oi[k] = xa; ++ia; }
                else       { ov[k] = vb; oi[k] = xb; ++ib; }
            }
            #pragma unroll
            for (int k = 0; k < TOPK; ++k) { sval[la+k] = ov[k]; sidx[la+k] = oi[k]; }
        }
    }
    __syncthreads();
    if (jl == 0) {
        int i = i0 + il;
        #pragma unroll
        for (int k = 0; k < TOPK; ++k) {
            int j = sidx[il * 32 * TOPK + k];
            Mbits[i * WPR + (j >> 5)] |= 1u << (j & 31);   // one thread per row
        }
    }
}

// ---- masked mean, 16 i-rows per block, agg streamed through LDS -----------
// thread t: il = t&15, sl = t>>4 (0..31; 4 channels each)
__launch_bounds__(512)
__global__ void fused_kernel(const uint32_t* __restrict__ Mbits,
                             const float* __restrict__ agg,
                             float* __restrict__ fused) {
    int i0 = blockIdx.x * IT;
    int t  = threadIdx.x;
    int il = t & 15;
    int sl = t >> 4;                      // 0..31
    __shared__ float sagg[64][132];       // 64-j tile, padded stride
    float4 acc = make_float4(0.f, 0.f, 0.f, 0.f);
    int cnt = 0;
    const int row = (i0 + il) * WPR;
    for (int tile = 0; tile < 64; ++tile) {
        // stage 64 j-rows (tile*64 .. tile*64+63)
        for (int r = t; r < 64 * 32; r += 512) {
            int jr = r >> 5, q = r & 31;
            *(float4*)&sagg[jr][4 * q] =
                *(const float4*)&agg[(size_t)(tile * 64 + jr) * C_DIM + 4 * q];
        }
        __syncthreads();
        #pragma unroll
        for (int w = 0; w < 2; ++w) {
            uint32_t bits = Mbits[row + tile * 2 + w];
            cnt += __popc(bits);
            while (bits) {
                int b = __ffs(bits) - 1;
                bits &= bits - 1;
                const float4 v = *(const float4*)&sagg[w * 32 + b][4 * sl];
                acc.x += v.x; acc.y += v.y; acc.z += v.z; acc.w += v.w;
            }
        }
        __syncthreads();
    }
    float inv = 1.f / ((float)cnt + 1e-6f);
    float4 r = make_float4(acc.x * inv, acc.y * inv, acc.z * inv, acc.w * inv);
    *(float4*)&fused[(size_t)(i0 + il) * C_DIM + 4 * sl] = r;
}

// ---- h = [x, fused] @ fusion_W + fusion_b ---------------------------------
__global__ void fusion_gemm(const float* __restrict__ xf,
                            const float* __restrict__ fused,
                            const float* __restrict__ W,
                            const float* __restrict__ b,
                            float* __restrict__ h) {
    int i = blockIdx.x;
    int o = threadIdx.x;                 // 128
    __shared__ float lx[256];
    lx[o]       = xf[i * C_DIM + o];
    lx[128 + o] = fused[i * C_DIM + o];
    __syncthreads();
    float acc = b[o];
    for (int k = 0; k < 256; ++k)
        acc = fmaf(lx[k], W[k * 128 + o], acc);
    h[i * 128 + o] = acc;
}

// ---- h1 = relu(h @ lin0_W + lin0_b) ---------------------------------------
__global__ void lin0_gemm(const float* __restrict__ h,
                          const float* __restrict__ W,
                          const float* __restrict__ b,
                          float* __restrict__ h1) {
    int i = blockIdx.x;
    int o = threadIdx.x;                 // 128
    __shared__ float lx[128];
    lx[o] = h[i * 128 + o];
    __syncthreads();
    float acc = b[o];
    for (int k = 0; k < 128; ++k)
        acc = fmaf(lx[k], W[k * 128 + o], acc);
    h1[i * 128 + o] = fmaxf(acc, 0.f);
}

// ---- out = log_softmax(h1 @ lin1_W + lin1_b); fp32 out; 64 thr = 1 wave ---
__global__ void lin1_lsm(const float* __restrict__ h1,
                         const float* __restrict__ W,
                         const float* __restrict__ b,
                         float* __restrict__ out) {
    int i = blockIdx.x;
    int o = threadIdx.x;                 // 64 threads = 1 wave
    __shared__ float lx[128];
    lx[o]      = h1[i * 128 + o];
    lx[64 + o] = h1[i * 128 + 64 + o];
    __syncthreads();
    float acc = b[o];
    for (int k = 0; k < 128; ++k)
        acc = fmaf(lx[k], W[k * 64 + o], acc);
    float m = acc;
    #pragma unroll
    for (int off = 32; off >= 1; off >>= 1) m = fmaxf(m, __shfl_xor(m, off));
    float e = expf(acc - m);
    float s = e;
    #pragma unroll
    for (int off = 32; off >= 1; off >>= 1) s += __shfl_xor(s, off);
    out[i * 64 + o] = acc - m - logf(s);
}

extern "C" void kernel_launch(void* const* d_in, const int* in_sizes, int n_in,
                              void* d_out, int out_size, void* d_ws, size_t ws_size,
                              hipStream_t stream) {
    const float* xf    = (const float*)d_in[0];
    const int*   ei    = (const int*)d_in[1];
    const float* alpha = (const float*)d_in[2];
    const float* fW    = (const float*)d_in[3];
    const float* fB    = (const float*)d_in[4];
    const float* l0W   = (const float*)d_in[5];
    const float* l0B   = (const float*)d_in[6];
    const float* l1W   = (const float*)d_in[7];
    const float* l1B   = (const float*)d_in[8];
    float* out = (float*)d_out;
    const int E  = in_sizes[1] / 2;     // 65536
    const int NC = N_NODES * C_DIM;     // 524288

    // workspace carve
    char* p = (char*)d_ws;
    uint32_t* flags = (uint32_t*)p; p += 256;
    const size_t SZ = (size_t)NC * 4;   // 2 MB
    uint32_t* Abits = (uint32_t*)p; p += SZ;
    float*    hop1  = (float*)p;    p += SZ;
    float*    hop2  = (float*)p;    p += SZ;
    float*    agg   = (float*)p;    p += SZ;
    float*    xn    = (float*)p;    p += SZ;
    uint32_t* Mbits = (uint32_t*)p; p += SZ;
    float*    fusd  = (float*)p;    p += SZ;
    float*    h     = (float*)p;    p += SZ;
    float*    h1    = (float*)p;    p += SZ;

    hipMemsetAsync(Abits, 0, SZ, stream);
    detect_kernel<<<1, 256, 0, stream>>>((const uint32_t*)ei, flags);
    scatter_kernel<<<(E + 255) / 256, 256, 0, stream>>>(ei, E, Abits, flags);
    spmm_kernel<<<N_NODES, 128, 0, stream>>>(Abits, xf, hop1);
    spmm_kernel<<<N_NODES, 128, 0, stream>>>(Abits, hop1, hop2);
    agg_kernel<<<(NC + 255) / 256, 256, 0, stream>>>(xf, hop1, hop2, alpha, agg, NC);
    norm_kernel<<<N_NODES, 128, 0, stream>>>(xf, xn);
    mask_kernel<<<(HALF_P >> 5) / 256, 256, 0, stream>>>(Mbits);
    topk_kernel<<<N_NODES / IT, 512, 0, stream>>>(xn, Mbits);
    fused_kernel<<<N_NODES / IT, 512, 0, stream>>>(Mbits, agg, fusd);
    fusion_gemm<<<N_NODES, 128, 0, stream>>>(xf, fusd, fW, fB, h);
    lin0_gemm<<<N_NODES, 128, 0, stream>>>(h, l0W, l0B, h1);
    lin1_lsm<<<N_NODES, 64, 0, stream>>>(h1, l1W, l1B, out);
}

// Round 5
// 379.076 us; speedup vs baseline: 3.6550x; 1.9858x over previous
//
#include <hip/hip_runtime.h>
#include <hip/hip_bf16.h>
#include <stdint.h>

// ScaleGNN on MI355X (gfx950). fp32 in / fp32 out. edge_index int32/int64
// auto-detect. Random mask reproduces JAX threefry2x32 key(42) bit-exactly.
// R5: topk & fused as outer-product register-tiled GEMMs (8i-rows/block,
//     coalesced b-streams, wave-uniform a-operands); agg folded into spmm2;
//     8-row GEMM epilogue kernels.

#define N_NODES 4096
#define C_DIM   128
#define WPR     128        // bitmask words per row (4096/32)
#define HALF_P  8388608u   // N*N/2
#define TOPK    10

__device__ __forceinline__ uint32_t rotl32(uint32_t v, int r) {
    return (v << r) | (v >> (32 - r));
}

__device__ __forceinline__ void threefry2x32(uint32_t k0, uint32_t k1,
                                             uint32_t x0, uint32_t x1,
                                             uint32_t& o0, uint32_t& o1) {
    uint32_t ks2 = k0 ^ k1 ^ 0x1BD11BDAu;
    x0 += k0; x1 += k1;
#define TF_ROUND(r) { x0 += x1; x1 = rotl32(x1, (r)); x1 ^= x0; }
    TF_ROUND(13) TF_ROUND(15) TF_ROUND(26) TF_ROUND(6)
    x0 += k1;  x1 += ks2 + 1u;
    TF_ROUND(17) TF_ROUND(29) TF_ROUND(16) TF_ROUND(24)
    x0 += ks2; x1 += k0 + 2u;
    TF_ROUND(13) TF_ROUND(15) TF_ROUND(26) TF_ROUND(6)
    x0 += k0;  x1 += k1 + 3u;
    TF_ROUND(17) TF_ROUND(29) TF_ROUND(16) TF_ROUND(24)
    x0 += k1;  x1 += ks2 + 4u;
    TF_ROUND(13) TF_ROUND(15) TF_ROUND(26) TF_ROUND(6)
    x0 += ks2; x1 += k0 + 5u;
#undef TF_ROUND
    o0 = x0; o1 = x1;
}

// ---- edge_index dtype detection: flags[0]=1 iff int64 ---------------------
__global__ void detect_kernel(const uint32_t* __restrict__ ew,
                              uint32_t* __restrict__ flags) {
    __shared__ int cnt_oddnz;
    int t = threadIdx.x;
    if (t == 0) cnt_oddnz = 0;
    __syncthreads();
    if (ew[2 * t + 1] != 0u) atomicAdd(&cnt_oddnz, 1);
    __syncthreads();
    if (t == 0) flags[0] = (cnt_oddnz > 8) ? 0u : 1u;
}

// ---- scatter edges into adjacency bitmask (dedup via OR) ------------------
__global__ void scatter_kernel(const int* __restrict__ ei, int E,
                               uint32_t* __restrict__ Abits,
                               const uint32_t* __restrict__ flags) {
    int e = blockIdx.x * blockDim.x + threadIdx.x;
    if (e >= E) return;
    int src, dst;
    if (flags[0]) { src = ei[2 * e]; dst = ei[2 * (E + e)]; }
    else          { src = ei[e];     dst = ei[E + e]; }
    src &= (N_NODES - 1);
    dst &= (N_NODES - 1);
    atomicOr(&Abits[src * WPR + (dst >> 5)], 1u << (dst & 31));
}

// ---- SpMM: hop1[i,:] = sum_{j in bits(i)} x[j,:] --------------------------
__global__ void spmm_kernel(const uint32_t* __restrict__ Abits,
                            const float* __restrict__ in,
                            float* __restrict__ out) {
    int i = blockIdx.x;
    int c = threadIdx.x;                 // 128
    __shared__ uint32_t wbits[WPR];
    wbits[c] = Abits[i * WPR + c];
    __syncthreads();
    float acc = 0.f;
    for (int w = 0; w < WPR; ++w) {
        uint32_t bits = wbits[w];
        while (bits) {
            int b = __ffs(bits) - 1;
            bits &= bits - 1;
            acc += in[(w * 32 + b) * C_DIM + c];
        }
    }
    out[i * C_DIM + c] = acc;
}

// ---- SpMM2 + agg: agg = a0*x + a1*hop1 + a2*(A@hop1) ----------------------
__global__ void spmm2_agg_kernel(const uint32_t* __restrict__ Abits,
                                 const float* __restrict__ hop1,
                                 const float* __restrict__ xf,
                                 const float* __restrict__ alpha,
                                 float* __restrict__ agg) {
    int i = blockIdx.x;
    int c = threadIdx.x;                 // 128
    __shared__ uint32_t wbits[WPR];
    wbits[c] = Abits[i * WPR + c];
    __syncthreads();
    float acc = 0.f;
    for (int w = 0; w < WPR; ++w) {
        uint32_t bits = wbits[w];
        while (bits) {
            int b = __ffs(bits) - 1;
            bits &= bits - 1;
            acc += hop1[(w * 32 + b) * C_DIM + c];
        }
    }
    agg[i * C_DIM + c] = alpha[0] * xf[i * C_DIM + c]
                       + alpha[1] * hop1[i * C_DIM + c]
                       + alpha[2] * acc;
}

// ---- row-normalize: xn = x / (||x|| + 1e-8) -------------------------------
__global__ void norm_kernel(const float* __restrict__ xf,
                            float* __restrict__ xn) {
    int i = blockIdx.x;
    int c = threadIdx.x;                 // 128
    float v = xf[i * C_DIM + c];
    float sq = v * v;
    #pragma unroll
    for (int off = 32; off >= 1; off >>= 1) sq += __shfl_xor(sq, off);
    __shared__ float ws[2];
    if ((c & 63) == 0) ws[c >> 6] = sq;
    __syncthreads();
    float tot = ws[0] + ws[1];
    xn[i * C_DIM + c] = v / (sqrtf(tot) + 1e-8f);
}

// ---- transpose xn [4096][128] -> xnT [128][4096] --------------------------
__global__ void transpose_kernel(const float* __restrict__ xn,
                                 float* __restrict__ xnT) {
    __shared__ float tile[32][33];
    int bi = blockIdx.x;                 // 0..127 (i tiles)
    int bc = blockIdx.y;                 // 0..3   (c tiles)
    int tx = threadIdx.x & 31, ty = threadIdx.x >> 5;   // 256 thr, ty 0..7
    #pragma unroll
    for (int r = 0; r < 32; r += 8)
        tile[ty + r][tx] = xn[(size_t)(bi * 32 + ty + r) * C_DIM + bc * 32 + tx];
    __syncthreads();
    #pragma unroll
    for (int r = 0; r < 32; r += 8)
        xnT[(size_t)(bc * 32 + ty + r) * N_NODES + bi * 32 + tx] = tile[tx][ty + r];
}

// ---- threefry random keep-mask: bit p set iff uniform[p] < 0.5 ------------
__global__ void mask_kernel(uint32_t* __restrict__ Mbits) {
    uint32_t tid = blockIdx.x * blockDim.x + threadIdx.x;  // < 262144
    uint32_t base = tid * 32u;
    uint32_t w0 = 0u, w1 = 0u;
    for (int k = 0; k < 32; ++k) {
        uint32_t o0, o1;
        threefry2x32(0u, 42u, base + k, HALF_P + base + k, o0, o1);
        w0 |= (uint32_t)((o0 >> 31) ^ 1u) << k;
        w1 |= (uint32_t)((o1 >> 31) ^ 1u) << k;
    }
    Mbits[tid] = w0;
    Mbits[(HALF_P >> 5) + tid] = w1;
}

// ---- topk: sim = xn @ xnT as outer-product GEMM, fused top-10 -------------
// block = 8 i-rows, 512 thr (8 waves). Wave w handles j-windows w and w+8
// (256 j each). Lane: acc[8 il][4 j]. Sim tile -> per-wave LDS -> per-lane
// top-10 (lane owns one il) -> tree merge of 64 lists per il.
__launch_bounds__(512, 4)
__global__ void topk_kernel(const float* __restrict__ xn,
                            const float* __restrict__ xnT,
                            uint32_t* __restrict__ Mbits) {
    int i0 = blockIdx.x * 8;
    int t  = threadIdx.x;
    int w  = t >> 6;                     // wave 0..7
    int jl = t & 63;                     // lane
    int il_s = jl >> 3;                  // il this lane scans
    int sub  = jl & 7;

    __shared__ float smem[8 * 8 * 260];  // per-wave S tiles; merge aliases
    float* S    = &smem[w * 8 * 260];
    float* sval = smem;                  // [8 il][64 L][10]
    int*   sidx = (int*)&smem[8 * 64 * TOPK];

    float tv[TOPK]; int ti[TOPK];
    #pragma unroll
    for (int k = 0; k < TOPK; ++k) { tv[k] = -1e30f; ti[k] = 0x7fffffff; }

    for (int pass = 0; pass < 2; ++pass) {
        int win = w + 8 * pass;
        int j0  = win * 256;
        float acc[8][4];
        #pragma unroll
        for (int il = 0; il < 8; ++il)
            { acc[il][0] = 0.f; acc[il][1] = 0.f; acc[il][2] = 0.f; acc[il][3] = 0.f; }

        for (int c4 = 0; c4 < 32; ++c4) {
            const float* bp = xnT + (size_t)(c4 * 4) * N_NODES + j0 + 4 * jl;
            float4 b0 = *(const float4*)(bp);
            float4 b1 = *(const float4*)(bp + N_NODES);
            float4 b2 = *(const float4*)(bp + 2 * N_NODES);
            float4 b3 = *(const float4*)(bp + 3 * N_NODES);
            #pragma unroll
            for (int il = 0; il < 8; ++il) {
                float4 a = *(const float4*)&xn[(size_t)(i0 + il) * C_DIM + c4 * 4];
                acc[il][0] = fmaf(a.x, b0.x, acc[il][0]);
                acc[il][0] = fmaf(a.y, b1.x, acc[il][0]);
                acc[il][0] = fmaf(a.z, b2.x, acc[il][0]);
                acc[il][0] = fmaf(a.w, b3.x, acc[il][0]);
                acc[il][1] = fmaf(a.x, b0.y, acc[il][1]);
                acc[il][1] = fmaf(a.y, b1.y, acc[il][1]);
                acc[il][1] = fmaf(a.z, b2.y, acc[il][1]);
                acc[il][1] = fmaf(a.w, b3.y, acc[il][1]);
                acc[il][2] = fmaf(a.x, b0.z, acc[il][2]);
                acc[il][2] = fmaf(a.y, b1.z, acc[il][2]);
                acc[il][2] = fmaf(a.z, b2.z, acc[il][2]);
                acc[il][2] = fmaf(a.w, b3.z, acc[il][2]);
                acc[il][3] = fmaf(a.x, b0.w, acc[il][3]);
                acc[il][3] = fmaf(a.y, b1.w, acc[il][3]);
                acc[il][3] = fmaf(a.z, b2.w, acc[il][3]);
                acc[il][3] = fmaf(a.w, b3.w, acc[il][3]);
            }
        }
        #pragma unroll
        for (int il = 0; il < 8; ++il)
            *(float4*)&S[il * 260 + 4 * jl] =
                make_float4(acc[il][0], acc[il][1], acc[il][2], acc[il][3]);
        __syncthreads();
        // scan own il: j_local = sub + 8k (ascending), 2-way-max bank spread
        for (int k = 0; k < 32; ++k) {
            int jloc = sub + 8 * k;
            float d = S[il_s * 260 + jloc];
            if (d > tv[TOPK-1]) {
                int j = j0 + jloc;
                tv[TOPK-1] = d; ti[TOPK-1] = j;
                #pragma unroll
                for (int q = TOPK - 2; q >= 0; --q) {
                    if (tv[q+1] > tv[q]) {
                        float fv = tv[q]; tv[q] = tv[q+1]; tv[q+1] = fv;
                        int iv = ti[q];  ti[q] = ti[q+1];  ti[q+1] = iv;
                    }
                }
            }
        }
        __syncthreads();
    }

    // store lists: list id L = w*8 + sub for row il_s
    int base = (il_s * 64 + w * 8 + sub) * TOPK;
    #pragma unroll
    for (int k = 0; k < TOPK; ++k) { sval[base + k] = tv[k]; sidx[base + k] = ti[k]; }

    // tree-merge 64 sorted lists per il; thread = (il = t&7, L = t>>3)
    int il = t & 7, L = t >> 3;
    for (int s = 32; s >= 1; s >>= 1) {
        __syncthreads();
        if (L < s) {
            int la = (il * 64 + L) * TOPK;
            int lb = (il * 64 + L + s) * TOPK;
            float ov[TOPK]; int oi[TOPK];
            int ia = 0, ib = 0;
            #pragma unroll
            for (int k = 0; k < TOPK; ++k) {
                float va = sval[la + ia], vb = sval[lb + ib];
                int   xa = sidx[la + ia], xb = sidx[lb + ib];
                bool takeA = (va > vb) || (va == vb && xa < xb);
                if (takeA) { ov[k] = va; oi[k] = xa; ++ia; }
                else       { ov[k] = vb; oi[k] = xb; ++ib; }
            }
            #pragma unroll
            for (int k = 0; k < TOPK; ++k) { sval[la + k] = ov[k]; sidx[la + k] = oi[k]; }
        }
    }
    __syncthreads();
    if (t < 8) {
        int i = i0 + t;
        #pragma unroll
        for (int k = 0; k < TOPK; ++k) {
            int j = sidx[(t * 64) * TOPK + k];
            Mbits[i * WPR + (j >> 5)] |= 1u << (j & 31);  // row-exclusive
        }
    }
}

// ---- masked mean as dense masked GEMM: fused = (Mf @ agg) / deg -----------
// block = 8 i-rows, 512 thr. Wave w covers j in [w*512, w*512+512).
// Lane owns c-pair (2*lane, 2*lane+1); acc[8 il] float2. Mask word uniform.
__launch_bounds__(512, 4)
__global__ void fused_kernel(const uint32_t* __restrict__ Mbits,
                             const float* __restrict__ agg,
                             float* __restrict__ fused) {
    int i0 = blockIdx.x * 8;
    int t  = threadIdx.x;
    int w  = t >> 6;
    int lane = t & 63;
    __shared__ float buf[8][8][128];     // [wave][il][c] partials (32 KB)
    __shared__ int   cw[8][8];           // [wave][il] popcounts

    float2 acc[8];
    #pragma unroll
    for (int il = 0; il < 8; ++il) acc[il] = make_float2(0.f, 0.f);
    int cnt[8];
    #pragma unroll
    for (int il = 0; il < 8; ++il) cnt[il] = 0;

    int wbase = w * 16;                  // first word index of this wave's j-range
    for (int seg = 0; seg < 16; ++seg) {
        uint32_t wd[8];
        #pragma unroll
        for (int il = 0; il < 8; ++il) {
            wd[il] = Mbits[(i0 + il) * WPR + wbase + seg];
            cnt[il] += __popc(wd[il]);
        }
        int jseg = (wbase + seg) * 32;
        for (int jj = 0; jj < 32; ++jj) {
            float2 b = *(const float2*)&agg[(size_t)(jseg + jj) * C_DIM + 2 * lane];
            #pragma unroll
            for (int il = 0; il < 8; ++il) {
                float a = ((wd[il] >> jj) & 1u) ? 1.f : 0.f;   // uniform SALU select
                acc[il].x = fmaf(a, b.x, acc[il].x);
                acc[il].y = fmaf(a, b.y, acc[il].y);
            }
        }
    }
    #pragma unroll
    for (int il = 0; il < 8; ++il)
        *(float2*)&buf[w][il][2 * lane] = acc[il];
    if (lane == 0) {
        #pragma unroll
        for (int il = 0; il < 8; ++il) cw[w][il] = cnt[il];
    }
    __syncthreads();
    // reduce 8 wave-partials; 1024 out elems, 2 per thread
    for (int e = t; e < 8 * C_DIM; e += 512) {
        int il = e >> 7, c = e & 127;
        float f = 0.f; int deg = 0;
        #pragma unroll
        for (int ww = 0; ww < 8; ++ww) { f += buf[ww][il][c]; deg += cw[ww][il]; }
        fused[(size_t)(i0 + il) * C_DIM + c] = f / ((float)deg + 1e-6f);
    }
}

// ---- h = [x, fused] @ fusion_W + fusion_b (8 rows/block) ------------------
__global__ void fusion_gemm(const float* __restrict__ xf,
                            const float* __restrict__ fused,
                            const float* __restrict__ W,
                            const float* __restrict__ b,
                            float* __restrict__ h) {
    int i0 = blockIdx.x * 8;
    int o = threadIdx.x;                 // 128
    __shared__ float lx[8][256];
    for (int r = o; r < 8 * 128; r += 128) {
        lx[r >> 7][r & 127]       = xf[(size_t)(i0 + (r >> 7)) * C_DIM + (r & 127)];
        lx[r >> 7][128 + (r & 127)] = fused[(size_t)(i0 + (r >> 7)) * C_DIM + (r & 127)];
    }
    __syncthreads();
    float acc[8];
    #pragma unroll
    for (int r = 0; r < 8; ++r) acc[r] = b[o];
    for (int k = 0; k < 256; ++k) {
        float wv = W[k * 128 + o];
        #pragma unroll
        for (int r = 0; r < 8; ++r) acc[r] = fmaf(lx[r][k], wv, acc[r]);
    }
    #pragma unroll
    for (int r = 0; r < 8; ++r) h[(size_t)(i0 + r) * 128 + o] = acc[r];
}

// ---- h1 = relu(h @ lin0_W + lin0_b) (8 rows/block) ------------------------
__global__ void lin0_gemm(const float* __restrict__ h,
                          const float* __restrict__ W,
                          const float* __restrict__ b,
                          float* __restrict__ h1) {
    int i0 = blockIdx.x * 8;
    int o = threadIdx.x;                 // 128
    __shared__ float lx[8][128];
    for (int r = o; r < 8 * 128; r += 128)
        lx[r >> 7][r & 127] = h[(size_t)(i0 + (r >> 7)) * 128 + (r & 127)];
    __syncthreads();
    float acc[8];
    #pragma unroll
    for (int r = 0; r < 8; ++r) acc[r] = b[o];
    for (int k = 0; k < 128; ++k) {
        float wv = W[k * 128 + o];
        #pragma unroll
        for (int r = 0; r < 8; ++r) acc[r] = fmaf(lx[r][k], wv, acc[r]);
    }
    #pragma unroll
    for (int r = 0; r < 8; ++r)
        h1[(size_t)(i0 + r) * 128 + o] = fmaxf(acc[r], 0.f);
}

// ---- out = log_softmax(h1 @ lin1_W + lin1_b) (8 rows/block, 1 wave) -------
__global__ void lin1_lsm(const float* __restrict__ h1,
                         const float* __restrict__ W,
                         const float* __restrict__ b,
                         float* __restrict__ out) {
    int i0 = blockIdx.x * 8;
    int o = threadIdx.x;                 // 64
    __shared__ float lx[8][128];
    for (int r = o; r < 8 * 128; r += 64)
        lx[r >> 7][r & 127] = h1[(size_t)(i0 + (r >> 7)) * 128 + (r & 127)];
    __syncthreads();
    float acc[8];
    #pragma unroll
    for (int r = 0; r < 8; ++r) acc[r] = b[o];
    for (int k = 0; k < 128; ++k) {
        float wv = W[k * 64 + o];
        #pragma unroll
        for (int r = 0; r < 8; ++r) acc[r] = fmaf(lx[r][k], wv, acc[r]);
    }
    #pragma unroll
    for (int r = 0; r < 8; ++r) {
        float m = acc[r];
        #pragma unroll
        for (int off = 32; off >= 1; off >>= 1) m = fmaxf(m, __shfl_xor(m, off));
        float e = expf(acc[r] - m);
        float s = e;
        #pragma unroll
        for (int off = 32; off >= 1; off >>= 1) s += __shfl_xor(s, off);
        out[(size_t)(i0 + r) * 64 + o] = acc[r] - m - logf(s);
    }
}

extern "C" void kernel_launch(void* const* d_in, const int* in_sizes, int n_in,
                              void* d_out, int out_size, void* d_ws, size_t ws_size,
                              hipStream_t stream) {
    const float* xf    = (const float*)d_in[0];
    const int*   ei    = (const int*)d_in[1];
    const float* alpha = (const float*)d_in[2];
    const float* fW    = (const float*)d_in[3];
    const float* fB    = (const float*)d_in[4];
    const float* l0W   = (const float*)d_in[5];
    const float* l0B   = (const float*)d_in[6];
    const float* l1W   = (const float*)d_in[7];
    const float* l1B   = (const float*)d_in[8];
    float* out = (float*)d_out;
    const int E  = in_sizes[1] / 2;     // 65536
    const int NC = N_NODES * C_DIM;     // 524288

    char* p = (char*)d_ws;
    uint32_t* flags = (uint32_t*)p; p += 256;
    const size_t SZ = (size_t)NC * 4;   // 2 MB
    uint32_t* Abits = (uint32_t*)p; p += SZ;
    float*    hop1  = (float*)p;    p += SZ;
    float*    agg   = (float*)p;    p += SZ;
    float*    xn    = (float*)p;    p += SZ;
    float*    xnT   = (float*)p;    p += SZ;
    uint32_t* Mbits = (uint32_t*)p; p += SZ;
    float*    fusd  = (float*)p;    p += SZ;
    float*    h     = (float*)p;    p += SZ;
    float*    h1    = (float*)p;    p += SZ;

    hipMemsetAsync(Abits, 0, SZ, stream);
    detect_kernel<<<1, 256, 0, stream>>>((const uint32_t*)ei, flags);
    scatter_kernel<<<(E + 255) / 256, 256, 0, stream>>>(ei, E, Abits, flags);
    spmm_kernel<<<N_NODES, 128, 0, stream>>>(Abits, xf, hop1);
    spmm2_agg_kernel<<<N_NODES, 128, 0, stream>>>(Abits, hop1, xf, alpha, agg);
    norm_kernel<<<N_NODES, 128, 0, stream>>>(xf, xn);
    transpose_kernel<<<dim3(128, 4), 256, 0, stream>>>(xn, xnT);
    mask_kernel<<<(HALF_P >> 5) / 256, 256, 0, stream>>>(Mbits);
    topk_kernel<<<N_NODES / 8, 512, 0, stream>>>(xn, xnT, Mbits);
    fused_kernel<<<N_NODES / 8, 512, 0, stream>>>(Mbits, agg, fusd);
    fusion_gemm<<<N_NODES / 8, 128, 0, stream>>>(xf, fusd, fW, fB, h);
    lin0_gemm<<<N_NODES / 8, 128, 0, stream>>>(h, l0W, l0B, h1);
    lin1_lsm<<<N_NODES / 8, 64, 0, stream>>>(h1, l1W, l1B, out);
}

// Round 6
// 352.683 us; speedup vs baseline: 3.9285x; 1.0748x over previous
//
#include <hip/hip_runtime.h>
#include <hip/hip_bf16.h>
#include <stdint.h>

// ScaleGNN on MI355X (gfx950). fp32 in / fp32 out. edge_index int32/int64
// auto-detect. Random mask reproduces JAX threefry2x32 key(42) bit-exactly.
// R6: topk-sim and masked-mean rewritten as bf16 MFMA GEMMs
//     (mfma_f32_16x16x32_bf16). Mask bits expand to exact 0/1 bf16 A-frags;
//     agg/xn carried as bf16 (error << tolerance, fp32 accumulate in AGPRs).

#define N_NODES 4096
#define C_DIM   128
#define WPR     128        // bitmask words per row (4096/32)
#define HALF_P  8388608u   // N*N/2
#define TOPK    10

typedef __attribute__((ext_vector_type(8))) short bf16x8;   // 8 bf16 = 4 VGPRs
typedef __attribute__((ext_vector_type(4))) float f32x4;    // MFMA C/D

__device__ __forceinline__ uint16_t f2bf(float f) {         // RNE fp32->bf16
    uint32_t u = __float_as_uint(f);
    return (uint16_t)((u + 0x7FFFu + ((u >> 16) & 1u)) >> 16);
}

__device__ __forceinline__ uint32_t rotl32(uint32_t v, int r) {
    return (v << r) | (v >> (32 - r));
}

__device__ __forceinline__ void threefry2x32(uint32_t k0, uint32_t k1,
                                             uint32_t x0, uint32_t x1,
                                             uint32_t& o0, uint32_t& o1) {
    uint32_t ks2 = k0 ^ k1 ^ 0x1BD11BDAu;
    x0 += k0; x1 += k1;
#define TF_ROUND(r) { x0 += x1; x1 = rotl32(x1, (r)); x1 ^= x0; }
    TF_ROUND(13) TF_ROUND(15) TF_ROUND(26) TF_ROUND(6)
    x0 += k1;  x1 += ks2 + 1u;
    TF_ROUND(17) TF_ROUND(29) TF_ROUND(16) TF_ROUND(24)
    x0 += ks2; x1 += k0 + 2u;
    TF_ROUND(13) TF_ROUND(15) TF_ROUND(26) TF_ROUND(6)
    x0 += k0;  x1 += k1 + 3u;
    TF_ROUND(17) TF_ROUND(29) TF_ROUND(16) TF_ROUND(24)
    x0 += k1;  x1 += ks2 + 4u;
    TF_ROUND(13) TF_ROUND(15) TF_ROUND(26) TF_ROUND(6)
    x0 += ks2; x1 += k0 + 5u;
#undef TF_ROUND
    o0 = x0; o1 = x1;
}

// ---- edge_index dtype detection: flags[0]=1 iff int64 ---------------------
__global__ void detect_kernel(const uint32_t* __restrict__ ew,
                              uint32_t* __restrict__ flags) {
    __shared__ int cnt_oddnz;
    int t = threadIdx.x;
    if (t == 0) cnt_oddnz = 0;
    __syncthreads();
    if (ew[2 * t + 1] != 0u) atomicAdd(&cnt_oddnz, 1);
    __syncthreads();
    if (t == 0) flags[0] = (cnt_oddnz > 8) ? 0u : 1u;
}

// ---- scatter edges into adjacency bitmask (dedup via OR) ------------------
__global__ void scatter_kernel(const int* __restrict__ ei, int E,
                               uint32_t* __restrict__ Abits,
                               const uint32_t* __restrict__ flags) {
    int e = blockIdx.x * blockDim.x + threadIdx.x;
    if (e >= E) return;
    int src, dst;
    if (flags[0]) { src = ei[2 * e]; dst = ei[2 * (E + e)]; }
    else          { src = ei[e];     dst = ei[E + e]; }
    src &= (N_NODES - 1);
    dst &= (N_NODES - 1);
    atomicOr(&Abits[src * WPR + (dst >> 5)], 1u << (dst & 31));
}

// ---- SpMM: hop1[i,:] = sum_{j in bits(i)} x[j,:] --------------------------
__global__ void spmm_kernel(const uint32_t* __restrict__ Abits,
                            const float* __restrict__ in,
                            float* __restrict__ out) {
    int i = blockIdx.x;
    int c = threadIdx.x;                 // 128
    __shared__ uint32_t wbits[WPR];
    wbits[c] = Abits[i * WPR + c];
    __syncthreads();
    float acc = 0.f;
    for (int w = 0; w < WPR; ++w) {
        uint32_t bits = wbits[w];
        while (bits) {
            int b = __ffs(bits) - 1;
            bits &= bits - 1;
            acc += in[(w * 32 + b) * C_DIM + c];
        }
    }
    out[i * C_DIM + c] = acc;
}

// ---- SpMM2 + agg: agg = a0*x + a1*hop1 + a2*(A@hop1) ----------------------
__global__ void spmm2_agg_kernel(const uint32_t* __restrict__ Abits,
                                 const float* __restrict__ hop1,
                                 const float* __restrict__ xf,
                                 const float* __restrict__ alpha,
                                 float* __restrict__ agg) {
    int i = blockIdx.x;
    int c = threadIdx.x;                 // 128
    __shared__ uint32_t wbits[WPR];
    wbits[c] = Abits[i * WPR + c];
    __syncthreads();
    float acc = 0.f;
    for (int w = 0; w < WPR; ++w) {
        uint32_t bits = wbits[w];
        while (bits) {
            int b = __ffs(bits) - 1;
            bits &= bits - 1;
            acc += hop1[(w * 32 + b) * C_DIM + c];
        }
    }
    agg[i * C_DIM + c] = alpha[0] * xf[i * C_DIM + c]
                       + alpha[1] * hop1[i * C_DIM + c]
                       + alpha[2] * acc;
}

// ---- row-normalize into bf16: xnb = bf16(x / (||x|| + 1e-8)) --------------
__global__ void norm_kernel(const float* __restrict__ xf,
                            uint16_t* __restrict__ xnb) {
    int i = blockIdx.x;
    int c = threadIdx.x;                 // 128
    float v = xf[i * C_DIM + c];
    float sq = v * v;
    #pragma unroll
    for (int off = 32; off >= 1; off >>= 1) sq += __shfl_xor(sq, off);
    __shared__ float ws[2];
    if ((c & 63) == 0) ws[c >> 6] = sq;
    __syncthreads();
    float tot = ws[0] + ws[1];
    xnb[i * C_DIM + c] = f2bf(v / (sqrtf(tot) + 1e-8f));
}

// ---- transpose agg fp32 [4096][128] -> aggTb bf16 [128][4096] -------------
__global__ void transpose_bf_kernel(const float* __restrict__ agg,
                                    uint16_t* __restrict__ aggTb) {
    __shared__ float tile[32][33];
    int bi = blockIdx.x;                 // j tile (128)
    int bc = blockIdx.y;                 // c tile (4)
    int tx = threadIdx.x & 31, ty = threadIdx.x >> 5;   // 256 thr
    #pragma unroll
    for (int r = 0; r < 32; r += 8)
        tile[ty + r][tx] = agg[(size_t)(bi * 32 + ty + r) * C_DIM + bc * 32 + tx];
    __syncthreads();
    #pragma unroll
    for (int r = 0; r < 32; r += 8)
        aggTb[(size_t)(bc * 32 + ty + r) * N_NODES + bi * 32 + tx] =
            f2bf(tile[tx][ty + r]);
}

// ---- threefry random keep-mask: bit p set iff uniform[p] < 0.5 ------------
__global__ void mask_kernel(uint32_t* __restrict__ Mbits) {
    uint32_t tid = blockIdx.x * blockDim.x + threadIdx.x;  // < 262144
    uint32_t base = tid * 32u;
    uint32_t w0 = 0u, w1 = 0u;
    for (int k = 0; k < 32; ++k) {
        uint32_t o0, o1;
        threefry2x32(0u, 42u, base + k, HALF_P + base + k, o0, o1);
        w0 |= (uint32_t)((o0 >> 31) ^ 1u) << k;
        w1 |= (uint32_t)((o1 >> 31) ^ 1u) << k;
    }
    Mbits[tid] = w0;
    Mbits[(HALF_P >> 5) + tid] = w1;
}

// ---- topk via MFMA: sim = xn @ xn^T (bf16), fused top-10 ------------------
// block = 16 i-rows (one MFMA m-tile), 512 thr = 8 waves.
// Wave w computes 16x16 sim tiles for j-tiles jt = w, w+8, ... (32 tiles).
// A-frag loaded once (K=128 = 4 steps). B-frag straight from row-major xnb
// (B[k][n] layout = lane n reads 8 contiguous k = xnb[j][c..c+7]).
// Per-tile: MFMA -> per-wave LDS tile -> 4 lanes/row scan -> tree-merge.
__launch_bounds__(512, 2)
__global__ void topk_kernel(const uint16_t* __restrict__ xnb,
                            uint32_t* __restrict__ Mbits) {
    int i0 = blockIdx.x * 16;
    int t = threadIdx.x;
    int w = t >> 6;                      // wave 0..7
    int lane = t & 63;
    int col = lane & 15;
    int quad = lane >> 4;                // 0..3

    __shared__ float stile[8][16][17];   // per-wave sim tiles (8.5 KB)
    __shared__ float sval[16 * 32 * TOPK];
    __shared__ int   sidx[16 * 32 * TOPK];

    bf16x8 af[4];
    #pragma unroll
    for (int s = 0; s < 4; ++s)
        af[s] = *(const bf16x8*)&xnb[(size_t)(i0 + col) * C_DIM + s * 32 + quad * 8];

    float tv[TOPK]; int ti[TOPK];
    #pragma unroll
    for (int k = 0; k < TOPK; ++k) { tv[k] = -1e30f; ti[k] = 0x7fffffff; }

    int row_s = lane >> 2;               // i-row this lane scans
    int sub   = lane & 3;                // j sub-stripe (4 j each)

    for (int jt = w; jt < 256; jt += 8) {
        int j0 = jt * 16;
        f32x4 acc = {0.f, 0.f, 0.f, 0.f};
        #pragma unroll
        for (int s = 0; s < 4; ++s) {
            bf16x8 bf = *(const bf16x8*)&xnb[(size_t)(j0 + col) * C_DIM + s * 32 + quad * 8];
            acc = __builtin_amdgcn_mfma_f32_16x16x32_bf16(af[s], bf, acc, 0, 0, 0);
        }
        // C/D: col=lane&15 (n=j), row=quad*4+reg (m=i)
        #pragma unroll
        for (int r = 0; r < 4; ++r)
            stile[w][quad * 4 + r][col] = acc[r];
        __syncthreads();
        #pragma unroll
        for (int v = 0; v < 4; ++v) {
            float d = stile[w][row_s][sub * 4 + v];
            if (d > tv[TOPK-1]) {        // ascending-j scan, strict >
                int j = j0 + sub * 4 + v;
                tv[TOPK-1] = d; ti[TOPK-1] = j;
                #pragma unroll
                for (int q = TOPK - 2; q >= 0; --q) {
                    if (tv[q+1] > tv[q]) {
                        float fv = tv[q]; tv[q] = tv[q+1]; tv[q+1] = fv;
                        int iv = ti[q];  ti[q] = ti[q+1];  ti[q+1] = iv;
                    }
                }
            }
        }
        __syncthreads();
    }

    // lists: [row][L][10], L = w*4 + sub (32 lists per row)
    int base = (row_s * 32 + w * 4 + sub) * TOPK;
    #pragma unroll
    for (int k = 0; k < TOPK; ++k) { sval[base + k] = tv[k]; sidx[base + k] = ti[k]; }

    int row = t >> 5, L = t & 31;
    for (int s = 16; s >= 1; s >>= 1) {
        __syncthreads();
        if (L < s) {
            int la = (row * 32 + L) * TOPK;
            int lb = (row * 32 + L + s) * TOPK;
            float ov[TOPK]; int oi[TOPK];
            int ia = 0, ib = 0;
            #pragma unroll
            for (int k = 0; k < TOPK; ++k) {
                float va = sval[la + ia], vb = sval[lb + ib];
                int   xa = sidx[la + ia], xb = sidx[lb + ib];
                bool takeA = (va > vb) || (va == vb && xa < xb);
                if (takeA) { ov[k] = va; oi[k] = xa; ++ia; }
                else       { ov[k] = vb; oi[k] = xb; ++ib; }
            }
            #pragma unroll
            for (int k = 0; k < TOPK; ++k) { sval[la + k] = ov[k]; sidx[la + k] = oi[k]; }
        }
    }
    __syncthreads();
    if (t < 16) {
        int i = i0 + t;
        #pragma unroll
        for (int k = 0; k < TOPK; ++k) {
            int j = sidx[(t * 32) * TOPK + k];
            Mbits[i * WPR + (j >> 5)] |= 1u << (j & 31);  // row-exclusive
        }
    }
}

// ---- degree per row (after topk forcing) ----------------------------------
__global__ void deg_kernel(const uint32_t* __restrict__ Mbits,
                           float* __restrict__ deg) {
    int i = blockIdx.x;
    int l = threadIdx.x;                 // 64
    const uint32_t* row = Mbits + (size_t)i * WPR;
    int c = __popc(row[l]) + __popc(row[l + 64]);
    #pragma unroll
    for (int off = 32; off >= 1; off >>= 1) c += __shfl_xor(c, off);
    if (l == 0) deg[i] = (float)c;
}

// ---- masked mean via MFMA: fused = (Mf @ agg) / deg -----------------------
// block = 16 i-rows, 512 thr = 8 waves; wave w owns c-tile n0 = w*16.
// A-frag (mask 0/1 bf16) built from the byte at [row][k0/8 + quad].
__launch_bounds__(512, 2)
__global__ void fused_kernel(const uint32_t* __restrict__ Mbits,
                             const uint16_t* __restrict__ aggTb,
                             const float* __restrict__ deg,
                             float* __restrict__ fused) {
    int i0 = blockIdx.x * 16;
    int t = threadIdx.x;
    int w = t >> 6;
    int lane = t & 63;
    int col = lane & 15;
    int quad = lane >> 4;
    __shared__ float sinv[16];
    if (t < 16) sinv[t] = 1.f / (deg[i0 + t] + 1e-6f);
    __syncthreads();

    const uint32_t* mrow = Mbits + (size_t)(i0 + col) * WPR;
    const uint16_t* brow = aggTb + (size_t)(w * 16 + col) * N_NODES;
    f32x4 acc = {0.f, 0.f, 0.f, 0.f};
    for (int k0 = 0; k0 < N_NODES; k0 += 32) {
        uint32_t mw = mrow[k0 >> 5];
        uint32_t byte = (mw >> (quad * 8)) & 0xFFu;   // bits j = k0+quad*8+e
        union { uint32_t u[4]; bf16x8 v; } a;
        #pragma unroll
        for (int p = 0; p < 4; ++p) {
            uint32_t lo = (byte >> (2 * p)) & 1u;
            uint32_t hi = (byte >> (2 * p + 1)) & 1u;
            a.u[p] = (lo ? 0x3F80u : 0u) | (hi ? 0x3F800000u : 0u);
        }
        bf16x8 b = *(const bf16x8*)&brow[k0 + quad * 8];
        acc = __builtin_amdgcn_mfma_f32_16x16x32_bf16(a.v, b, acc, 0, 0, 0);
    }
    #pragma unroll
    for (int r = 0; r < 4; ++r) {
        int il = quad * 4 + r;
        fused[(size_t)(i0 + il) * C_DIM + w * 16 + col] = acc[r] * sinv[il];
    }
}

// ---- h = [x, fused] @ fusion_W + fusion_b (8 rows/block) ------------------
__global__ void fusion_gemm(const float* __restrict__ xf,
                            const float* __restrict__ fused,
                            const float* __restrict__ W,
                            const float* __restrict__ b,
                            float* __restrict__ h) {
    int i0 = blockIdx.x * 8;
    int o = threadIdx.x;                 // 128
    __shared__ float lx[8][256];
    for (int r = o; r < 8 * 128; r += 128) {
        lx[r >> 7][r & 127]         = xf[(size_t)(i0 + (r >> 7)) * C_DIM + (r & 127)];
        lx[r >> 7][128 + (r & 127)] = fused[(size_t)(i0 + (r >> 7)) * C_DIM + (r & 127)];
    }
    __syncthreads();
    float acc[8];
    #pragma unroll
    for (int r = 0; r < 8; ++r) acc[r] = b[o];
    for (int k = 0; k < 256; ++k) {
        float wv = W[k * 128 + o];
        #pragma unroll
        for (int r = 0; r < 8; ++r) acc[r] = fmaf(lx[r][k], wv, acc[r]);
    }
    #pragma unroll
    for (int r = 0; r < 8; ++r) h[(size_t)(i0 + r) * 128 + o] = acc[r];
}

// ---- h1 = relu(h @ lin0_W + lin0_b) (8 rows/block) ------------------------
__global__ void lin0_gemm(const float* __restrict__ h,
                          const float* __restrict__ W,
                          const float* __restrict__ b,
                          float* __restrict__ h1) {
    int i0 = blockIdx.x * 8;
    int o = threadIdx.x;                 // 128
    __shared__ float lx[8][128];
    for (int r = o; r < 8 * 128; r += 128)
        lx[r >> 7][r & 127] = h[(size_t)(i0 + (r >> 7)) * 128 + (r & 127)];
    __syncthreads();
    float acc[8];
    #pragma unroll
    for (int r = 0; r < 8; ++r) acc[r] = b[o];
    for (int k = 0; k < 128; ++k) {
        float wv = W[k * 128 + o];
        #pragma unroll
        for (int r = 0; r < 8; ++r) acc[r] = fmaf(lx[r][k], wv, acc[r]);
    }
    #pragma unroll
    for (int r = 0; r < 8; ++r)
        h1[(size_t)(i0 + r) * 128 + o] = fmaxf(acc[r], 0.f);
}

// ---- out = log_softmax(h1 @ lin1_W + lin1_b) (8 rows/block, 1 wave) -------
__global__ void lin1_lsm(const float* __restrict__ h1,
                         const float* __restrict__ W,
                         const float* __restrict__ b,
                         float* __restrict__ out) {
    int i0 = blockIdx.x * 8;
    int o = threadIdx.x;                 // 64
    __shared__ float lx[8][128];
    for (int r = o; r < 8 * 128; r += 64)
        lx[r >> 7][r & 127] = h1[(size_t)(i0 + (r >> 7)) * 128 + (r & 127)];
    __syncthreads();
    float acc[8];
    #pragma unroll
    for (int r = 0; r < 8; ++r) acc[r] = b[o];
    for (int k = 0; k < 128; ++k) {
        float wv = W[k * 64 + o];
        #pragma unroll
        for (int r = 0; r < 8; ++r) acc[r] = fmaf(lx[r][k], wv, acc[r]);
    }
    #pragma unroll
    for (int r = 0; r < 8; ++r) {
        float m = acc[r];
        #pragma unroll
        for (int off = 32; off >= 1; off >>= 1) m = fmaxf(m, __shfl_xor(m, off));
        float e = expf(acc[r] - m);
        float s = e;
        #pragma unroll
        for (int off = 32; off >= 1; off >>= 1) s += __shfl_xor(s, off);
        out[(size_t)(i0 + r) * 64 + o] = acc[r] - m - logf(s);
    }
}

extern "C" void kernel_launch(void* const* d_in, const int* in_sizes, int n_in,
                              void* d_out, int out_size, void* d_ws, size_t ws_size,
                              hipStream_t stream) {
    const float* xf    = (const float*)d_in[0];
    const int*   ei    = (const int*)d_in[1];
    const float* alpha = (const float*)d_in[2];
    const float* fW    = (const float*)d_in[3];
    const float* fB    = (const float*)d_in[4];
    const float* l0W   = (const float*)d_in[5];
    const float* l0B   = (const float*)d_in[6];
    const float* l1W   = (const float*)d_in[7];
    const float* l1B   = (const float*)d_in[8];
    float* out = (float*)d_out;
    const int E  = in_sizes[1] / 2;     // 65536
    const int NC = N_NODES * C_DIM;     // 524288

    char* p = (char*)d_ws;
    uint32_t* flags = (uint32_t*)p; p += 256;
    const size_t SZ = (size_t)NC * 4;   // 2 MB
    uint32_t* Abits = (uint32_t*)p; p += SZ;
    float*    hop1  = (float*)p;    p += SZ;
    float*    agg   = (float*)p;    p += SZ;
    uint32_t* Mbits = (uint32_t*)p; p += SZ;
    float*    fusd  = (float*)p;    p += SZ;
    float*    h     = (float*)p;    p += SZ;
    float*    h1    = (float*)p;    p += SZ;
    uint16_t* xnb   = (uint16_t*)p; p += SZ / 2;   // 1 MB bf16
    uint16_t* aggTb = (uint16_t*)p; p += SZ / 2;   // 1 MB bf16
    float*    deg   = (float*)p;    p += N_NODES * 4;

    hipMemsetAsync(Abits, 0, SZ, stream);
    detect_kernel<<<1, 256, 0, stream>>>((const uint32_t*)ei, flags);
    scatter_kernel<<<(E + 255) / 256, 256, 0, stream>>>(ei, E, Abits, flags);
    spmm_kernel<<<N_NODES, 128, 0, stream>>>(Abits, xf, hop1);
    spmm2_agg_kernel<<<N_NODES, 128, 0, stream>>>(Abits, hop1, xf, alpha, agg);
    norm_kernel<<<N_NODES, 128, 0, stream>>>(xf, xnb);
    transpose_bf_kernel<<<dim3(128, 4), 256, 0, stream>>>(agg, aggTb);
    mask_kernel<<<(HALF_P >> 5) / 256, 256, 0, stream>>>(Mbits);
    topk_kernel<<<N_NODES / 16, 512, 0, stream>>>(xnb, Mbits);
    deg_kernel<<<N_NODES, 64, 0, stream>>>(Mbits, deg);
    fused_kernel<<<N_NODES / 16, 512, 0, stream>>>(Mbits, aggTb, deg, fusd);
    fusion_gemm<<<N_NODES / 8, 128, 0, stream>>>(xf, fusd, fW, fB, h);
    lin0_gemm<<<N_NODES / 8, 128, 0, stream>>>(h, l0W, l0B, h1);
    lin1_lsm<<<N_NODES / 8, 64, 0, stream>>>(h1, l1W, l1B, out);
}

// Round 7
// 320.291 us; speedup vs baseline: 4.3258x; 1.1011x over previous
//
#include <hip/hip_runtime.h>
#include <hip/hip_bf16.h>
#include <stdint.h>

// ScaleGNN on MI355X (gfx950). fp32 in / fp32 out. edge_index int32/int64
// auto-detect. Random mask reproduces JAX threefry2x32 key(42) bit-exactly.
// R7: topk barrier fix — per-wave LDS sim tile needs NO block barrier
//     (wave-local s_waitcnt + wave_barrier); j-range split across 2 blocks
//     (2 blocks/CU); sorted half-lists merged by tiny topmerge kernel.

#define N_NODES 4096
#define C_DIM   128
#define WPR     128        // bitmask words per row (4096/32)
#define HALF_P  8388608u   // N*N/2
#define TOPK    10

typedef __attribute__((ext_vector_type(8))) short bf16x8;   // 8 bf16 = 4 VGPRs
typedef __attribute__((ext_vector_type(4))) float f32x4;    // MFMA C/D

__device__ __forceinline__ uint16_t f2bf(float f) {         // RNE fp32->bf16
    uint32_t u = __float_as_uint(f);
    return (uint16_t)((u + 0x7FFFu + ((u >> 16) & 1u)) >> 16);
}

__device__ __forceinline__ uint32_t rotl32(uint32_t v, int r) {
    return (v << r) | (v >> (32 - r));
}

__device__ __forceinline__ void threefry2x32(uint32_t k0, uint32_t k1,
                                             uint32_t x0, uint32_t x1,
                                             uint32_t& o0, uint32_t& o1) {
    uint32_t ks2 = k0 ^ k1 ^ 0x1BD11BDAu;
    x0 += k0; x1 += k1;
#define TF_ROUND(r) { x0 += x1; x1 = rotl32(x1, (r)); x1 ^= x0; }
    TF_ROUND(13) TF_ROUND(15) TF_ROUND(26) TF_ROUND(6)
    x0 += k1;  x1 += ks2 + 1u;
    TF_ROUND(17) TF_ROUND(29) TF_ROUND(16) TF_ROUND(24)
    x0 += ks2; x1 += k0 + 2u;
    TF_ROUND(13) TF_ROUND(15) TF_ROUND(26) TF_ROUND(6)
    x0 += k0;  x1 += k1 + 3u;
    TF_ROUND(17) TF_ROUND(29) TF_ROUND(16) TF_ROUND(24)
    x0 += k1;  x1 += ks2 + 4u;
    TF_ROUND(13) TF_ROUND(15) TF_ROUND(26) TF_ROUND(6)
    x0 += ks2; x1 += k0 + 5u;
#undef TF_ROUND
    o0 = x0; o1 = x1;
}

// ---- edge_index dtype detection: flags[0]=1 iff int64 ---------------------
__global__ void detect_kernel(const uint32_t* __restrict__ ew,
                              uint32_t* __restrict__ flags) {
    __shared__ int cnt_oddnz;
    int t = threadIdx.x;
    if (t == 0) cnt_oddnz = 0;
    __syncthreads();
    if (ew[2 * t + 1] != 0u) atomicAdd(&cnt_oddnz, 1);
    __syncthreads();
    if (t == 0) flags[0] = (cnt_oddnz > 8) ? 0u : 1u;
}

// ---- scatter edges into adjacency bitmask (dedup via OR) ------------------
__global__ void scatter_kernel(const int* __restrict__ ei, int E,
                               uint32_t* __restrict__ Abits,
                               const uint32_t* __restrict__ flags) {
    int e = blockIdx.x * blockDim.x + threadIdx.x;
    if (e >= E) return;
    int src, dst;
    if (flags[0]) { src = ei[2 * e]; dst = ei[2 * (E + e)]; }
    else          { src = ei[e];     dst = ei[E + e]; }
    src &= (N_NODES - 1);
    dst &= (N_NODES - 1);
    atomicOr(&Abits[src * WPR + (dst >> 5)], 1u << (dst & 31));
}

// ---- SpMM: hop1[i,:] = sum_{j in bits(i)} x[j,:] --------------------------
__global__ void spmm_kernel(const uint32_t* __restrict__ Abits,
                            const float* __restrict__ in,
                            float* __restrict__ out) {
    int i = blockIdx.x;
    int c = threadIdx.x;                 // 128
    __shared__ uint32_t wbits[WPR];
    wbits[c] = Abits[i * WPR + c];
    __syncthreads();
    float acc = 0.f;
    for (int w = 0; w < WPR; ++w) {
        uint32_t bits = wbits[w];
        while (bits) {
            int b = __ffs(bits) - 1;
            bits &= bits - 1;
            acc += in[(w * 32 + b) * C_DIM + c];
        }
    }
    out[i * C_DIM + c] = acc;
}

// ---- SpMM2 + agg: agg = a0*x + a1*hop1 + a2*(A@hop1) ----------------------
__global__ void spmm2_agg_kernel(const uint32_t* __restrict__ Abits,
                                 const float* __restrict__ hop1,
                                 const float* __restrict__ xf,
                                 const float* __restrict__ alpha,
                                 float* __restrict__ agg) {
    int i = blockIdx.x;
    int c = threadIdx.x;                 // 128
    __shared__ uint32_t wbits[WPR];
    wbits[c] = Abits[i * WPR + c];
    __syncthreads();
    float acc = 0.f;
    for (int w = 0; w < WPR; ++w) {
        uint32_t bits = wbits[w];
        while (bits) {
            int b = __ffs(bits) - 1;
            bits &= bits - 1;
            acc += hop1[(w * 32 + b) * C_DIM + c];
        }
    }
    agg[i * C_DIM + c] = alpha[0] * xf[i * C_DIM + c]
                       + alpha[1] * hop1[i * C_DIM + c]
                       + alpha[2] * acc;
}

// ---- row-normalize into bf16: xnb = bf16(x / (||x|| + 1e-8)) --------------
__global__ void norm_kernel(const float* __restrict__ xf,
                            uint16_t* __restrict__ xnb) {
    int i = blockIdx.x;
    int c = threadIdx.x;                 // 128
    float v = xf[i * C_DIM + c];
    float sq = v * v;
    #pragma unroll
    for (int off = 32; off >= 1; off >>= 1) sq += __shfl_xor(sq, off);
    __shared__ float ws[2];
    if ((c & 63) == 0) ws[c >> 6] = sq;
    __syncthreads();
    float tot = ws[0] + ws[1];
    xnb[i * C_DIM + c] = f2bf(v / (sqrtf(tot) + 1e-8f));
}

// ---- transpose agg fp32 [4096][128] -> aggTb bf16 [128][4096] -------------
__global__ void transpose_bf_kernel(const float* __restrict__ agg,
                                    uint16_t* __restrict__ aggTb) {
    __shared__ float tile[32][33];
    int bi = blockIdx.x;                 // j tile (128)
    int bc = blockIdx.y;                 // c tile (4)
    int tx = threadIdx.x & 31, ty = threadIdx.x >> 5;   // 256 thr
    #pragma unroll
    for (int r = 0; r < 32; r += 8)
        tile[ty + r][tx] = agg[(size_t)(bi * 32 + ty + r) * C_DIM + bc * 32 + tx];
    __syncthreads();
    #pragma unroll
    for (int r = 0; r < 32; r += 8)
        aggTb[(size_t)(bc * 32 + ty + r) * N_NODES + bi * 32 + tx] =
            f2bf(tile[tx][ty + r]);
}

// ---- threefry random keep-mask: bit p set iff uniform[p] < 0.5 ------------
__global__ void mask_kernel(uint32_t* __restrict__ Mbits) {
    uint32_t tid = blockIdx.x * blockDim.x + threadIdx.x;  // < 262144
    uint32_t base = tid * 32u;
    uint32_t w0 = 0u, w1 = 0u;
    for (int k = 0; k < 32; ++k) {
        uint32_t o0, o1;
        threefry2x32(0u, 42u, base + k, HALF_P + base + k, o0, o1);
        w0 |= (uint32_t)((o0 >> 31) ^ 1u) << k;
        w1 |= (uint32_t)((o1 >> 31) ^ 1u) << k;
    }
    Mbits[tid] = w0;
    Mbits[(HALF_P >> 5) + tid] = w1;
}

// ---- topk via MFMA: sim = xn @ xn^T (bf16); per-half sorted top-10 --------
// grid (256, 2): block = 16 i-rows x half of j. 512 thr = 8 waves; wave w
// scans 16 contiguous j-tiles. Per-wave LDS sim tile — NO block barrier in
// the hot loop (intra-wave DS ordering + lgkmcnt). Epilogue: 32-list LDS
// tree-merge per row (verified R6 structure), result to global topv/topi.
__launch_bounds__(512, 4)
__global__ void topk_kernel(const uint16_t* __restrict__ xnb,
                            float* __restrict__ topv,
                            int* __restrict__ topi) {
    int i0 = blockIdx.x * 16;
    int half = blockIdx.y;
    int t = threadIdx.x;
    int w = t >> 6;                      // wave 0..7
    int lane = t & 63;
    int col = lane & 15;
    int quad = lane >> 4;                // 0..3

    __shared__ float stile[8][16][17];   // per-wave sim tiles
    __shared__ float sval[16 * 32 * TOPK];
    __shared__ int   sidx[16 * 32 * TOPK];

    bf16x8 af[4];
    #pragma unroll
    for (int s = 0; s < 4; ++s)
        af[s] = *(const bf16x8*)&xnb[(size_t)(i0 + col) * C_DIM + s * 32 + quad * 8];

    float tv[TOPK]; int ti[TOPK];
    #pragma unroll
    for (int k = 0; k < TOPK; ++k) { tv[k] = -1e30f; ti[k] = 0x7fffffff; }

    int row_s = lane >> 2;               // i-row this lane scans
    int sub   = lane & 3;                // j sub-stripe (4 j each)

    int jt0 = half * 128 + w * 16;
    for (int p = 0; p < 16; ++p) {
        int j0 = (jt0 + p) * 16;
        f32x4 acc = {0.f, 0.f, 0.f, 0.f};
        #pragma unroll
        for (int s = 0; s < 4; ++s) {
            bf16x8 bf = *(const bf16x8*)&xnb[(size_t)(j0 + col) * C_DIM + s * 32 + quad * 8];
            acc = __builtin_amdgcn_mfma_f32_16x16x32_bf16(af[s], bf, acc, 0, 0, 0);
        }
        // C/D: col=lane&15 (j), row=quad*4+reg (i)
        #pragma unroll
        for (int r = 0; r < 4; ++r)
            stile[w][quad * 4 + r][col] = acc[r];
        // wave-local ordering only: DS pipe is in-order per wave
        __asm__ volatile("s_waitcnt lgkmcnt(0)" ::: "memory");
        __builtin_amdgcn_wave_barrier();
        #pragma unroll
        for (int v = 0; v < 4; ++v) {
            float d = stile[w][row_s][sub * 4 + v];
            if (d > tv[TOPK-1]) {        // ascending-j scan, strict >
                int j = j0 + sub * 4 + v;
                tv[TOPK-1] = d; ti[TOPK-1] = j;
                #pragma unroll
                for (int q = TOPK - 2; q >= 0; --q) {
                    if (tv[q+1] > tv[q]) {
                        float fv = tv[q]; tv[q] = tv[q+1]; tv[q+1] = fv;
                        int iv = ti[q];  ti[q] = ti[q+1];  ti[q+1] = iv;
                    }
                }
            }
        }
        __builtin_amdgcn_wave_barrier();
    }

    // lists: [row][L][10], L = w*4 + sub (32 lists per row)
    int base = (row_s * 32 + w * 4 + sub) * TOPK;
    #pragma unroll
    for (int k = 0; k < TOPK; ++k) { sval[base + k] = tv[k]; sidx[base + k] = ti[k]; }

    int row = t >> 5, L = t & 31;
    for (int s = 16; s >= 1; s >>= 1) {
        __syncthreads();
        if (L < s) {
            int la = (row * 32 + L) * TOPK;
            int lb = (row * 32 + L + s) * TOPK;
            float ov[TOPK]; int oi[TOPK];
            int ia = 0, ib = 0;
            #pragma unroll
            for (int k = 0; k < TOPK; ++k) {
                float va = sval[la + ia], vb = sval[lb + ib];
                int   xa = sidx[la + ia], xb = sidx[lb + ib];
                bool takeA = (va > vb) || (va == vb && xa < xb);
                if (takeA) { ov[k] = va; oi[k] = xa; ++ia; }
                else       { ov[k] = vb; oi[k] = xb; ++ib; }
            }
            #pragma unroll
            for (int k = 0; k < TOPK; ++k) { sval[la + k] = ov[k]; sidx[la + k] = oi[k]; }
        }
    }
    __syncthreads();
    if (t < 16) {
        size_t gi = (size_t)(half * N_NODES + i0 + t) * TOPK;
        #pragma unroll
        for (int k = 0; k < TOPK; ++k) {
            topv[gi + k] = sval[(t * 32) * TOPK + k];
            topi[gi + k] = sidx[(t * 32) * TOPK + k];
        }
    }
}

// ---- merge the two half top-10 lists per row, OR bits into Mbits ----------
__global__ void topmerge_kernel(const float* __restrict__ topv,
                                const int* __restrict__ topi,
                                uint32_t* __restrict__ Mbits) {
    int i = blockIdx.x * blockDim.x + threadIdx.x;
    if (i >= N_NODES) return;
    const float* va = topv + (size_t)i * TOPK;
    const float* vb = topv + (size_t)(N_NODES + i) * TOPK;
    const int*   xa = topi + (size_t)i * TOPK;
    const int*   xb = topi + (size_t)(N_NODES + i) * TOPK;
    int ia = 0, ib = 0;
    #pragma unroll
    for (int k = 0; k < TOPK; ++k) {     // ia+ib==k<=9 => in-bounds
        float fa = va[ia], fb = vb[ib];
        int   ja = xa[ia], jb = xb[ib];
        bool takeA = (fa > fb) || (fa == fb && ja < jb);
        int j = takeA ? ja : jb;
        if (takeA) ++ia; else ++ib;
        Mbits[(size_t)i * WPR + (j >> 5)] |= 1u << (j & 31);  // row-exclusive
    }
}

// ---- degree per row (after topk forcing) ----------------------------------
__global__ void deg_kernel(const uint32_t* __restrict__ Mbits,
                           float* __restrict__ deg) {
    int i = blockIdx.x;
    int l = threadIdx.x;                 // 64
    const uint32_t* row = Mbits + (size_t)i * WPR;
    int c = __popc(row[l]) + __popc(row[l + 64]);
    #pragma unroll
    for (int off = 32; off >= 1; off >>= 1) c += __shfl_xor(c, off);
    if (l == 0) deg[i] = (float)c;
}

// ---- masked mean via MFMA: fused = (Mf @ agg) / deg -----------------------
__launch_bounds__(512, 2)
__global__ void fused_kernel(const uint32_t* __restrict__ Mbits,
                             const uint16_t* __restrict__ aggTb,
                             const float* __restrict__ deg,
                             float* __restrict__ fused) {
    int i0 = blockIdx.x * 16;
    int t = threadIdx.x;
    int w = t >> 6;
    int lane = t & 63;
    int col = lane & 15;
    int quad = lane >> 4;
    __shared__ float sinv[16];
    if (t < 16) sinv[t] = 1.f / (deg[i0 + t] + 1e-6f);
    __syncthreads();

    const uint32_t* mrow = Mbits + (size_t)(i0 + col) * WPR;
    const uint16_t* brow = aggTb + (size_t)(w * 16 + col) * N_NODES;
    f32x4 acc = {0.f, 0.f, 0.f, 0.f};
    for (int k0 = 0; k0 < N_NODES; k0 += 32) {
        uint32_t mw = mrow[k0 >> 5];
        uint32_t byte = (mw >> (quad * 8)) & 0xFFu;   // bits j = k0+quad*8+e
        union { uint32_t u[4]; bf16x8 v; } a;
        #pragma unroll
        for (int p = 0; p < 4; ++p) {
            uint32_t lo = (byte >> (2 * p)) & 1u;
            uint32_t hi = (byte >> (2 * p + 1)) & 1u;
            a.u[p] = (lo ? 0x3F80u : 0u) | (hi ? 0x3F800000u : 0u);
        }
        bf16x8 b = *(const bf16x8*)&brow[k0 + quad * 8];
        acc = __builtin_amdgcn_mfma_f32_16x16x32_bf16(a.v, b, acc, 0, 0, 0);
    }
    #pragma unroll
    for (int r = 0; r < 4; ++r) {
        int il = quad * 4 + r;
        fused[(size_t)(i0 + il) * C_DIM + w * 16 + col] = acc[r] * sinv[il];
    }
}

// ---- h = [x, fused] @ fusion_W + fusion_b (8 rows/block) ------------------
__global__ void fusion_gemm(const float* __restrict__ xf,
                            const float* __restrict__ fused,
                            const float* __restrict__ W,
                            const float* __restrict__ b,
                            float* __restrict__ h) {
    int i0 = blockIdx.x * 8;
    int o = threadIdx.x;                 // 128
    __shared__ float lx[8][256];
    for (int r = o; r < 8 * 128; r += 128) {
        lx[r >> 7][r & 127]         = xf[(size_t)(i0 + (r >> 7)) * C_DIM + (r & 127)];
        lx[r >> 7][128 + (r & 127)] = fused[(size_t)(i0 + (r >> 7)) * C_DIM + (r & 127)];
    }
    __syncthreads();
    float acc[8];
    #pragma unroll
    for (int r = 0; r < 8; ++r) acc[r] = b[o];
    for (int k = 0; k < 256; ++k) {
        float wv = W[k * 128 + o];
        #pragma unroll
        for (int r = 0; r < 8; ++r) acc[r] = fmaf(lx[r][k], wv, acc[r]);
    }
    #pragma unroll
    for (int r = 0; r < 8; ++r) h[(size_t)(i0 + r) * 128 + o] = acc[r];
}

// ---- h1 = relu(h @ lin0_W + lin0_b) (8 rows/block) ------------------------
__global__ void lin0_gemm(const float* __restrict__ h,
                          const float* __restrict__ W,
                          const float* __restrict__ b,
                          float* __restrict__ h1) {
    int i0 = blockIdx.x * 8;
    int o = threadIdx.x;                 // 128
    __shared__ float lx[8][128];
    for (int r = o; r < 8 * 128; r += 128)
        lx[r >> 7][r & 127] = h[(size_t)(i0 + (r >> 7)) * 128 + (r & 127)];
    __syncthreads();
    float acc[8];
    #pragma unroll
    for (int r = 0; r < 8; ++r) acc[r] = b[o];
    for (int k = 0; k < 128; ++k) {
        float wv = W[k * 128 + o];
        #pragma unroll
        for (int r = 0; r < 8; ++r) acc[r] = fmaf(lx[r][k], wv, acc[r]);
    }
    #pragma unroll
    for (int r = 0; r < 8; ++r)
        h1[(size_t)(i0 + r) * 128 + o] = fmaxf(acc[r], 0.f);
}

// ---- out = log_softmax(h1 @ lin1_W + lin1_b) (8 rows/block, 1 wave) -------
__global__ void lin1_lsm(const float* __restrict__ h1,
                         const float* __restrict__ W,
                         const float* __restrict__ b,
                         float* __restrict__ out) {
    int i0 = blockIdx.x * 8;
    int o = threadIdx.x;                 // 64
    __shared__ float lx[8][128];
    for (int r = o; r < 8 * 128; r += 64)
        lx[r >> 7][r & 127] = h1[(size_t)(i0 + (r >> 7)) * 128 + (r & 127)];
    __syncthreads();
    float acc[8];
    #pragma unroll
    for (int r = 0; r < 8; ++r) acc[r] = b[o];
    for (int k = 0; k < 128; ++k) {
        float wv = W[k * 64 + o];
        #pragma unroll
        for (int r = 0; r < 8; ++r) acc[r] = fmaf(lx[r][k], wv, acc[r]);
    }
    #pragma unroll
    for (int r = 0; r < 8; ++r) {
        float m = acc[r];
        #pragma unroll
        for (int off = 32; off >= 1; off >>= 1) m = fmaxf(m, __shfl_xor(m, off));
        float e = expf(acc[r] - m);
        float s = e;
        #pragma unroll
        for (int off = 32; off >= 1; off >>= 1) s += __shfl_xor(s, off);
        out[(size_t)(i0 + r) * 64 + o] = acc[r] - m - logf(s);
    }
}

extern "C" void kernel_launch(void* const* d_in, const int* in_sizes, int n_in,
                              void* d_out, int out_size, void* d_ws, size_t ws_size,
                              hipStream_t stream) {
    const float* xf    = (const float*)d_in[0];
    const int*   ei    = (const int*)d_in[1];
    const float* alpha = (const float*)d_in[2];
    const float* fW    = (const float*)d_in[3];
    const float* fB    = (const float*)d_in[4];
    const float* l0W   = (const float*)d_in[5];
    const float* l0B   = (const float*)d_in[6];
    const float* l1W   = (const float*)d_in[7];
    const float* l1B   = (const float*)d_in[8];
    float* out = (float*)d_out;
    const int E  = in_sizes[1] / 2;     // 65536
    const int NC = N_NODES * C_DIM;     // 524288

    char* p = (char*)d_ws;
    uint32_t* flags = (uint32_t*)p; p += 256;
    const size_t SZ = (size_t)NC * 4;   // 2 MB
    uint32_t* Abits = (uint32_t*)p; p += SZ;
    float*    hop1  = (float*)p;    p += SZ;
    float*    agg   = (float*)p;    p += SZ;
    uint32_t* Mbits = (uint32_t*)p; p += SZ;
    float*    fusd  = (float*)p;    p += SZ;
    float*    h     = (float*)p;    p += SZ;
    float*    h1    = (float*)p;    p += SZ;
    uint16_t* xnb   = (uint16_t*)p; p += SZ / 2;   // 1 MB bf16
    uint16_t* aggTb = (uint16_t*)p; p += SZ / 2;   // 1 MB bf16
    float*    deg   = (float*)p;    p += N_NODES * 4;
    float*    topv  = (float*)p;    p += (size_t)2 * N_NODES * TOPK * 4;
    int*      topi  = (int*)p;      p += (size_t)2 * N_NODES * TOPK * 4;

    hipMemsetAsync(Abits, 0, SZ, stream);
    detect_kernel<<<1, 256, 0, stream>>>((const uint32_t*)ei, flags);
    scatter_kernel<<<(E + 255) / 256, 256, 0, stream>>>(ei, E, Abits, flags);
    spmm_kernel<<<N_NODES, 128, 0, stream>>>(Abits, xf, hop1);
    spmm2_agg_kernel<<<N_NODES, 128, 0, stream>>>(Abits, hop1, xf, alpha, agg);
    norm_kernel<<<N_NODES, 128, 0, stream>>>(xf, xnb);
    transpose_bf_kernel<<<dim3(128, 4), 256, 0, stream>>>(agg, aggTb);
    mask_kernel<<<(HALF_P >> 5) / 256, 256, 0, stream>>>(Mbits);
    topk_kernel<<<dim3(N_NODES / 16, 2), 512, 0, stream>>>(xnb, topv, topi);
    topmerge_kernel<<<N_NODES / 256, 256, 0, stream>>>(topv, topi, Mbits);
    deg_kernel<<<N_NODES, 64, 0, stream>>>(Mbits, deg);
    fused_kernel<<<N_NODES / 16, 512, 0, stream>>>(Mbits, aggTb, deg, fusd);
    fusion_gemm<<<N_NODES / 8, 128, 0, stream>>>(xf, fusd, fW, fB, h);
    lin0_gemm<<<N_NODES / 8, 128, 0, stream>>>(h, l0W, l0B, h1);
    lin1_lsm<<<N_NODES / 8, 64, 0, stream>>>(h1, l1W, l1B, out);
}

// Round 8
// 311.623 us; speedup vs baseline: 4.4462x; 1.0278x over previous
//
#include <hip/hip_runtime.h>
#include <hip/hip_bf16.h>
#include <stdint.h>

// ScaleGNN on MI355X (gfx950). fp32 in / fp32 out. edge_index int32/int64
// auto-detect. Random mask reproduces JAX threefry2x32 key(42) bit-exactly.
// R8: topk MFMA operand swap — D[m=j][n=i] puts each lane's sim values for
//     its OWN i-row in registers; per-tile LDS round-trip deleted entirely.
//     fused_kernel: 4 independent MFMA accumulators (break latency chain).

#define N_NODES 4096
#define C_DIM   128
#define WPR     128        // bitmask words per row (4096/32)
#define HALF_P  8388608u   // N*N/2
#define TOPK    10

typedef __attribute__((ext_vector_type(8))) short bf16x8;   // 8 bf16 = 4 VGPRs
typedef __attribute__((ext_vector_type(4))) float f32x4;    // MFMA C/D

__device__ __forceinline__ uint16_t f2bf(float f) {         // RNE fp32->bf16
    uint32_t u = __float_as_uint(f);
    return (uint16_t)((u + 0x7FFFu + ((u >> 16) & 1u)) >> 16);
}

__device__ __forceinline__ uint32_t rotl32(uint32_t v, int r) {
    return (v << r) | (v >> (32 - r));
}

__device__ __forceinline__ void threefry2x32(uint32_t k0, uint32_t k1,
                                             uint32_t x0, uint32_t x1,
                                             uint32_t& o0, uint32_t& o1) {
    uint32_t ks2 = k0 ^ k1 ^ 0x1BD11BDAu;
    x0 += k0; x1 += k1;
#define TF_ROUND(r) { x0 += x1; x1 = rotl32(x1, (r)); x1 ^= x0; }
    TF_ROUND(13) TF_ROUND(15) TF_ROUND(26) TF_ROUND(6)
    x0 += k1;  x1 += ks2 + 1u;
    TF_ROUND(17) TF_ROUND(29) TF_ROUND(16) TF_ROUND(24)
    x0 += ks2; x1 += k0 + 2u;
    TF_ROUND(13) TF_ROUND(15) TF_ROUND(26) TF_ROUND(6)
    x0 += k0;  x1 += k1 + 3u;
    TF_ROUND(17) TF_ROUND(29) TF_ROUND(16) TF_ROUND(24)
    x0 += k1;  x1 += ks2 + 4u;
    TF_ROUND(13) TF_ROUND(15) TF_ROUND(26) TF_ROUND(6)
    x0 += ks2; x1 += k0 + 5u;
#undef TF_ROUND
    o0 = x0; o1 = x1;
}

// ---- edge_index dtype detection: flags[0]=1 iff int64 ---------------------
__global__ void detect_kernel(const uint32_t* __restrict__ ew,
                              uint32_t* __restrict__ flags) {
    __shared__ int cnt_oddnz;
    int t = threadIdx.x;
    if (t == 0) cnt_oddnz = 0;
    __syncthreads();
    if (ew[2 * t + 1] != 0u) atomicAdd(&cnt_oddnz, 1);
    __syncthreads();
    if (t == 0) flags[0] = (cnt_oddnz > 8) ? 0u : 1u;
}

// ---- scatter edges into adjacency bitmask (dedup via OR) ------------------
__global__ void scatter_kernel(const int* __restrict__ ei, int E,
                               uint32_t* __restrict__ Abits,
                               const uint32_t* __restrict__ flags) {
    int e = blockIdx.x * blockDim.x + threadIdx.x;
    if (e >= E) return;
    int src, dst;
    if (flags[0]) { src = ei[2 * e]; dst = ei[2 * (E + e)]; }
    else          { src = ei[e];     dst = ei[E + e]; }
    src &= (N_NODES - 1);
    dst &= (N_NODES - 1);
    atomicOr(&Abits[src * WPR + (dst >> 5)], 1u << (dst & 31));
}

// ---- SpMM: hop1[i,:] = sum_{j in bits(i)} x[j,:] --------------------------
__global__ void spmm_kernel(const uint32_t* __restrict__ Abits,
                            const float* __restrict__ in,
                            float* __restrict__ out) {
    int i = blockIdx.x;
    int c = threadIdx.x;                 // 128
    __shared__ uint32_t wbits[WPR];
    wbits[c] = Abits[i * WPR + c];
    __syncthreads();
    float acc = 0.f;
    for (int w = 0; w < WPR; ++w) {
        uint32_t bits = wbits[w];
        while (bits) {
            int b = __ffs(bits) - 1;
            bits &= bits - 1;
            acc += in[(w * 32 + b) * C_DIM + c];
        }
    }
    out[i * C_DIM + c] = acc;
}

// ---- SpMM2 + agg: agg = a0*x + a1*hop1 + a2*(A@hop1) ----------------------
__global__ void spmm2_agg_kernel(const uint32_t* __restrict__ Abits,
                                 const float* __restrict__ hop1,
                                 const float* __restrict__ xf,
                                 const float* __restrict__ alpha,
                                 float* __restrict__ agg) {
    int i = blockIdx.x;
    int c = threadIdx.x;                 // 128
    __shared__ uint32_t wbits[WPR];
    wbits[c] = Abits[i * WPR + c];
    __syncthreads();
    float acc = 0.f;
    for (int w = 0; w < WPR; ++w) {
        uint32_t bits = wbits[w];
        while (bits) {
            int b = __ffs(bits) - 1;
            bits &= bits - 1;
            acc += hop1[(w * 32 + b) * C_DIM + c];
        }
    }
    agg[i * C_DIM + c] = alpha[0] * xf[i * C_DIM + c]
                       + alpha[1] * hop1[i * C_DIM + c]
                       + alpha[2] * acc;
}

// ---- row-normalize into bf16: xnb = bf16(x / (||x|| + 1e-8)) --------------
__global__ void norm_kernel(const float* __restrict__ xf,
                            uint16_t* __restrict__ xnb) {
    int i = blockIdx.x;
    int c = threadIdx.x;                 // 128
    float v = xf[i * C_DIM + c];
    float sq = v * v;
    #pragma unroll
    for (int off = 32; off >= 1; off >>= 1) sq += __shfl_xor(sq, off);
    __shared__ float ws[2];
    if ((c & 63) == 0) ws[c >> 6] = sq;
    __syncthreads();
    float tot = ws[0] + ws[1];
    xnb[i * C_DIM + c] = f2bf(v / (sqrtf(tot) + 1e-8f));
}

// ---- transpose agg fp32 [4096][128] -> aggTb bf16 [128][4096] -------------
__global__ void transpose_bf_kernel(const float* __restrict__ agg,
                                    uint16_t* __restrict__ aggTb) {
    __shared__ float tile[32][33];
    int bi = blockIdx.x;                 // j tile (128)
    int bc = blockIdx.y;                 // c tile (4)
    int tx = threadIdx.x & 31, ty = threadIdx.x >> 5;   // 256 thr
    #pragma unroll
    for (int r = 0; r < 32; r += 8)
        tile[ty + r][tx] = agg[(size_t)(bi * 32 + ty + r) * C_DIM + bc * 32 + tx];
    __syncthreads();
    #pragma unroll
    for (int r = 0; r < 32; r += 8)
        aggTb[(size_t)(bc * 32 + ty + r) * N_NODES + bi * 32 + tx] =
            f2bf(tile[tx][ty + r]);
}

// ---- threefry random keep-mask: bit p set iff uniform[p] < 0.5 ------------
__global__ void mask_kernel(uint32_t* __restrict__ Mbits) {
    uint32_t tid = blockIdx.x * blockDim.x + threadIdx.x;  // < 262144
    uint32_t base = tid * 32u;
    uint32_t w0 = 0u, w1 = 0u;
    for (int k = 0; k < 32; ++k) {
        uint32_t o0, o1;
        threefry2x32(0u, 42u, base + k, HALF_P + base + k, o0, o1);
        w0 |= (uint32_t)((o0 >> 31) ^ 1u) << k;
        w1 |= (uint32_t)((o1 >> 31) ^ 1u) << k;
    }
    Mbits[tid] = w0;
    Mbits[(HALF_P >> 5) + tid] = w1;
}

// ---- topk via MFMA, register-direct scan ----------------------------------
// grid (256, 2): block = 16 i-rows x half of j. 512 thr = 8 waves.
// OPERAND SWAP: acc = mfma(A=xn[j-tile], B=xn[i-rows]) => D[m=j][n=i]:
// lane's col (lane&15) = its OWN i-row; rows m = quad*4+reg = j offsets.
// Top-10 scan runs on acc registers — no LDS in the hot loop.
// Epilogue: 32 lists/row (8 waves x 4 quads), verified tree-merge.
__launch_bounds__(512, 4)
__global__ void topk_kernel(const uint16_t* __restrict__ xnb,
                            float* __restrict__ topv,
                            int* __restrict__ topi) {
    int i0 = blockIdx.x * 16;
    int half = blockIdx.y;
    int t = threadIdx.x;
    int w = t >> 6;                      // wave 0..7
    int lane = t & 63;
    int col = lane & 15;
    int quad = lane >> 4;                // 0..3

    __shared__ float sval[16 * 32 * TOPK];
    __shared__ int   sidx[16 * 32 * TOPK];

    // B-frag: the block's 16 i-rows (loaded once)
    bf16x8 bfi[4];
    #pragma unroll
    for (int s = 0; s < 4; ++s)
        bfi[s] = *(const bf16x8*)&xnb[(size_t)(i0 + col) * C_DIM + s * 32 + quad * 8];

    float tv[TOPK]; int ti[TOPK];
    #pragma unroll
    for (int k = 0; k < TOPK; ++k) { tv[k] = -1e30f; ti[k] = 0x7fffffff; }

    int jt0 = half * 128 + w * 16;
    for (int p = 0; p < 16; ++p) {
        int j0 = (jt0 + p) * 16;
        f32x4 acc = {0.f, 0.f, 0.f, 0.f};
        #pragma unroll
        for (int s = 0; s < 4; ++s) {
            bf16x8 aj = *(const bf16x8*)&xnb[(size_t)(j0 + col) * C_DIM + s * 32 + quad * 8];
            acc = __builtin_amdgcn_mfma_f32_16x16x32_bf16(aj, bfi[s], acc, 0, 0, 0);
        }
        // lane holds sim[j0+quad*4+r][i0+col], r=0..3, j ascending
        #pragma unroll
        for (int r = 0; r < 4; ++r) {
            float d = acc[r];
            if (d > tv[TOPK-1]) {        // strict > keeps earliest j
                int j = j0 + quad * 4 + r;
                tv[TOPK-1] = d; ti[TOPK-1] = j;
                #pragma unroll
                for (int q = TOPK - 2; q >= 0; --q) {
                    if (tv[q+1] > tv[q]) {
                        float fv = tv[q]; tv[q] = tv[q+1]; tv[q+1] = fv;
                        int iv = ti[q];  ti[q] = ti[q+1];  ti[q+1] = iv;
                    }
                }
            }
        }
    }

    // lists: [row=col][L][10], L = w*4 + quad (32 lists per row)
    int base = (col * 32 + w * 4 + quad) * TOPK;
    #pragma unroll
    for (int k = 0; k < TOPK; ++k) { sval[base + k] = tv[k]; sidx[base + k] = ti[k]; }

    int row = t >> 5, L = t & 31;
    for (int s = 16; s >= 1; s >>= 1) {
        __syncthreads();
        if (L < s) {
            int la = (row * 32 + L) * TOPK;
            int lb = (row * 32 + L + s) * TOPK;
            float ov[TOPK]; int oi[TOPK];
            int ia = 0, ib = 0;
            #pragma unroll
            for (int k = 0; k < TOPK; ++k) {
                float va = sval[la + ia], vb = sval[lb + ib];
                int   xa = sidx[la + ia], xb = sidx[lb + ib];
                bool takeA = (va > vb) || (va == vb && xa < xb);
                if (takeA) { ov[k] = va; oi[k] = xa; ++ia; }
                else       { ov[k] = vb; oi[k] = xb; ++ib; }
            }
            #pragma unroll
            for (int k = 0; k < TOPK; ++k) { sval[la + k] = ov[k]; sidx[la + k] = oi[k]; }
        }
    }
    __syncthreads();
    if (t < 16) {
        size_t gi = (size_t)(half * N_NODES + i0 + t) * TOPK;
        #pragma unroll
        for (int k = 0; k < TOPK; ++k) {
            topv[gi + k] = sval[(t * 32) * TOPK + k];
            topi[gi + k] = sidx[(t * 32) * TOPK + k];
        }
    }
}

// ---- merge the two half top-10 lists per row, OR bits into Mbits ----------
__global__ void topmerge_kernel(const float* __restrict__ topv,
                                const int* __restrict__ topi,
                                uint32_t* __restrict__ Mbits) {
    int i = blockIdx.x * blockDim.x + threadIdx.x;
    if (i >= N_NODES) return;
    const float* va = topv + (size_t)i * TOPK;
    const float* vb = topv + (size_t)(N_NODES + i) * TOPK;
    const int*   xa = topi + (size_t)i * TOPK;
    const int*   xb = topi + (size_t)(N_NODES + i) * TOPK;
    int ia = 0, ib = 0;
    #pragma unroll
    for (int k = 0; k < TOPK; ++k) {     // ia+ib==k<=9 => in-bounds
        float fa = va[ia], fb = vb[ib];
        int   ja = xa[ia], jb = xb[ib];
        bool takeA = (fa > fb) || (fa == fb && ja < jb);
        int j = takeA ? ja : jb;
        if (takeA) ++ia; else ++ib;
        Mbits[(size_t)i * WPR + (j >> 5)] |= 1u << (j & 31);  // row-exclusive
    }
}

// ---- degree per row (after topk forcing) ----------------------------------
__global__ void deg_kernel(const uint32_t* __restrict__ Mbits,
                           float* __restrict__ deg) {
    int i = blockIdx.x;
    int l = threadIdx.x;                 // 64
    const uint32_t* row = Mbits + (size_t)i * WPR;
    int c = __popc(row[l]) + __popc(row[l + 64]);
    #pragma unroll
    for (int off = 32; off >= 1; off >>= 1) c += __shfl_xor(c, off);
    if (l == 0) deg[i] = (float)c;
}

// ---- masked mean via MFMA: fused = (Mf @ agg) / deg -----------------------
// 4 independent accumulators break the 128-deep MFMA latency chain.
__launch_bounds__(512, 2)
__global__ void fused_kernel(const uint32_t* __restrict__ Mbits,
                             const uint16_t* __restrict__ aggTb,
                             const float* __restrict__ deg,
                             float* __restrict__ fused) {
    int i0 = blockIdx.x * 16;
    int t = threadIdx.x;
    int w = t >> 6;
    int lane = t & 63;
    int col = lane & 15;
    int quad = lane >> 4;
    __shared__ float sinv[16];
    if (t < 16) sinv[t] = 1.f / (deg[i0 + t] + 1e-6f);
    __syncthreads();

    const uint32_t* mrow = Mbits + (size_t)(i0 + col) * WPR;
    const uint16_t* brow = aggTb + (size_t)(w * 16 + col) * N_NODES;
    f32x4 acc[4];
    #pragma unroll
    for (int u = 0; u < 4; ++u) acc[u] = (f32x4){0.f, 0.f, 0.f, 0.f};

    for (int k0 = 0; k0 < N_NODES; k0 += 128) {
        uint4 mw4 = *(const uint4*)&mrow[k0 >> 5];
        uint32_t mws[4] = {mw4.x, mw4.y, mw4.z, mw4.w};
        #pragma unroll
        for (int u = 0; u < 4; ++u) {
            uint32_t byte = (mws[u] >> (quad * 8)) & 0xFFu;
            union { uint32_t uu[4]; bf16x8 v; } a;
            #pragma unroll
            for (int pp = 0; pp < 4; ++pp) {
                uint32_t lo = (byte >> (2 * pp)) & 1u;
                uint32_t hi = (byte >> (2 * pp + 1)) & 1u;
                a.uu[pp] = (lo ? 0x3F80u : 0u) | (hi ? 0x3F800000u : 0u);
            }
            bf16x8 b = *(const bf16x8*)&brow[k0 + u * 32 + quad * 8];
            acc[u] = __builtin_amdgcn_mfma_f32_16x16x32_bf16(a.v, b, acc[u], 0, 0, 0);
        }
    }
    #pragma unroll
    for (int r = 0; r < 4; ++r) {
        int il = quad * 4 + r;
        float s = (acc[0][r] + acc[1][r]) + (acc[2][r] + acc[3][r]);
        fused[(size_t)(i0 + il) * C_DIM + w * 16 + col] = s * sinv[il];
    }
}

// ---- h = [x, fused] @ fusion_W + fusion_b (8 rows/block) ------------------
__global__ void fusion_gemm(const float* __restrict__ xf,
                            const float* __restrict__ fused,
                            const float* __restrict__ W,
                            const float* __restrict__ b,
                            float* __restrict__ h) {
    int i0 = blockIdx.x * 8;
    int o = threadIdx.x;                 // 128
    __shared__ float lx[8][256];
    for (int r = o; r < 8 * 128; r += 128) {
        lx[r >> 7][r & 127]         = xf[(size_t)(i0 + (r >> 7)) * C_DIM + (r & 127)];
        lx[r >> 7][128 + (r & 127)] = fused[(size_t)(i0 + (r >> 7)) * C_DIM + (r & 127)];
    }
    __syncthreads();
    float acc[8];
    #pragma unroll
    for (int r = 0; r < 8; ++r) acc[r] = b[o];
    for (int k = 0; k < 256; ++k) {
        float wv = W[k * 128 + o];
        #pragma unroll
        for (int r = 0; r < 8; ++r) acc[r] = fmaf(lx[r][k], wv, acc[r]);
    }
    #pragma unroll
    for (int r = 0; r < 8; ++r) h[(size_t)(i0 + r) * 128 + o] = acc[r];
}

// ---- h1 = relu(h @ lin0_W + lin0_b) (8 rows/block) ------------------------
__global__ void lin0_gemm(const float* __restrict__ h,
                          const float* __restrict__ W,
                          const float* __restrict__ b,
                          float* __restrict__ h1) {
    int i0 = blockIdx.x * 8;
    int o = threadIdx.x;                 // 128
    __shared__ float lx[8][128];
    for (int r = o; r < 8 * 128; r += 128)
        lx[r >> 7][r & 127] = h[(size_t)(i0 + (r >> 7)) * 128 + (r & 127)];
    __syncthreads();
    float acc[8];
    #pragma unroll
    for (int r = 0; r < 8; ++r) acc[r] = b[o];
    for (int k = 0; k < 128; ++k) {
        float wv = W[k * 128 + o];
        #pragma unroll
        for (int r = 0; r < 8; ++r) acc[r] = fmaf(lx[r][k], wv, acc[r]);
    }
    #pragma unroll
    for (int r = 0; r < 8; ++r)
        h1[(size_t)(i0 + r) * 128 + o] = fmaxf(acc[r], 0.f);
}

// ---- out = log_softmax(h1 @ lin1_W + lin1_b) (8 rows/block, 1 wave) -------
__global__ void lin1_lsm(const float* __restrict__ h1,
                         const float* __restrict__ W,
                         const float* __restrict__ b,
                         float* __restrict__ out) {
    int i0 = blockIdx.x * 8;
    int o = threadIdx.x;                 // 64
    __shared__ float lx[8][128];
    for (int r = o; r < 8 * 128; r += 64)
        lx[r >> 7][r & 127] = h1[(size_t)(i0 + (r >> 7)) * 128 + (r & 127)];
    __syncthreads();
    float acc[8];
    #pragma unroll
    for (int r = 0; r < 8; ++r) acc[r] = b[o];
    for (int k = 0; k < 128; ++k) {
        float wv = W[k * 64 + o];
        #pragma unroll
        for (int r = 0; r < 8; ++r) acc[r] = fmaf(lx[r][k], wv, acc[r]);
    }
    #pragma unroll
    for (int r = 0; r < 8; ++r) {
        float m = acc[r];
        #pragma unroll
        for (int off = 32; off >= 1; off >>= 1) m = fmaxf(m, __shfl_xor(m, off));
        float e = expf(acc[r] - m);
        float s = e;
        #pragma unroll
        for (int off = 32; off >= 1; off >>= 1) s += __shfl_xor(s, off);
        out[(size_t)(i0 + r) * 64 + o] = acc[r] - m - logf(s);
    }
}

extern "C" void kernel_launch(void* const* d_in, const int* in_sizes, int n_in,
                              void* d_out, int out_size, void* d_ws, size_t ws_size,
                              hipStream_t stream) {
    const float* xf    = (const float*)d_in[0];
    const int*   ei    = (const int*)d_in[1];
    const float* alpha = (const float*)d_in[2];
    const float* fW    = (const float*)d_in[3];
    const float* fB    = (const float*)d_in[4];
    const float* l0W   = (const float*)d_in[5];
    const float* l0B   = (const float*)d_in[6];
    const float* l1W   = (const float*)d_in[7];
    const float* l1B   = (const float*)d_in[8];
    float* out = (float*)d_out;
    const int E  = in_sizes[1] / 2;     // 65536
    const int NC = N_NODES * C_DIM;     // 524288

    char* p = (char*)d_ws;
    uint32_t* flags = (uint32_t*)p; p += 256;
    const size_t SZ = (size_t)NC * 4;   // 2 MB
    uint32_t* Abits = (uint32_t*)p; p += SZ;
    float*    hop1  = (float*)p;    p += SZ;
    float*    agg   = (float*)p;    p += SZ;
    uint32_t* Mbits = (uint32_t*)p; p += SZ;
    float*    fusd  = (float*)p;    p += SZ;
    float*    h     = (float*)p;    p += SZ;
    float*    h1    = (float*)p;    p += SZ;
    uint16_t* xnb   = (uint16_t*)p; p += SZ / 2;   // 1 MB bf16
    uint16_t* aggTb = (uint16_t*)p; p += SZ / 2;   // 1 MB bf16
    float*    deg   = (float*)p;    p += N_NODES * 4;
    float*    topv  = (float*)p;    p += (size_t)2 * N_NODES * TOPK * 4;
    int*      topi  = (int*)p;      p += (size_t)2 * N_NODES * TOPK * 4;

    hipMemsetAsync(Abits, 0, SZ, stream);
    detect_kernel<<<1, 256, 0, stream>>>((const uint32_t*)ei, flags);
    scatter_kernel<<<(E + 255) / 256, 256, 0, stream>>>(ei, E, Abits, flags);
    spmm_kernel<<<N_NODES, 128, 0, stream>>>(Abits, xf, hop1);
    spmm2_agg_kernel<<<N_NODES, 128, 0, stream>>>(Abits, hop1, xf, alpha, agg);
    norm_kernel<<<N_NODES, 128, 0, stream>>>(xf, xnb);
    transpose_bf_kernel<<<dim3(128, 4), 256, 0, stream>>>(agg, aggTb);
    mask_kernel<<<(HALF_P >> 5) / 256, 256, 0, stream>>>(Mbits);
    topk_kernel<<<dim3(N_NODES / 16, 2), 512, 0, stream>>>(xnb, topv, topi);
    topmerge_kernel<<<N_NODES / 256, 256, 0, stream>>>(topv, topi, Mbits);
    deg_kernel<<<N_NODES, 64, 0, stream>>>(Mbits, deg);
    fused_kernel<<<N_NODES / 16, 512, 0, stream>>>(Mbits, aggTb, deg, fusd);
    fusion_gemm<<<N_NODES / 8, 128, 0, stream>>>(xf, fusd, fW, fB, h);
    lin0_gemm<<<N_NODES / 8, 128, 0, stream>>>(h, l0W, l0B, h1);
    lin1_lsm<<<N_NODES / 8, 64, 0, stream>>>(h1, l1W, l1B, out);
}

// Round 9
// 268.866 us; speedup vs baseline: 5.1532x; 1.1590x over previous
//
#include <hip/hip_runtime.h>
#include <hip/hip_bf16.h>
#include <stdint.h>

// ScaleGNN on MI355X (gfx950). fp32 in / fp32 out. edge_index int32/int64
// auto-detect. Random mask reproduces JAX threefry2x32 key(42) bit-exactly.
// R9: topk j-split x4 (1024 blocks = 4/CU, LDS-exact) + max4 scan pre-filter;
//     4-way sorted-list merge; epilogue GEMMs at 4 rows/block.

#define N_NODES 4096
#define C_DIM   128
#define WPR     128        // bitmask words per row (4096/32)
#define HALF_P  8388608u   // N*N/2
#define TOPK    10
#define JSPLIT  4

typedef __attribute__((ext_vector_type(8))) short bf16x8;   // 8 bf16 = 4 VGPRs
typedef __attribute__((ext_vector_type(4))) float f32x4;    // MFMA C/D

__device__ __forceinline__ uint16_t f2bf(float f) {         // RNE fp32->bf16
    uint32_t u = __float_as_uint(f);
    return (uint16_t)((u + 0x7FFFu + ((u >> 16) & 1u)) >> 16);
}

__device__ __forceinline__ uint32_t rotl32(uint32_t v, int r) {
    return (v << r) | (v >> (32 - r));
}

__device__ __forceinline__ void threefry2x32(uint32_t k0, uint32_t k1,
                                             uint32_t x0, uint32_t x1,
                                             uint32_t& o0, uint32_t& o1) {
    uint32_t ks2 = k0 ^ k1 ^ 0x1BD11BDAu;
    x0 += k0; x1 += k1;
#define TF_ROUND(r) { x0 += x1; x1 = rotl32(x1, (r)); x1 ^= x0; }
    TF_ROUND(13) TF_ROUND(15) TF_ROUND(26) TF_ROUND(6)
    x0 += k1;  x1 += ks2 + 1u;
    TF_ROUND(17) TF_ROUND(29) TF_ROUND(16) TF_ROUND(24)
    x0 += ks2; x1 += k0 + 2u;
    TF_ROUND(13) TF_ROUND(15) TF_ROUND(26) TF_ROUND(6)
    x0 += k0;  x1 += k1 + 3u;
    TF_ROUND(17) TF_ROUND(29) TF_ROUND(16) TF_ROUND(24)
    x0 += k1;  x1 += ks2 + 4u;
    TF_ROUND(13) TF_ROUND(15) TF_ROUND(26) TF_ROUND(6)
    x0 += ks2; x1 += k0 + 5u;
#undef TF_ROUND
    o0 = x0; o1 = x1;
}

// ---- edge_index dtype detection: flags[0]=1 iff int64 ---------------------
__global__ void detect_kernel(const uint32_t* __restrict__ ew,
                              uint32_t* __restrict__ flags) {
    __shared__ int cnt_oddnz;
    int t = threadIdx.x;
    if (t == 0) cnt_oddnz = 0;
    __syncthreads();
    if (ew[2 * t + 1] != 0u) atomicAdd(&cnt_oddnz, 1);
    __syncthreads();
    if (t == 0) flags[0] = (cnt_oddnz > 8) ? 0u : 1u;
}

// ---- scatter edges into adjacency bitmask (dedup via OR) ------------------
__global__ void scatter_kernel(const int* __restrict__ ei, int E,
                               uint32_t* __restrict__ Abits,
                               const uint32_t* __restrict__ flags) {
    int e = blockIdx.x * blockDim.x + threadIdx.x;
    if (e >= E) return;
    int src, dst;
    if (flags[0]) { src = ei[2 * e]; dst = ei[2 * (E + e)]; }
    else          { src = ei[e];     dst = ei[E + e]; }
    src &= (N_NODES - 1);
    dst &= (N_NODES - 1);
    atomicOr(&Abits[src * WPR + (dst >> 5)], 1u << (dst & 31));
}

// ---- SpMM: hop1[i,:] = sum_{j in bits(i)} x[j,:] --------------------------
__global__ void spmm_kernel(const uint32_t* __restrict__ Abits,
                            const float* __restrict__ in,
                            float* __restrict__ out) {
    int i = blockIdx.x;
    int c = threadIdx.x;                 // 128
    __shared__ uint32_t wbits[WPR];
    wbits[c] = Abits[i * WPR + c];
    __syncthreads();
    float acc = 0.f;
    for (int w = 0; w < WPR; ++w) {
        uint32_t bits = wbits[w];
        while (bits) {
            int b = __ffs(bits) - 1;
            bits &= bits - 1;
            acc += in[(w * 32 + b) * C_DIM + c];
        }
    }
    out[i * C_DIM + c] = acc;
}

// ---- SpMM2 + agg: agg = a0*x + a1*hop1 + a2*(A@hop1) ----------------------
__global__ void spmm2_agg_kernel(const uint32_t* __restrict__ Abits,
                                 const float* __restrict__ hop1,
                                 const float* __restrict__ xf,
                                 const float* __restrict__ alpha,
                                 float* __restrict__ agg) {
    int i = blockIdx.x;
    int c = threadIdx.x;                 // 128
    __shared__ uint32_t wbits[WPR];
    wbits[c] = Abits[i * WPR + c];
    __syncthreads();
    float acc = 0.f;
    for (int w = 0; w < WPR; ++w) {
        uint32_t bits = wbits[w];
        while (bits) {
            int b = __ffs(bits) - 1;
            bits &= bits - 1;
            acc += hop1[(w * 32 + b) * C_DIM + c];
        }
    }
    agg[i * C_DIM + c] = alpha[0] * xf[i * C_DIM + c]
                       + alpha[1] * hop1[i * C_DIM + c]
                       + alpha[2] * acc;
}

// ---- row-normalize into bf16: xnb = bf16(x / (||x|| + 1e-8)) --------------
__global__ void norm_kernel(const float* __restrict__ xf,
                            uint16_t* __restrict__ xnb) {
    int i = blockIdx.x;
    int c = threadIdx.x;                 // 128
    float v = xf[i * C_DIM + c];
    float sq = v * v;
    #pragma unroll
    for (int off = 32; off >= 1; off >>= 1) sq += __shfl_xor(sq, off);
    __shared__ float ws[2];
    if ((c & 63) == 0) ws[c >> 6] = sq;
    __syncthreads();
    float tot = ws[0] + ws[1];
    xnb[i * C_DIM + c] = f2bf(v / (sqrtf(tot) + 1e-8f));
}

// ---- transpose agg fp32 [4096][128] -> aggTb bf16 [128][4096] -------------
__global__ void transpose_bf_kernel(const float* __restrict__ agg,
                                    uint16_t* __restrict__ aggTb) {
    __shared__ float tile[32][33];
    int bi = blockIdx.x;                 // j tile (128)
    int bc = blockIdx.y;                 // c tile (4)
    int tx = threadIdx.x & 31, ty = threadIdx.x >> 5;   // 256 thr
    #pragma unroll
    for (int r = 0; r < 32; r += 8)
        tile[ty + r][tx] = agg[(size_t)(bi * 32 + ty + r) * C_DIM + bc * 32 + tx];
    __syncthreads();
    #pragma unroll
    for (int r = 0; r < 32; r += 8)
        aggTb[(size_t)(bc * 32 + ty + r) * N_NODES + bi * 32 + tx] =
            f2bf(tile[tx][ty + r]);
}

// ---- threefry random keep-mask: bit p set iff uniform[p] < 0.5 ------------
__global__ void mask_kernel(uint32_t* __restrict__ Mbits) {
    uint32_t tid = blockIdx.x * blockDim.x + threadIdx.x;  // < 262144
    uint32_t base = tid * 32u;
    uint32_t w0 = 0u, w1 = 0u;
    for (int k = 0; k < 32; ++k) {
        uint32_t o0, o1;
        threefry2x32(0u, 42u, base + k, HALF_P + base + k, o0, o1);
        w0 |= (uint32_t)((o0 >> 31) ^ 1u) << k;
        w1 |= (uint32_t)((o1 >> 31) ^ 1u) << k;
    }
    Mbits[tid] = w0;
    Mbits[(HALF_P >> 5) + tid] = w1;
}

// ---- topk via MFMA, register-direct scan, j split 4 ways ------------------
// grid (256, 4): block = 16 i-rows x quarter of j (1024 j). 512 thr = 8
// waves; wave scans 8 16x16 tiles. Operand swap => lane's col = own i-row,
// sim values in acc registers. max4 pre-filter gates the insert path.
__launch_bounds__(512, 4)
__global__ void topk_kernel(const uint16_t* __restrict__ xnb,
                            float* __restrict__ topv,
                            int* __restrict__ topi) {
    int i0 = blockIdx.x * 16;
    int part = blockIdx.y;               // 0..3
    int t = threadIdx.x;
    int w = t >> 6;                      // wave 0..7
    int lane = t & 63;
    int col = lane & 15;
    int quad = lane >> 4;                // 0..3

    __shared__ float sval[16 * 32 * TOPK];
    __shared__ int   sidx[16 * 32 * TOPK];

    // B-frag: the block's 16 i-rows (loaded once)
    bf16x8 bfi[4];
    #pragma unroll
    for (int s = 0; s < 4; ++s)
        bfi[s] = *(const bf16x8*)&xnb[(size_t)(i0 + col) * C_DIM + s * 32 + quad * 8];

    float tv[TOPK]; int ti[TOPK];
    #pragma unroll
    for (int k = 0; k < TOPK; ++k) { tv[k] = -1e30f; ti[k] = 0x7fffffff; }

    int jt0 = part * 64 + w * 8;
    for (int p = 0; p < 8; ++p) {
        int j0 = (jt0 + p) * 16;
        f32x4 acc = {0.f, 0.f, 0.f, 0.f};
        #pragma unroll
        for (int s = 0; s < 4; ++s) {
            bf16x8 aj = *(const bf16x8*)&xnb[(size_t)(j0 + col) * C_DIM + s * 32 + quad * 8];
            acc = __builtin_amdgcn_mfma_f32_16x16x32_bf16(aj, bfi[s], acc, 0, 0, 0);
        }
        // lane holds sim[j0+quad*4+r][i0+col], r=0..3, j ascending
        float m4 = fmaxf(fmaxf(acc[0], acc[1]), fmaxf(acc[2], acc[3]));
        if (m4 > tv[TOPK-1]) {
            #pragma unroll
            for (int r = 0; r < 4; ++r) {
                float d = acc[r];
                if (d > tv[TOPK-1]) {    // strict > keeps earliest j
                    int j = j0 + quad * 4 + r;
                    tv[TOPK-1] = d; ti[TOPK-1] = j;
                    #pragma unroll
                    for (int q = TOPK - 2; q >= 0; --q) {
                        if (tv[q+1] > tv[q]) {
                            float fv = tv[q]; tv[q] = tv[q+1]; tv[q+1] = fv;
                            int iv = ti[q];  ti[q] = ti[q+1];  ti[q+1] = iv;
                        }
                    }
                }
            }
        }
    }

    // lists: [row=col][L][10], L = w*4 + quad (32 lists per row)
    int base = (col * 32 + w * 4 + quad) * TOPK;
    #pragma unroll
    for (int k = 0; k < TOPK; ++k) { sval[base + k] = tv[k]; sidx[base + k] = ti[k]; }

    int row = t >> 5, L = t & 31;
    for (int s = 16; s >= 1; s >>= 1) {
        __syncthreads();
        if (L < s) {
            int la = (row * 32 + L) * TOPK;
            int lb = (row * 32 + L + s) * TOPK;
            float ov[TOPK]; int oi[TOPK];
            int ia = 0, ib = 0;
            #pragma unroll
            for (int k = 0; k < TOPK; ++k) {
                float va = sval[la + ia], vb = sval[lb + ib];
                int   xa = sidx[la + ia], xb = sidx[lb + ib];
                bool takeA = (va > vb) || (va == vb && xa < xb);
                if (takeA) { ov[k] = va; oi[k] = xa; ++ia; }
                else       { ov[k] = vb; oi[k] = xb; ++ib; }
            }
            #pragma unroll
            for (int k = 0; k < TOPK; ++k) { sval[la + k] = ov[k]; sidx[la + k] = oi[k]; }
        }
    }
    __syncthreads();
    if (t < 16) {
        size_t gi = (size_t)(part * N_NODES + i0 + t) * TOPK;
        #pragma unroll
        for (int k = 0; k < TOPK; ++k) {
            topv[gi + k] = sval[(t * 32) * TOPK + k];
            topi[gi + k] = sidx[(t * 32) * TOPK + k];
        }
    }
}

// ---- 4-way merge of sorted quarter lists, OR bits into Mbits --------------
__global__ void topmerge_kernel(const float* __restrict__ topv,
                                const int* __restrict__ topi,
                                uint32_t* __restrict__ Mbits) {
    int i = blockIdx.x * blockDim.x + threadIdx.x;
    if (i >= N_NODES) return;
    const float* v[JSPLIT]; const int* x[JSPLIT]; int ix[JSPLIT];
    #pragma unroll
    for (int q = 0; q < JSPLIT; ++q) {
        v[q] = topv + (size_t)(q * N_NODES + i) * TOPK;
        x[q] = topi + (size_t)(q * N_NODES + i) * TOPK;
        ix[q] = 0;
    }
    #pragma unroll
    for (int k = 0; k < TOPK; ++k) {
        float bestv = -1e38f; int bestj = 0x7fffffff; int bestq = 0;
        #pragma unroll
        for (int q = 0; q < JSPLIT; ++q) {
            bool ok = ix[q] < TOPK;
            float fv = ok ? v[q][ix[q]] : -1e38f;
            int   jj = ok ? x[q][ix[q]] : 0x7fffffff;
            if (fv > bestv || (fv == bestv && jj < bestj)) {
                bestv = fv; bestj = jj; bestq = q;
            }
        }
        ++ix[bestq];
        Mbits[(size_t)i * WPR + (bestj >> 5)] |= 1u << (bestj & 31);
    }
}

// ---- degree per row (after topk forcing) ----------------------------------
__global__ void deg_kernel(const uint32_t* __restrict__ Mbits,
                           float* __restrict__ deg) {
    int i = blockIdx.x;
    int l = threadIdx.x;                 // 64
    const uint32_t* row = Mbits + (size_t)i * WPR;
    int c = __popc(row[l]) + __popc(row[l + 64]);
    #pragma unroll
    for (int off = 32; off >= 1; off >>= 1) c += __shfl_xor(c, off);
    if (l == 0) deg[i] = (float)c;
}

// ---- masked mean via MFMA: fused = (Mf @ agg) / deg -----------------------
__launch_bounds__(512, 2)
__global__ void fused_kernel(const uint32_t* __restrict__ Mbits,
                             const uint16_t* __restrict__ aggTb,
                             const float* __restrict__ deg,
                             float* __restrict__ fused) {
    int i0 = blockIdx.x * 16;
    int t = threadIdx.x;
    int w = t >> 6;
    int lane = t & 63;
    int col = lane & 15;
    int quad = lane >> 4;
    __shared__ float sinv[16];
    if (t < 16) sinv[t] = 1.f / (deg[i0 + t] + 1e-6f);
    __syncthreads();

    const uint32_t* mrow = Mbits + (size_t)(i0 + col) * WPR;
    const uint16_t* brow = aggTb + (size_t)(w * 16 + col) * N_NODES;
    f32x4 acc[4];
    #pragma unroll
    for (int u = 0; u < 4; ++u) acc[u] = (f32x4){0.f, 0.f, 0.f, 0.f};

    for (int k0 = 0; k0 < N_NODES; k0 += 128) {
        uint4 mw4 = *(const uint4*)&mrow[k0 >> 5];
        uint32_t mws[4] = {mw4.x, mw4.y, mw4.z, mw4.w};
        #pragma unroll
        for (int u = 0; u < 4; ++u) {
            uint32_t byte = (mws[u] >> (quad * 8)) & 0xFFu;
            union { uint32_t uu[4]; bf16x8 v; } a;
            #pragma unroll
            for (int pp = 0; pp < 4; ++pp) {
                uint32_t lo = (byte >> (2 * pp)) & 1u;
                uint32_t hi = (byte >> (2 * pp + 1)) & 1u;
                a.uu[pp] = (lo ? 0x3F80u : 0u) | (hi ? 0x3F800000u : 0u);
            }
            bf16x8 b = *(const bf16x8*)&brow[k0 + u * 32 + quad * 8];
            acc[u] = __builtin_amdgcn_mfma_f32_16x16x32_bf16(a.v, b, acc[u], 0, 0, 0);
        }
    }
    #pragma unroll
    for (int r = 0; r < 4; ++r) {
        int il = quad * 4 + r;
        float s = (acc[0][r] + acc[1][r]) + (acc[2][r] + acc[3][r]);
        fused[(size_t)(i0 + il) * C_DIM + w * 16 + col] = s * sinv[il];
    }
}

// ---- h = [x, fused] @ fusion_W + fusion_b (4 rows/block) ------------------
__global__ void fusion_gemm(const float* __restrict__ xf,
                            const float* __restrict__ fused,
                            const float* __restrict__ W,
                            const float* __restrict__ b,
                            float* __restrict__ h) {
    int i0 = blockIdx.x * 4;
    int o = threadIdx.x;                 // 128
    __shared__ float lx[4][256];
    for (int r = o; r < 4 * 128; r += 128) {
        lx[r >> 7][r & 127]         = xf[(size_t)(i0 + (r >> 7)) * C_DIM + (r & 127)];
        lx[r >> 7][128 + (r & 127)] = fused[(size_t)(i0 + (r >> 7)) * C_DIM + (r & 127)];
    }
    __syncthreads();
    float acc[4];
    #pragma unroll
    for (int r = 0; r < 4; ++r) acc[r] = b[o];
    for (int k = 0; k < 256; ++k) {
        float wv = W[k * 128 + o];
        #pragma unroll
        for (int r = 0; r < 4; ++r) acc[r] = fmaf(lx[r][k], wv, acc[r]);
    }
    #pragma unroll
    for (int r = 0; r < 4; ++r) h[(size_t)(i0 + r) * 128 + o] = acc[r];
}

// ---- h1 = relu(h @ lin0_W + lin0_b) (4 rows/block) ------------------------
__global__ void lin0_gemm(const float* __restrict__ h,
                          const float* __restrict__ W,
                          const float* __restrict__ b,
                          float* __restrict__ h1) {
    int i0 = blockIdx.x * 4;
    int o = threadIdx.x;                 // 128
    __shared__ float lx[4][128];
    for (int r = o; r < 4 * 128; r += 128)
        lx[r >> 7][r & 127] = h[(size_t)(i0 + (r >> 7)) * 128 + (r & 127)];
    __syncthreads();
    float acc[4];
    #pragma unroll
    for (int r = 0; r < 4; ++r) acc[r] = b[o];
    for (int k = 0; k < 128; ++k) {
        float wv = W[k * 128 + o];
        #pragma unroll
        for (int r = 0; r < 4; ++r) acc[r] = fmaf(lx[r][k], wv, acc[r]);
    }
    #pragma unroll
    for (int r = 0; r < 4; ++r)
        h1[(size_t)(i0 + r) * 128 + o] = fmaxf(acc[r], 0.f);
}

// ---- out = log_softmax(h1 @ lin1_W + lin1_b) (4 rows/block, 1 wave) -------
__global__ void lin1_lsm(const float* __restrict__ h1,
                         const float* __restrict__ W,
                         const float* __restrict__ b,
                         float* __restrict__ out) {
    int i0 = blockIdx.x * 4;
    int o = threadIdx.x;                 // 64
    __shared__ float lx[4][128];
    for (int r = o; r < 4 * 128; r += 64)
        lx[r >> 7][r & 127] = h1[(size_t)(i0 + (r >> 7)) * 128 + (r & 127)];
    __syncthreads();
    float acc[4];
    #pragma unroll
    for (int r = 0; r < 4; ++r) acc[r] = b[o];
    for (int k = 0; k < 128; ++k) {
        float wv = W[k * 64 + o];
        #pragma unroll
        for (int r = 0; r < 4; ++r) acc[r] = fmaf(lx[r][k], wv, acc[r]);
    }
    #pragma unroll
    for (int r = 0; r < 4; ++r) {
        float m = acc[r];
        #pragma unroll
        for (int off = 32; off >= 1; off >>= 1) m = fmaxf(m, __shfl_xor(m, off));
        float e = expf(acc[r] - m);
        float s = e;
        #pragma unroll
        for (int off = 32; off >= 1; off >>= 1) s += __shfl_xor(s, off);
        out[(size_t)(i0 + r) * 64 + o] = acc[r] - m - logf(s);
    }
}

extern "C" void kernel_launch(void* const* d_in, const int* in_sizes, int n_in,
                              void* d_out, int out_size, void* d_ws, size_t ws_size,
                              hipStream_t stream) {
    const float* xf    = (const float*)d_in[0];
    const int*   ei    = (const int*)d_in[1];
    const float* alpha = (const float*)d_in[2];
    const float* fW    = (const float*)d_in[3];
    const float* fB    = (const float*)d_in[4];
    const float* l0W   = (const float*)d_in[5];
    const float* l0B   = (const float*)d_in[6];
    const float* l1W   = (const float*)d_in[7];
    const float* l1B   = (const float*)d_in[8];
    float* out = (float*)d_out;
    const int E  = in_sizes[1] / 2;     // 65536
    const int NC = N_NODES * C_DIM;     // 524288

    char* p = (char*)d_ws;
    uint32_t* flags = (uint32_t*)p; p += 256;
    const size_t SZ = (size_t)NC * 4;   // 2 MB
    uint32_t* Abits = (uint32_t*)p; p += SZ;
    float*    hop1  = (float*)p;    p += SZ;
    float*    agg   = (float*)p;    p += SZ;
    uint32_t* Mbits = (uint32_t*)p; p += SZ;
    float*    fusd  = (float*)p;    p += SZ;
    float*    h     = (float*)p;    p += SZ;
    float*    h1    = (float*)p;    p += SZ;
    uint16_t* xnb   = (uint16_t*)p; p += SZ / 2;   // 1 MB bf16
    uint16_t* aggTb = (uint16_t*)p; p += SZ / 2;   // 1 MB bf16
    float*    deg   = (float*)p;    p += N_NODES * 4;
    float*    topv  = (float*)p;    p += (size_t)JSPLIT * N_NODES * TOPK * 4;
    int*      topi  = (int*)p;      p += (size_t)JSPLIT * N_NODES * TOPK * 4;

    hipMemsetAsync(Abits, 0, SZ, stream);
    detect_kernel<<<1, 256, 0, stream>>>((const uint32_t*)ei, flags);
    scatter_kernel<<<(E + 255) / 256, 256, 0, stream>>>(ei, E, Abits, flags);
    spmm_kernel<<<N_NODES, 128, 0, stream>>>(Abits, xf, hop1);
    spmm2_agg_kernel<<<N_NODES, 128, 0, stream>>>(Abits, hop1, xf, alpha, agg);
    norm_kernel<<<N_NODES, 128, 0, stream>>>(xf, xnb);
    transpose_bf_kernel<<<dim3(128, 4), 256, 0, stream>>>(agg, aggTb);
    mask_kernel<<<(HALF_P >> 5) / 256, 256, 0, stream>>>(Mbits);
    topk_kernel<<<dim3(N_NODES / 16, JSPLIT), 512, 0, stream>>>(xnb, topv, topi);
    topmerge_kernel<<<N_NODES / 256, 256, 0, stream>>>(topv, topi, Mbits);
    deg_kernel<<<N_NODES, 64, 0, stream>>>(Mbits, deg);
    fused_kernel<<<N_NODES / 16, 512, 0, stream>>>(Mbits, aggTb, deg, fusd);
    fusion_gemm<<<N_NODES / 4, 128, 0, stream>>>(xf, fusd, fW, fB, h);
    lin0_gemm<<<N_NODES / 4, 128, 0, stream>>>(h, l0W, l0B, h1);
    lin1_lsm<<<N_NODES / 4, 64, 0, stream>>>(h1, l1W, l1B, out);
}

// Round 10
// 257.528 us; speedup vs baseline: 5.3801x; 1.0440x over previous
//
#include <hip/hip_runtime.h>
#include <hip/hip_bf16.h>
#include <stdint.h>

// ScaleGNN on MI355X (gfx950). fp32 in / fp32 out. edge_index int32/int64
// auto-detect (folded into scatter). Mask = JAX threefry2x32 key(42) exact.
// R10: topk merge stride 11 (bank-conflict-free) + 2-tile MFMA ILP;
//      launch fusion: detect->scatter, deg->mask+topmerge, MLP fused;
//      fused_kernel K-split x2 with partial combine in MLP.

#define N_NODES 4096
#define C_DIM   128
#define WPR     128        // bitmask words per row (4096/32)
#define HALF_P  8388608u   // N*N/2
#define TOPK    10
#define LSTR    11         // LDS list stride (gcd(11,32)=1 -> conflict-free)
#define JSPLIT  4

typedef __attribute__((ext_vector_type(8))) short bf16x8;   // 8 bf16 = 4 VGPRs
typedef __attribute__((ext_vector_type(4))) float f32x4;    // MFMA C/D

__device__ __forceinline__ uint16_t f2bf(float f) {         // RNE fp32->bf16
    uint32_t u = __float_as_uint(f);
    return (uint16_t)((u + 0x7FFFu + ((u >> 16) & 1u)) >> 16);
}

__device__ __forceinline__ uint32_t rotl32(uint32_t v, int r) {
    return (v << r) | (v >> (32 - r));
}

__device__ __forceinline__ void threefry2x32(uint32_t k0, uint32_t k1,
                                             uint32_t x0, uint32_t x1,
                                             uint32_t& o0, uint32_t& o1) {
    uint32_t ks2 = k0 ^ k1 ^ 0x1BD11BDAu;
    x0 += k0; x1 += k1;
#define TF_ROUND(r) { x0 += x1; x1 = rotl32(x1, (r)); x1 ^= x0; }
    TF_ROUND(13) TF_ROUND(15) TF_ROUND(26) TF_ROUND(6)
    x0 += k1;  x1 += ks2 + 1u;
    TF_ROUND(17) TF_ROUND(29) TF_ROUND(16) TF_ROUND(24)
    x0 += ks2; x1 += k0 + 2u;
    TF_ROUND(13) TF_ROUND(15) TF_ROUND(26) TF_ROUND(6)
    x0 += k0;  x1 += k1 + 3u;
    TF_ROUND(17) TF_ROUND(29) TF_ROUND(16) TF_ROUND(24)
    x0 += k1;  x1 += ks2 + 4u;
    TF_ROUND(13) TF_ROUND(15) TF_ROUND(26) TF_ROUND(6)
    x0 += ks2; x1 += k0 + 5u;
#undef TF_ROUND
    o0 = x0; o1 = x1;
}

// ---- scatter edges (int64/int32 detected per block) -----------------------
__global__ void scatter_kernel(const int* __restrict__ ei, int E,
                               uint32_t* __restrict__ Abits) {
    __shared__ int cnt_oddnz;
    int t = threadIdx.x;
    if (t == 0) cnt_oddnz = 0;
    __syncthreads();
    // first 512 ints are safe to read under either dtype
    if (((const uint32_t*)ei)[2 * t + 1] != 0u) atomicAdd(&cnt_oddnz, 1);
    __syncthreads();
    bool is64 = (cnt_oddnz <= 8);        // int64 => high words all zero
    int e = blockIdx.x * blockDim.x + t;
    if (e >= E) return;
    int src, dst;
    if (is64) { src = ei[2 * e]; dst = ei[2 * (E + e)]; }
    else      { src = ei[e];     dst = ei[E + e]; }
    src &= (N_NODES - 1);
    dst &= (N_NODES - 1);
    atomicOr(&Abits[src * WPR + (dst >> 5)], 1u << (dst & 31));
}

// ---- SpMM: hop1[i,:] = sum_{j in bits(i)} x[j,:] --------------------------
__global__ void spmm_kernel(const uint32_t* __restrict__ Abits,
                            const float* __restrict__ in,
                            float* __restrict__ out) {
    int i = blockIdx.x;
    int c = threadIdx.x;                 // 128
    __shared__ uint32_t wbits[WPR];
    wbits[c] = Abits[i * WPR + c];
    __syncthreads();
    float acc = 0.f;
    for (int w = 0; w < WPR; ++w) {
        uint32_t bits = wbits[w];
        while (bits) {
            int b = __ffs(bits) - 1;
            bits &= bits - 1;
            acc += in[(w * 32 + b) * C_DIM + c];
        }
    }
    out[i * C_DIM + c] = acc;
}

// ---- SpMM2 + agg: agg = a0*x + a1*hop1 + a2*(A@hop1) ----------------------
__global__ void spmm2_agg_kernel(const uint32_t* __restrict__ Abits,
                                 const float* __restrict__ hop1,
                                 const float* __restrict__ xf,
                                 const float* __restrict__ alpha,
                                 float* __restrict__ agg) {
    int i = blockIdx.x;
    int c = threadIdx.x;                 // 128
    __shared__ uint32_t wbits[WPR];
    wbits[c] = Abits[i * WPR + c];
    __syncthreads();
    float acc = 0.f;
    for (int w = 0; w < WPR; ++w) {
        uint32_t bits = wbits[w];
        while (bits) {
            int b = __ffs(bits) - 1;
            bits &= bits - 1;
            acc += hop1[(w * 32 + b) * C_DIM + c];
        }
    }
    agg[i * C_DIM + c] = alpha[0] * xf[i * C_DIM + c]
                       + alpha[1] * hop1[i * C_DIM + c]
                       + alpha[2] * acc;
}

// ---- row-normalize into bf16: xnb = bf16(x / (||x|| + 1e-8)) --------------
__global__ void norm_kernel(const float* __restrict__ xf,
                            uint16_t* __restrict__ xnb) {
    int i = blockIdx.x;
    int c = threadIdx.x;                 // 128
    float v = xf[i * C_DIM + c];
    float sq = v * v;
    #pragma unroll
    for (int off = 32; off >= 1; off >>= 1) sq += __shfl_xor(sq, off);
    __shared__ float ws[2];
    if ((c & 63) == 0) ws[c >> 6] = sq;
    __syncthreads();
    float tot = ws[0] + ws[1];
    xnb[i * C_DIM + c] = f2bf(v / (sqrtf(tot) + 1e-8f));
}

// ---- transpose agg fp32 [4096][128] -> aggTb bf16 [128][4096] -------------
__global__ void transpose_bf_kernel(const float* __restrict__ agg,
                                    uint16_t* __restrict__ aggTb) {
    __shared__ float tile[32][33];
    int bi = blockIdx.x;                 // j tile (128)
    int bc = blockIdx.y;                 // c tile (4)
    int tx = threadIdx.x & 31, ty = threadIdx.x >> 5;   // 256 thr
    #pragma unroll
    for (int r = 0; r < 32; r += 8)
        tile[ty + r][tx] = agg[(size_t)(bi * 32 + ty + r) * C_DIM + bc * 32 + tx];
    __syncthreads();
    #pragma unroll
    for (int r = 0; r < 32; r += 8)
        aggTb[(size_t)(bc * 32 + ty + r) * N_NODES + bi * 32 + tx] =
            f2bf(tile[tx][ty + r]);
}

// ---- threefry mask + per-row popcount (degpre) ----------------------------
// Word tid covers row tid>>7 (w0) and row 2048+(tid>>7) (w1); each 64-lane
// wave spans 64 consecutive tids => row is wave-uniform.
__global__ void mask_kernel(uint32_t* __restrict__ Mbits,
                            int* __restrict__ degpre) {
    uint32_t tid = blockIdx.x * blockDim.x + threadIdx.x;  // < 262144
    uint32_t base = tid * 32u;
    uint32_t w0 = 0u, w1 = 0u;
    for (int k = 0; k < 32; ++k) {
        uint32_t o0, o1;
        threefry2x32(0u, 42u, base + k, HALF_P + base + k, o0, o1);
        w0 |= (uint32_t)((o0 >> 31) ^ 1u) << k;
        w1 |= (uint32_t)((o1 >> 31) ^ 1u) << k;
    }
    Mbits[tid] = w0;
    Mbits[(HALF_P >> 5) + tid] = w1;
    int p0 = __popc(w0), p1 = __popc(w1);
    #pragma unroll
    for (int off = 32; off >= 1; off >>= 1) {
        p0 += __shfl_xor(p0, off);
        p1 += __shfl_xor(p1, off);
    }
    if ((threadIdx.x & 63) == 0) {
        int row0 = (int)(tid >> 7);      // wave-uniform
        atomicAdd(&degpre[row0], p0);
        atomicAdd(&degpre[2048 + row0], p1);
    }
}

// ---- topk via MFMA, register-direct scan, j split 4 ways, 2-tile ILP ------
__launch_bounds__(512, 3)
__global__ void topk_kernel(const uint16_t* __restrict__ xnb,
                            float* __restrict__ topv,
                            int* __restrict__ topi) {
    int i0 = blockIdx.x * 16;
    int part = blockIdx.y;               // 0..3
    int t = threadIdx.x;
    int w = t >> 6;                      // wave 0..7
    int lane = t & 63;
    int col = lane & 15;
    int quad = lane >> 4;                // 0..3

    __shared__ float sval[16 * 32 * LSTR];
    __shared__ int   sidx[16 * 32 * LSTR];

    // B-frag: the block's 16 i-rows (loaded once)
    bf16x8 bfi[4];
    #pragma unroll
    for (int s = 0; s < 4; ++s)
        bfi[s] = *(const bf16x8*)&xnb[(size_t)(i0 + col) * C_DIM + s * 32 + quad * 8];

    float tv[TOPK]; int ti[TOPK];
    #pragma unroll
    for (int k = 0; k < TOPK; ++k) { tv[k] = -1e30f; ti[k] = 0x7fffffff; }

    int jt0 = part * 64 + w * 8;
    for (int p = 0; p < 4; ++p) {
        int j0a = (jt0 + 2 * p) * 16;
        int j0b = j0a + 16;
        f32x4 acc0 = {0.f, 0.f, 0.f, 0.f};
        f32x4 acc1 = {0.f, 0.f, 0.f, 0.f};
        #pragma unroll
        for (int s = 0; s < 4; ++s) {
            bf16x8 aj0 = *(const bf16x8*)&xnb[(size_t)(j0a + col) * C_DIM + s * 32 + quad * 8];
            bf16x8 aj1 = *(const bf16x8*)&xnb[(size_t)(j0b + col) * C_DIM + s * 32 + quad * 8];
            acc0 = __builtin_amdgcn_mfma_f32_16x16x32_bf16(aj0, bfi[s], acc0, 0, 0, 0);
            acc1 = __builtin_amdgcn_mfma_f32_16x16x32_bf16(aj1, bfi[s], acc1, 0, 0, 0);
        }
        // lane holds sim[j0+quad*4+r][i0+col]; scan tile a then b (j asc)
        #pragma unroll
        for (int g = 0; g < 2; ++g) {
            f32x4 acc = g ? acc1 : acc0;
            int j0 = g ? j0b : j0a;
            float m4 = fmaxf(fmaxf(acc[0], acc[1]), fmaxf(acc[2], acc[3]));
            if (m4 > tv[TOPK-1]) {
                #pragma unroll
                for (int r = 0; r < 4; ++r) {
                    float d = acc[r];
                    if (d > tv[TOPK-1]) {    // strict > keeps earliest j
                        int j = j0 + quad * 4 + r;
                        tv[TOPK-1] = d; ti[TOPK-1] = j;
                        #pragma unroll
                        for (int q = TOPK - 2; q >= 0; --q) {
                            if (tv[q+1] > tv[q]) {
                                float fv = tv[q]; tv[q] = tv[q+1]; tv[q+1] = fv;
                                int iv = ti[q];  ti[q] = ti[q+1];  ti[q+1] = iv;
                            }
                        }
                    }
                }
            }
        }
    }

    // lists: [row=col][L][LSTR], L = w*4 + quad (32 lists per row)
    int base = (col * 32 + w * 4 + quad) * LSTR;
    #pragma unroll
    for (int k = 0; k < TOPK; ++k) { sval[base + k] = tv[k]; sidx[base + k] = ti[k]; }

    int row = t >> 5, L = t & 31;
    for (int s = 16; s >= 1; s >>= 1) {
        __syncthreads();
        if (L < s) {
            int la = (row * 32 + L) * LSTR;
            int lb = (row * 32 + L + s) * LSTR;
            float ov[TOPK]; int oi[TOPK];
            int ia = 0, ib = 0;
            #pragma unroll
            for (int k = 0; k < TOPK; ++k) {
                float va = sval[la + ia], vb = sval[lb + ib];
                int   xa = sidx[la + ia], xb = sidx[lb + ib];
                bool takeA = (va > vb) || (va == vb && xa < xb);
                if (takeA) { ov[k] = va; oi[k] = xa; ++ia; }
                else       { ov[k] = vb; oi[k] = xb; ++ib; }
            }
            #pragma unroll
            for (int k = 0; k < TOPK; ++k) { sval[la + k] = ov[k]; sidx[la + k] = oi[k]; }
        }
    }
    __syncthreads();
    if (t < 16) {
        size_t gi = (size_t)(part * N_NODES + i0 + t) * TOPK;
        #pragma unroll
        for (int k = 0; k < TOPK; ++k) {
            topv[gi + k] = sval[(t * 32) * LSTR + k];
            topi[gi + k] = sidx[(t * 32) * LSTR + k];
        }
    }
}

// ---- 4-way merge of sorted quarter lists; OR bits; final deg --------------
__global__ void topmerge_kernel(const float* __restrict__ topv,
                                const int* __restrict__ topi,
                                const int* __restrict__ degpre,
                                uint32_t* __restrict__ Mbits,
                                float* __restrict__ deg) {
    int i = blockIdx.x * blockDim.x + threadIdx.x;
    if (i >= N_NODES) return;
    const float* v[JSPLIT]; const int* x[JSPLIT]; int ix[JSPLIT];
    #pragma unroll
    for (int q = 0; q < JSPLIT; ++q) {
        v[q] = topv + (size_t)(q * N_NODES + i) * TOPK;
        x[q] = topi + (size_t)(q * N_NODES + i) * TOPK;
        ix[q] = 0;
    }
    int newc = 0;
    #pragma unroll
    for (int k = 0; k < TOPK; ++k) {
        float bestv = -1e38f; int bestj = 0x7fffffff; int bestq = 0;
        #pragma unroll
        for (int q = 0; q < JSPLIT; ++q) {
            bool ok = ix[q] < TOPK;
            float fv = ok ? v[q][ix[q]] : -1e38f;
            int   jj = ok ? x[q][ix[q]] : 0x7fffffff;
            if (fv > bestv || (fv == bestv && jj < bestj)) {
                bestv = fv; bestj = jj; bestq = q;
            }
        }
        ++ix[bestq];
        uint32_t* wp = &Mbits[(size_t)i * WPR + (bestj >> 5)];
        uint32_t old = *wp, bit = 1u << (bestj & 31);
        newc += ((old & bit) == 0u);
        *wp = old | bit;                 // row-exclusive, serial in-thread
    }
    deg[i] = (float)(degpre[i] + newc);
}

// ---- masked mean partials via MFMA, K split x2 ----------------------------
// grid (256, 2): part p covers k in [p*2048, p*2048+2048). No scaling here.
__launch_bounds__(512, 2)
__global__ void fused_kernel(const uint32_t* __restrict__ Mbits,
                             const uint16_t* __restrict__ aggTb,
                             float* __restrict__ fpart) {
    int i0 = blockIdx.x * 16;
    int part = blockIdx.y;
    int t = threadIdx.x;
    int w = t >> 6;
    int lane = t & 63;
    int col = lane & 15;
    int quad = lane >> 4;

    const uint32_t* mrow = Mbits + (size_t)(i0 + col) * WPR;
    const uint16_t* brow = aggTb + (size_t)(w * 16 + col) * N_NODES;
    f32x4 acc[4];
    #pragma unroll
    for (int u = 0; u < 4; ++u) acc[u] = (f32x4){0.f, 0.f, 0.f, 0.f};

    int kbase = part * 2048;
    for (int k0 = kbase; k0 < kbase + 2048; k0 += 128) {
        uint4 mw4 = *(const uint4*)&mrow[k0 >> 5];
        uint32_t mws[4] = {mw4.x, mw4.y, mw4.z, mw4.w};
        #pragma unroll
        for (int u = 0; u < 4; ++u) {
            uint32_t byte = (mws[u] >> (quad * 8)) & 0xFFu;
            union { uint32_t uu[4]; bf16x8 v; } a;
            #pragma unroll
            for (int pp = 0; pp < 4; ++pp) {
                uint32_t lo = (byte >> (2 * pp)) & 1u;
                uint32_t hi = (byte >> (2 * pp + 1)) & 1u;
                a.uu[pp] = (lo ? 0x3F80u : 0u) | (hi ? 0x3F800000u : 0u);
            }
            bf16x8 b = *(const bf16x8*)&brow[k0 + u * 32 + quad * 8];
            acc[u] = __builtin_amdgcn_mfma_f32_16x16x32_bf16(a.v, b, acc[u], 0, 0, 0);
        }
    }
    #pragma unroll
    for (int r = 0; r < 4; ++r) {
        int il = quad * 4 + r;
        float s = (acc[0][r] + acc[1][r]) + (acc[2][r] + acc[3][r]);
        fpart[(size_t)part * (N_NODES * C_DIM)
              + (size_t)(i0 + il) * C_DIM + w * 16 + col] = s;
    }
}

// ---- fused MLP: h=[x,fused]@fW+fB; h1=relu(h@l0W+l0B); out=lsm(h1@l1W+l1B)
// block = 4 rows, 128 threads (2 waves).
__global__ void mlp_kernel(const float* __restrict__ xf,
                           const float* __restrict__ fpart,
                           const float* __restrict__ deg,
                           const float* __restrict__ fW, const float* __restrict__ fB,
                           const float* __restrict__ l0W, const float* __restrict__ l0B,
                           const float* __restrict__ l1W, const float* __restrict__ l1B,
                           float* __restrict__ out) {
    int i0 = blockIdx.x * 4;
    int t = threadIdx.x;                 // 128
    __shared__ float lx[4][256];
    __shared__ float hb[4][128];
    const float* f0 = fpart;
    const float* f1 = fpart + (size_t)N_NODES * C_DIM;
    for (int r = t; r < 4 * 128; r += 128) {
        int row = r >> 7, c = r & 127;
        size_t idx = (size_t)(i0 + row) * C_DIM + c;
        lx[row][c] = xf[idx];
        lx[row][128 + c] = (f0[idx] + f1[idx]) / (deg[i0 + row] + 1e-6f);
    }
    __syncthreads();
    float acc[4];
    #pragma unroll
    for (int r = 0; r < 4; ++r) acc[r] = fB[t];
    for (int k = 0; k < 256; ++k) {
        float wv = fW[k * 128 + t];
        #pragma unroll
        for (int r = 0; r < 4; ++r) acc[r] = fmaf(lx[r][k], wv, acc[r]);
    }
    #pragma unroll
    for (int r = 0; r < 4; ++r) hb[r][t] = acc[r];
    __syncthreads();
    #pragma unroll
    for (int r = 0; r < 4; ++r) acc[r] = l0B[t];
    for (int k = 0; k < 128; ++k) {
        float wv = l0W[k * 128 + t];
        #pragma unroll
        for (int r = 0; r < 4; ++r) acc[r] = fmaf(hb[r][k], wv, acc[r]);
    }
    __syncthreads();                     // lx no longer needed as input
    #pragma unroll
    for (int r = 0; r < 4; ++r) lx[r][t] = fmaxf(acc[r], 0.f);   // h1
    __syncthreads();
    int o = t & 63, pr = t >> 6;         // wave 0: rows 0,2; wave 1: rows 1,3
    #pragma unroll
    for (int rr = 0; rr < 2; ++rr) {
        int r = pr + 2 * rr;
        float a = l1B[o];
        for (int k = 0; k < 128; ++k)
            a = fmaf(lx[r][k], l1W[k * 64 + o], a);
        float m = a;
        #pragma unroll
        for (int off = 32; off >= 1; off >>= 1) m = fmaxf(m, __shfl_xor(m, off));
        float e = expf(a - m);
        float s = e;
        #pragma unroll
        for (int off = 32; off >= 1; off >>= 1) s += __shfl_xor(s, off);
        out[(size_t)(i0 + r) * 64 + o] = a - m - logf(s);
    }
}

extern "C" void kernel_launch(void* const* d_in, const int* in_sizes, int n_in,
                              void* d_out, int out_size, void* d_ws, size_t ws_size,
                              hipStream_t stream) {
    const float* xf    = (const float*)d_in[0];
    const int*   ei    = (const int*)d_in[1];
    const float* alpha = (const float*)d_in[2];
    const float* fW    = (const float*)d_in[3];
    const float* fB    = (const float*)d_in[4];
    const float* l0W   = (const float*)d_in[5];
    const float* l0B   = (const float*)d_in[6];
    const float* l1W   = (const float*)d_in[7];
    const float* l1B   = (const float*)d_in[8];
    float* out = (float*)d_out;
    const int E  = in_sizes[1] / 2;     // 65536
    const int NC = N_NODES * C_DIM;     // 524288

    char* p = (char*)d_ws;
    const size_t SZ = (size_t)NC * 4;   // 2 MB
    uint32_t* Abits  = (uint32_t*)p; p += SZ;
    int*      degpre = (int*)p;      p += N_NODES * 4;   // contiguous w/ Abits
    float*    hop1   = (float*)p;    p += SZ;
    float*    agg    = (float*)p;    p += SZ;
    uint32_t* Mbits  = (uint32_t*)p; p += SZ;
    float*    fpart  = (float*)p;    p += 2 * SZ;        // two K-half partials
    uint16_t* xnb    = (uint16_t*)p; p += SZ / 2;
    uint16_t* aggTb  = (uint16_t*)p; p += SZ / 2;
    float*    deg    = (float*)p;    p += N_NODES * 4;
    float*    topv   = (float*)p;    p += (size_t)JSPLIT * N_NODES * TOPK * 4;
    int*      topi   = (int*)p;      p += (size_t)JSPLIT * N_NODES * TOPK * 4;

    hipMemsetAsync(Abits, 0, SZ + N_NODES * 4, stream);  // Abits + degpre
    scatter_kernel<<<(E + 255) / 256, 256, 0, stream>>>(ei, E, Abits);
    spmm_kernel<<<N_NODES, 128, 0, stream>>>(Abits, xf, hop1);
    spmm2_agg_kernel<<<N_NODES, 128, 0, stream>>>(Abits, hop1, xf, alpha, agg);
    norm_kernel<<<N_NODES, 128, 0, stream>>>(xf, xnb);
    transpose_bf_kernel<<<dim3(128, 4), 256, 0, stream>>>(agg, aggTb);
    mask_kernel<<<(HALF_P >> 5) / 256, 256, 0, stream>>>(Mbits, degpre);
    topk_kernel<<<dim3(N_NODES / 16, JSPLIT), 512, 0, stream>>>(xnb, topv, topi);
    topmerge_kernel<<<N_NODES / 256, 256, 0, stream>>>(topv, topi, degpre, Mbits, deg);
    fused_kernel<<<dim3(N_NODES / 16, 2), 512, 0, stream>>>(Mbits, aggTb, fpart);
    mlp_kernel<<<N_NODES / 4, 128, 0, stream>>>(xf, fpart, deg,
                                                fW, fB, l0W, l0B, l1W, l1B, out);
}

// Round 11
// 250.703 us; speedup vs baseline: 5.5265x; 1.0272x over previous
//
#include <hip/hip_runtime.h>
#include <hip/hip_bf16.h>
#include <stdint.h>

// ScaleGNN on MI355X (gfx950). fp32 in / fp32 out. edge_index int32/int64
// auto-detect (folded into scatter). Mask = JAX threefry2x32 key(42) exact.
// R11: topk reverted to R9 loop (1-tile, 4 blocks/CU) + transposed LDS list
//      layout (list = L*16+row, stride 13, uint16 idx) -> 2-way max banking,
//      39.9KB LDS. Tail fusions from R10 kept.

#define N_NODES 4096
#define C_DIM   128
#define WPR     128        // bitmask words per row (4096/32)
#define HALF_P  8388608u   // N*N/2
#define TOPK    10
#define LSTR    13         // list stride; (16L + 13c) mod 32 covers all banks
#define JSPLIT  4

typedef __attribute__((ext_vector_type(8))) short bf16x8;   // 8 bf16 = 4 VGPRs
typedef __attribute__((ext_vector_type(4))) float f32x4;    // MFMA C/D

__device__ __forceinline__ uint16_t f2bf(float f) {         // RNE fp32->bf16
    uint32_t u = __float_as_uint(f);
    return (uint16_t)((u + 0x7FFFu + ((u >> 16) & 1u)) >> 16);
}

__device__ __forceinline__ uint32_t rotl32(uint32_t v, int r) {
    return (v << r) | (v >> (32 - r));
}

__device__ __forceinline__ void threefry2x32(uint32_t k0, uint32_t k1,
                                             uint32_t x0, uint32_t x1,
                                             uint32_t& o0, uint32_t& o1) {
    uint32_t ks2 = k0 ^ k1 ^ 0x1BD11BDAu;
    x0 += k0; x1 += k1;
#define TF_ROUND(r) { x0 += x1; x1 = rotl32(x1, (r)); x1 ^= x0; }
    TF_ROUND(13) TF_ROUND(15) TF_ROUND(26) TF_ROUND(6)
    x0 += k1;  x1 += ks2 + 1u;
    TF_ROUND(17) TF_ROUND(29) TF_ROUND(16) TF_ROUND(24)
    x0 += ks2; x1 += k0 + 2u;
    TF_ROUND(13) TF_ROUND(15) TF_ROUND(26) TF_ROUND(6)
    x0 += k0;  x1 += k1 + 3u;
    TF_ROUND(17) TF_ROUND(29) TF_ROUND(16) TF_ROUND(24)
    x0 += k1;  x1 += ks2 + 4u;
    TF_ROUND(13) TF_ROUND(15) TF_ROUND(26) TF_ROUND(6)
    x0 += ks2; x1 += k0 + 5u;
#undef TF_ROUND
    o0 = x0; o1 = x1;
}

// ---- scatter edges (int64/int32 detected per block) -----------------------
__global__ void scatter_kernel(const int* __restrict__ ei, int E,
                               uint32_t* __restrict__ Abits) {
    __shared__ int cnt_oddnz;
    int t = threadIdx.x;
    if (t == 0) cnt_oddnz = 0;
    __syncthreads();
    if (((const uint32_t*)ei)[2 * t + 1] != 0u) atomicAdd(&cnt_oddnz, 1);
    __syncthreads();
    bool is64 = (cnt_oddnz <= 8);        // int64 => high words all zero
    int e = blockIdx.x * blockDim.x + t;
    if (e >= E) return;
    int src, dst;
    if (is64) { src = ei[2 * e]; dst = ei[2 * (E + e)]; }
    else      { src = ei[e];     dst = ei[E + e]; }
    src &= (N_NODES - 1);
    dst &= (N_NODES - 1);
    atomicOr(&Abits[src * WPR + (dst >> 5)], 1u << (dst & 31));
}

// ---- SpMM: hop1[i,:] = sum_{j in bits(i)} x[j,:] --------------------------
__global__ void spmm_kernel(const uint32_t* __restrict__ Abits,
                            const float* __restrict__ in,
                            float* __restrict__ out) {
    int i = blockIdx.x;
    int c = threadIdx.x;                 // 128
    __shared__ uint32_t wbits[WPR];
    wbits[c] = Abits[i * WPR + c];
    __syncthreads();
    float acc = 0.f;
    for (int w = 0; w < WPR; ++w) {
        uint32_t bits = wbits[w];
        while (bits) {
            int b = __ffs(bits) - 1;
            bits &= bits - 1;
            acc += in[(w * 32 + b) * C_DIM + c];
        }
    }
    out[i * C_DIM + c] = acc;
}

// ---- SpMM2 + agg: agg = a0*x + a1*hop1 + a2*(A@hop1) ----------------------
__global__ void spmm2_agg_kernel(const uint32_t* __restrict__ Abits,
                                 const float* __restrict__ hop1,
                                 const float* __restrict__ xf,
                                 const float* __restrict__ alpha,
                                 float* __restrict__ agg) {
    int i = blockIdx.x;
    int c = threadIdx.x;                 // 128
    __shared__ uint32_t wbits[WPR];
    wbits[c] = Abits[i * WPR + c];
    __syncthreads();
    float acc = 0.f;
    for (int w = 0; w < WPR; ++w) {
        uint32_t bits = wbits[w];
        while (bits) {
            int b = __ffs(bits) - 1;
            bits &= bits - 1;
            acc += hop1[(w * 32 + b) * C_DIM + c];
        }
    }
    agg[i * C_DIM + c] = alpha[0] * xf[i * C_DIM + c]
                       + alpha[1] * hop1[i * C_DIM + c]
                       + alpha[2] * acc;
}

// ---- row-normalize into bf16: xnb = bf16(x / (||x|| + 1e-8)) --------------
__global__ void norm_kernel(const float* __restrict__ xf,
                            uint16_t* __restrict__ xnb) {
    int i = blockIdx.x;
    int c = threadIdx.x;                 // 128
    float v = xf[i * C_DIM + c];
    float sq = v * v;
    #pragma unroll
    for (int off = 32; off >= 1; off >>= 1) sq += __shfl_xor(sq, off);
    __shared__ float ws[2];
    if ((c & 63) == 0) ws[c >> 6] = sq;
    __syncthreads();
    float tot = ws[0] + ws[1];
    xnb[i * C_DIM + c] = f2bf(v / (sqrtf(tot) + 1e-8f));
}

// ---- transpose agg fp32 [4096][128] -> aggTb bf16 [128][4096] -------------
__global__ void transpose_bf_kernel(const float* __restrict__ agg,
                                    uint16_t* __restrict__ aggTb) {
    __shared__ float tile[32][33];
    int bi = blockIdx.x;                 // j tile (128)
    int bc = blockIdx.y;                 // c tile (4)
    int tx = threadIdx.x & 31, ty = threadIdx.x >> 5;   // 256 thr
    #pragma unroll
    for (int r = 0; r < 32; r += 8)
        tile[ty + r][tx] = agg[(size_t)(bi * 32 + ty + r) * C_DIM + bc * 32 + tx];
    __syncthreads();
    #pragma unroll
    for (int r = 0; r < 32; r += 8)
        aggTb[(size_t)(bc * 32 + ty + r) * N_NODES + bi * 32 + tx] =
            f2bf(tile[tx][ty + r]);
}

// ---- threefry mask + per-row popcount (degpre) ----------------------------
__global__ void mask_kernel(uint32_t* __restrict__ Mbits,
                            int* __restrict__ degpre) {
    uint32_t tid = blockIdx.x * blockDim.x + threadIdx.x;  // < 262144
    uint32_t base = tid * 32u;
    uint32_t w0 = 0u, w1 = 0u;
    for (int k = 0; k < 32; ++k) {
        uint32_t o0, o1;
        threefry2x32(0u, 42u, base + k, HALF_P + base + k, o0, o1);
        w0 |= (uint32_t)((o0 >> 31) ^ 1u) << k;
        w1 |= (uint32_t)((o1 >> 31) ^ 1u) << k;
    }
    Mbits[tid] = w0;
    Mbits[(HALF_P >> 5) + tid] = w1;
    int p0 = __popc(w0), p1 = __popc(w1);
    #pragma unroll
    for (int off = 32; off >= 1; off >>= 1) {
        p0 += __shfl_xor(p0, off);
        p1 += __shfl_xor(p1, off);
    }
    if ((threadIdx.x & 63) == 0) {
        int row0 = (int)(tid >> 7);      // wave-uniform
        atomicAdd(&degpre[row0], p0);
        atomicAdd(&degpre[2048 + row0], p1);
    }
}

// ---- topk via MFMA, register-direct scan, j split 4 ways ------------------
// grid (256, 4). Transposed list layout: list = L*16+row, stride LSTR=13,
// idx as uint16 -> 39.9KB LDS (4 blocks/CU), 2-way max bank aliasing.
__launch_bounds__(512, 4)
__global__ void topk_kernel(const uint16_t* __restrict__ xnb,
                            float* __restrict__ topv,
                            int* __restrict__ topi) {
    int i0 = blockIdx.x * 16;
    int part = blockIdx.y;               // 0..3
    int t = threadIdx.x;
    int w = t >> 6;                      // wave 0..7
    int lane = t & 63;
    int col = lane & 15;
    int quad = lane >> 4;                // 0..3

    __shared__ float    sval[32 * 16 * LSTR];
    __shared__ uint16_t sidx[32 * 16 * LSTR];

    // B-frag: the block's 16 i-rows (loaded once)
    bf16x8 bfi[4];
    #pragma unroll
    for (int s = 0; s < 4; ++s)
        bfi[s] = *(const bf16x8*)&xnb[(size_t)(i0 + col) * C_DIM + s * 32 + quad * 8];

    float tv[TOPK]; int ti[TOPK];
    #pragma unroll
    for (int k = 0; k < TOPK; ++k) { tv[k] = -1e30f; ti[k] = 0xFFFF; }

    int jt0 = part * 64 + w * 8;
    for (int p = 0; p < 8; ++p) {
        int j0 = (jt0 + p) * 16;
        f32x4 acc = {0.f, 0.f, 0.f, 0.f};
        #pragma unroll
        for (int s = 0; s < 4; ++s) {
            bf16x8 aj = *(const bf16x8*)&xnb[(size_t)(j0 + col) * C_DIM + s * 32 + quad * 8];
            acc = __builtin_amdgcn_mfma_f32_16x16x32_bf16(aj, bfi[s], acc, 0, 0, 0);
        }
        // lane holds sim[j0+quad*4+r][i0+col], r=0..3, j ascending
        float m4 = fmaxf(fmaxf(acc[0], acc[1]), fmaxf(acc[2], acc[3]));
        if (m4 > tv[TOPK-1]) {
            #pragma unroll
            for (int r = 0; r < 4; ++r) {
                float d = acc[r];
                if (d > tv[TOPK-1]) {    // strict > keeps earliest j
                    int j = j0 + quad * 4 + r;
                    tv[TOPK-1] = d; ti[TOPK-1] = j;
                    #pragma unroll
                    for (int q = TOPK - 2; q >= 0; --q) {
                        if (tv[q+1] > tv[q]) {
                            float fv = tv[q]; tv[q] = tv[q+1]; tv[q+1] = fv;
                            int iv = ti[q];  ti[q] = ti[q+1];  ti[q+1] = iv;
                        }
                    }
                }
            }
        }
    }

    // store lists: list id = L*16 + row, L = w*4+quad, row = col
    int base = ((w * 4 + quad) * 16 + col) * LSTR;
    #pragma unroll
    for (int k = 0; k < TOPK; ++k) {
        sval[base + k] = tv[k];
        sidx[base + k] = (uint16_t)ti[k];
    }

    // tree-merge 32 lists per row; thread: row = t&15, L = t>>4
    int row = t & 15, L = t >> 4;
    for (int s = 16; s >= 1; s >>= 1) {
        __syncthreads();
        if (L < s) {
            int la = (L * 16 + row) * LSTR;
            int lb = ((L + s) * 16 + row) * LSTR;
            float ov[TOPK]; uint16_t oi[TOPK];
            int ia = 0, ib = 0;
            #pragma unroll
            for (int k = 0; k < TOPK; ++k) {
                float va = sval[la + ia], vb = sval[lb + ib];
                uint16_t xa = sidx[la + ia], xb = sidx[lb + ib];
                bool takeA = (va > vb) || (va == vb && xa < xb);
                if (takeA) { ov[k] = va; oi[k] = xa; ++ia; }
                else       { ov[k] = vb; oi[k] = xb; ++ib; }
            }
            #pragma unroll
            for (int k = 0; k < TOPK; ++k) { sval[la + k] = ov[k]; sidx[la + k] = oi[k]; }
        }
    }
    __syncthreads();
    if (t < 16) {
        size_t gi = (size_t)(part * N_NODES + i0 + t) * TOPK;
        #pragma unroll
        for (int k = 0; k < TOPK; ++k) {
            topv[gi + k] = sval[t * LSTR + k];
            topi[gi + k] = (int)sidx[t * LSTR + k];
        }
    }
}

// ---- 4-way merge of sorted quarter lists; OR bits; final deg --------------
__global__ void topmerge_kernel(const float* __restrict__ topv,
                                const int* __restrict__ topi,
                                const int* __restrict__ degpre,
                                uint32_t* __restrict__ Mbits,
                                float* __restrict__ deg) {
    int i = blockIdx.x * blockDim.x + threadIdx.x;
    if (i >= N_NODES) return;
    const float* v[JSPLIT]; const int* x[JSPLIT]; int ix[JSPLIT];
    #pragma unroll
    for (int q = 0; q < JSPLIT; ++q) {
        v[q] = topv + (size_t)(q * N_NODES + i) * TOPK;
        x[q] = topi + (size_t)(q * N_NODES + i) * TOPK;
        ix[q] = 0;
    }
    int newc = 0;
    #pragma unroll
    for (int k = 0; k < TOPK; ++k) {
        float bestv = -1e38f; int bestj = 0x7fffffff; int bestq = 0;
        #pragma unroll
        for (int q = 0; q < JSPLIT; ++q) {
            bool ok = ix[q] < TOPK;
            float fv = ok ? v[q][ix[q]] : -1e38f;
            int   jj = ok ? x[q][ix[q]] : 0x7fffffff;
            if (fv > bestv || (fv == bestv && jj < bestj)) {
                bestv = fv; bestj = jj; bestq = q;
            }
        }
        ++ix[bestq];
        uint32_t* wp = &Mbits[(size_t)i * WPR + (bestj >> 5)];
        uint32_t old = *wp, bit = 1u << (bestj & 31);
        newc += ((old & bit) == 0u);
        *wp = old | bit;                 // row-exclusive, serial in-thread
    }
    deg[i] = (float)(degpre[i] + newc);
}

// ---- masked mean partials via MFMA, K split x2 ----------------------------
__launch_bounds__(512, 2)
__global__ void fused_kernel(const uint32_t* __restrict__ Mbits,
                             const uint16_t* __restrict__ aggTb,
                             float* __restrict__ fpart) {
    int i0 = blockIdx.x * 16;
    int part = blockIdx.y;
    int t = threadIdx.x;
    int w = t >> 6;
    int lane = t & 63;
    int col = lane & 15;
    int quad = lane >> 4;

    const uint32_t* mrow = Mbits + (size_t)(i0 + col) * WPR;
    const uint16_t* brow = aggTb + (size_t)(w * 16 + col) * N_NODES;
    f32x4 acc[4];
    #pragma unroll
    for (int u = 0; u < 4; ++u) acc[u] = (f32x4){0.f, 0.f, 0.f, 0.f};

    int kbase = part * 2048;
    for (int k0 = kbase; k0 < kbase + 2048; k0 += 128) {
        uint4 mw4 = *(const uint4*)&mrow[k0 >> 5];
        uint32_t mws[4] = {mw4.x, mw4.y, mw4.z, mw4.w};
        #pragma unroll
        for (int u = 0; u < 4; ++u) {
            uint32_t byte = (mws[u] >> (quad * 8)) & 0xFFu;
            union { uint32_t uu[4]; bf16x8 v; } a;
            #pragma unroll
            for (int pp = 0; pp < 4; ++pp) {
                uint32_t lo = (byte >> (2 * pp)) & 1u;
                uint32_t hi = (byte >> (2 * pp + 1)) & 1u;
                a.uu[pp] = (lo ? 0x3F80u : 0u) | (hi ? 0x3F800000u : 0u);
            }
            bf16x8 b = *(const bf16x8*)&brow[k0 + u * 32 + quad * 8];
            acc[u] = __builtin_amdgcn_mfma_f32_16x16x32_bf16(a.v, b, acc[u], 0, 0, 0);
        }
    }
    #pragma unroll
    for (int r = 0; r < 4; ++r) {
        int il = quad * 4 + r;
        float s = (acc[0][r] + acc[1][r]) + (acc[2][r] + acc[3][r]);
        fpart[(size_t)part * (N_NODES * C_DIM)
              + (size_t)(i0 + il) * C_DIM + w * 16 + col] = s;
    }
}

// ---- fused MLP: h=[x,fused]@fW+fB; h1=relu(h@l0W+l0B); out=lsm(h1@l1W+l1B)
__global__ void mlp_kernel(const float* __restrict__ xf,
                           const float* __restrict__ fpart,
                           const float* __restrict__ deg,
                           const float* __restrict__ fW, const float* __restrict__ fB,
                           const float* __restrict__ l0W, const float* __restrict__ l0B,
                           const float* __restrict__ l1W, const float* __restrict__ l1B,
                           float* __restrict__ out) {
    int i0 = blockIdx.x * 4;
    int t = threadIdx.x;                 // 128
    __shared__ float lx[4][256];
    __shared__ float hb[4][128];
    const float* f0 = fpart;
    const float* f1 = fpart + (size_t)N_NODES * C_DIM;
    for (int r = t; r < 4 * 128; r += 128) {
        int row = r >> 7, c = r & 127;
        size_t idx = (size_t)(i0 + row) * C_DIM + c;
        lx[row][c] = xf[idx];
        lx[row][128 + c] = (f0[idx] + f1[idx]) / (deg[i0 + row] + 1e-6f);
    }
    __syncthreads();
    float acc[4];
    #pragma unroll
    for (int r = 0; r < 4; ++r) acc[r] = fB[t];
    for (int k = 0; k < 256; ++k) {
        float wv = fW[k * 128 + t];
        #pragma unroll
        for (int r = 0; r < 4; ++r) acc[r] = fmaf(lx[r][k], wv, acc[r]);
    }
    #pragma unroll
    for (int r = 0; r < 4; ++r) hb[r][t] = acc[r];
    __syncthreads();
    #pragma unroll
    for (int r = 0; r < 4; ++r) acc[r] = l0B[t];
    for (int k = 0; k < 128; ++k) {
        float wv = l0W[k * 128 + t];
        #pragma unroll
        for (int r = 0; r < 4; ++r) acc[r] = fmaf(hb[r][k], wv, acc[r]);
    }
    __syncthreads();
    #pragma unroll
    for (int r = 0; r < 4; ++r) lx[r][t] = fmaxf(acc[r], 0.f);   // h1
    __syncthreads();
    int o = t & 63, pr = t >> 6;
    #pragma unroll
    for (int rr = 0; rr < 2; ++rr) {
        int r = pr + 2 * rr;
        float a = l1B[o];
        for (int k = 0; k < 128; ++k)
            a = fmaf(lx[r][k], l1W[k * 64 + o], a);
        float m = a;
        #pragma unroll
        for (int off = 32; off >= 1; off >>= 1) m = fmaxf(m, __shfl_xor(m, off));
        float e = expf(a - m);
        float s = e;
        #pragma unroll
        for (int off = 32; off >= 1; off >>= 1) s += __shfl_xor(s, off);
        out[(size_t)(i0 + r) * 64 + o] = a - m - logf(s);
    }
}

extern "C" void kernel_launch(void* const* d_in, const int* in_sizes, int n_in,
                              void* d_out, int out_size, void* d_ws, size_t ws_size,
                              hipStream_t stream) {
    const float* xf    = (const float*)d_in[0];
    const int*   ei    = (const int*)d_in[1];
    const float* alpha = (const float*)d_in[2];
    const float* fW    = (const float*)d_in[3];
    const float* fB    = (const float*)d_in[4];
    const float* l0W   = (const float*)d_in[5];
    const float* l0B   = (const float*)d_in[6];
    const float* l1W   = (const float*)d_in[7];
    const float* l1B   = (const float*)d_in[8];
    float* out = (float*)d_out;
    const int E  = in_sizes[1] / 2;     // 65536
    const int NC = N_NODES * C_DIM;     // 524288

    char* p = (char*)d_ws;
    const size_t SZ = (size_t)NC * 4;   // 2 MB
    uint32_t* Abits  = (uint32_t*)p; p += SZ;
    int*      degpre = (int*)p;      p += N_NODES * 4;   // contiguous w/ Abits
    float*    hop1   = (float*)p;    p += SZ;
    float*    agg    = (float*)p;    p += SZ;
    uint32_t* Mbits  = (uint32_t*)p; p += SZ;
    float*    fpart  = (float*)p;    p += 2 * SZ;        // two K-half partials
    uint16_t* xnb    = (uint16_t*)p; p += SZ / 2;
    uint16_t* aggTb  = (uint16_t*)p; p += SZ / 2;
    float*    deg    = (float*)p;    p += N_NODES * 4;
    float*    topv   = (float*)p;    p += (size_t)JSPLIT * N_NODES * TOPK * 4;
    int*      topi   = (int*)p;      p += (size_t)JSPLIT * N_NODES * TOPK * 4;

    hipMemsetAsync(Abits, 0, SZ + N_NODES * 4, stream);  // Abits + degpre
    scatter_kernel<<<(E + 255) / 256, 256, 0, stream>>>(ei, E, Abits);
    spmm_kernel<<<N_NODES, 128, 0, stream>>>(Abits, xf, hop1);
    spmm2_agg_kernel<<<N_NODES, 128, 0, stream>>>(Abits, hop1, xf, alpha, agg);
    norm_kernel<<<N_NODES, 128, 0, stream>>>(xf, xnb);
    transpose_bf_kernel<<<dim3(128, 4), 256, 0, stream>>>(agg, aggTb);
    mask_kernel<<<(HALF_P >> 5) / 256, 256, 0, stream>>>(Mbits, degpre);
    topk_kernel<<<dim3(N_NODES / 16, JSPLIT), 512, 0, stream>>>(xnb, topv, topi);
    topmerge_kernel<<<N_NODES / 256, 256, 0, stream>>>(topv, topi, degpre, Mbits, deg);
    fused_kernel<<<dim3(N_NODES / 16, 2), 512, 0, stream>>>(Mbits, aggTb, fpart);
    mlp_kernel<<<N_NODES / 4, 128, 0, stream>>>(xf, fpart, deg,
                                                fW, fB, l0W, l0B, l1W, l1B, out);
}

// Round 12
// 245.083 us; speedup vs baseline: 5.6533x; 1.0229x over previous
//
#include <hip/hip_runtime.h>
#include <hip/hip_bf16.h>
#include <stdint.h>

// ScaleGNN on MI355X (gfx950). fp32 in / fp32 out. edge_index int32/int64
// auto-detect (in scatter). Mask = JAX threefry2x32 key(42) bit-exact.
// R12: dispatch-count surgery 11 -> 7.
//   spmm2_combo = spmm2+agg + norm + aggT-bf16 store + threefry mask + degpre
//   fused       = topmerge (per-block, local window) + masked-mean MFMA (K/4)
//                 + deg write; Mbits is read-only after combo.
//   topk unchanged from R11 (48 us, conflict-free merge layout).

#define N_NODES 4096
#define C_DIM   128
#define WPR     128        // bitmask words per row (4096/32)
#define HALF_P  8388608u   // N*N/2
#define TOPK    10
#define LSTR    13         // topk list stride; (16L+13c) mod 32 covers banks
#define JSPLIT  4          // topk j-split and fused K-split

typedef __attribute__((ext_vector_type(8))) short bf16x8;   // 8 bf16 = 4 VGPRs
typedef __attribute__((ext_vector_type(4))) float f32x4;    // MFMA C/D

__device__ __forceinline__ uint16_t f2bf(float f) {         // RNE fp32->bf16
    uint32_t u = __float_as_uint(f);
    return (uint16_t)((u + 0x7FFFu + ((u >> 16) & 1u)) >> 16);
}

__device__ __forceinline__ uint32_t rotl32(uint32_t v, int r) {
    return (v << r) | (v >> (32 - r));
}

__device__ __forceinline__ void threefry2x32(uint32_t k0, uint32_t k1,
                                             uint32_t x0, uint32_t x1,
                                             uint32_t& o0, uint32_t& o1) {
    uint32_t ks2 = k0 ^ k1 ^ 0x1BD11BDAu;
    x0 += k0; x1 += k1;
#define TF_ROUND(r) { x0 += x1; x1 = rotl32(x1, (r)); x1 ^= x0; }
    TF_ROUND(13) TF_ROUND(15) TF_ROUND(26) TF_ROUND(6)
    x0 += k1;  x1 += ks2 + 1u;
    TF_ROUND(17) TF_ROUND(29) TF_ROUND(16) TF_ROUND(24)
    x0 += ks2; x1 += k0 + 2u;
    TF_ROUND(13) TF_ROUND(15) TF_ROUND(26) TF_ROUND(6)
    x0 += k0;  x1 += k1 + 3u;
    TF_ROUND(17) TF_ROUND(29) TF_ROUND(16) TF_ROUND(24)
    x0 += k1;  x1 += ks2 + 4u;
    TF_ROUND(13) TF_ROUND(15) TF_ROUND(26) TF_ROUND(6)
    x0 += ks2; x1 += k0 + 5u;
#undef TF_ROUND
    o0 = x0; o1 = x1;
}

// ---- scatter edges (int64/int32 detected per block) -----------------------
__global__ void scatter_kernel(const int* __restrict__ ei, int E,
                               uint32_t* __restrict__ Abits) {
    __shared__ int cnt_oddnz;
    int t = threadIdx.x;
    if (t == 0) cnt_oddnz = 0;
    __syncthreads();
    if (((const uint32_t*)ei)[2 * t + 1] != 0u) atomicAdd(&cnt_oddnz, 1);
    __syncthreads();
    bool is64 = (cnt_oddnz <= 8);        // int64 => high words all zero
    int e = blockIdx.x * blockDim.x + t;
    if (e >= E) return;
    int src, dst;
    if (is64) { src = ei[2 * e]; dst = ei[2 * (E + e)]; }
    else      { src = ei[e];     dst = ei[E + e]; }
    src &= (N_NODES - 1);
    dst &= (N_NODES - 1);
    atomicOr(&Abits[src * WPR + (dst >> 5)], 1u << (dst & 31));
}

// ---- SpMM: hop1[i,:] = sum_{j in bits(i)} x[j,:] --------------------------
__global__ void spmm_kernel(const uint32_t* __restrict__ Abits,
                            const float* __restrict__ in,
                            float* __restrict__ out) {
    int i = blockIdx.x;
    int c = threadIdx.x;                 // 128
    __shared__ uint32_t wbits[WPR];
    wbits[c] = Abits[i * WPR + c];
    __syncthreads();
    float acc = 0.f;
    for (int w = 0; w < WPR; ++w) {
        uint32_t bits = wbits[w];
        while (bits) {
            int b = __ffs(bits) - 1;
            bits &= bits - 1;
            acc += in[(w * 32 + b) * C_DIM + c];
        }
    }
    out[i * C_DIM + c] = acc;
}

// ---- combo: spmm2+agg, norm->xnb, aggT bf16 store, threefry mask, degpre --
// grid 4096 x 128. Thread job u = i*128+c for hashing (16 counters each;
// halves recombined via lane shuffle -> bit-exact original word mapping).
__global__ void spmm2_combo_kernel(const uint32_t* __restrict__ Abits,
                                   const float* __restrict__ hop1,
                                   const float* __restrict__ xf,
                                   const float* __restrict__ alpha,
                                   float* __restrict__ agg,
                                   uint16_t* __restrict__ aggTb,
                                   uint16_t* __restrict__ xnb,
                                   uint32_t* __restrict__ Mbits,
                                   int* __restrict__ degpre) {
    int i = blockIdx.x;
    int c = threadIdx.x;                 // 128
    __shared__ uint32_t wbits[WPR];
    __shared__ float ws[2];
    wbits[c] = Abits[i * WPR + c];
    __syncthreads();
    float acc = 0.f;
    for (int w = 0; w < WPR; ++w) {
        uint32_t bits = wbits[w];
        while (bits) {
            int b = __ffs(bits) - 1;
            bits &= bits - 1;
            acc += hop1[(w * 32 + b) * C_DIM + c];
        }
    }
    float xv  = xf[i * C_DIM + c];
    float h1v = hop1[i * C_DIM + c];
    float a = alpha[0] * xv + alpha[1] * h1v + alpha[2] * acc;
    agg[i * C_DIM + c] = a;
    aggTb[(size_t)c * N_NODES + i] = f2bf(a);   // transposed bf16 (scattered)

    // norm of row i -> xnb
    float sq = xv * xv;
    #pragma unroll
    for (int off = 32; off >= 1; off >>= 1) sq += __shfl_xor(sq, off);
    if ((c & 63) == 0) ws[c >> 6] = sq;
    __syncthreads();
    float tot = ws[0] + ws[1];
    xnb[i * C_DIM + c] = f2bf(xv / (sqrtf(tot) + 1e-8f));

    // threefry mask: job u covers half of word tid = u>>1
    uint32_t u = (uint32_t)(i * 128 + c);
    uint32_t tid = u >> 1;
    uint32_t halfb = u & 1u;
    uint32_t base = tid * 32u + halfb * 16u;
    uint32_t w0 = 0u, w1 = 0u;
    for (int k = 0; k < 16; ++k) {
        uint32_t o0, o1;
        threefry2x32(0u, 42u, base + k, HALF_P + base + k, o0, o1);
        w0 |= (uint32_t)((o0 >> 31) ^ 1u) << k;
        w1 |= (uint32_t)((o1 >> 31) ^ 1u) << k;
    }
    uint32_t w0o = (uint32_t)__shfl_xor((int)w0, 1);
    uint32_t w1o = (uint32_t)__shfl_xor((int)w1, 1);
    int p0 = 0, p1 = 0;
    if (halfb == 0u) {
        uint32_t W0 = w0 | (w0o << 16);
        uint32_t W1 = w1 | (w1o << 16);
        Mbits[tid] = W0;
        Mbits[(HALF_P >> 5) + tid] = W1;
        p0 = __popc(W0); p1 = __popc(W1);
    }
    #pragma unroll
    for (int off = 32; off >= 1; off >>= 1) {
        p0 += __shfl_xor(p0, off);
        p1 += __shfl_xor(p1, off);
    }
    if ((c & 63) == 0) {
        int row0 = i >> 1;               // wave-uniform (see derivation)
        atomicAdd(&degpre[row0], p0);
        atomicAdd(&degpre[2048 + row0], p1);
    }
}

// ---- topk via MFMA (R11, unchanged) ---------------------------------------
__launch_bounds__(512, 4)
__global__ void topk_kernel(const uint16_t* __restrict__ xnb,
                            float* __restrict__ topv,
                            int* __restrict__ topi) {
    int i0 = blockIdx.x * 16;
    int part = blockIdx.y;               // 0..3
    int t = threadIdx.x;
    int w = t >> 6;
    int lane = t & 63;
    int col = lane & 15;
    int quad = lane >> 4;

    __shared__ float    sval[32 * 16 * LSTR];
    __shared__ uint16_t sidx[32 * 16 * LSTR];

    bf16x8 bfi[4];
    #pragma unroll
    for (int s = 0; s < 4; ++s)
        bfi[s] = *(const bf16x8*)&xnb[(size_t)(i0 + col) * C_DIM + s * 32 + quad * 8];

    float tv[TOPK]; int ti[TOPK];
    #pragma unroll
    for (int k = 0; k < TOPK; ++k) { tv[k] = -1e30f; ti[k] = 0xFFFF; }

    int jt0 = part * 64 + w * 8;
    for (int p = 0; p < 8; ++p) {
        int j0 = (jt0 + p) * 16;
        f32x4 acc = {0.f, 0.f, 0.f, 0.f};
        #pragma unroll
        for (int s = 0; s < 4; ++s) {
            bf16x8 aj = *(const bf16x8*)&xnb[(size_t)(j0 + col) * C_DIM + s * 32 + quad * 8];
            acc = __builtin_amdgcn_mfma_f32_16x16x32_bf16(aj, bfi[s], acc, 0, 0, 0);
        }
        float m4 = fmaxf(fmaxf(acc[0], acc[1]), fmaxf(acc[2], acc[3]));
        if (m4 > tv[TOPK-1]) {
            #pragma unroll
            for (int r = 0; r < 4; ++r) {
                float d = acc[r];
                if (d > tv[TOPK-1]) {    // strict > keeps earliest j
                    int j = j0 + quad * 4 + r;
                    tv[TOPK-1] = d; ti[TOPK-1] = j;
                    #pragma unroll
                    for (int q = TOPK - 2; q >= 0; --q) {
                        if (tv[q+1] > tv[q]) {
                            float fv = tv[q]; tv[q] = tv[q+1]; tv[q+1] = fv;
                            int iv = ti[q];  ti[q] = ti[q+1];  ti[q+1] = iv;
                        }
                    }
                }
            }
        }
    }

    int base = ((w * 4 + quad) * 16 + col) * LSTR;
    #pragma unroll
    for (int k = 0; k < TOPK; ++k) {
        sval[base + k] = tv[k];
        sidx[base + k] = (uint16_t)ti[k];
    }

    int row = t & 15, L = t >> 4;
    for (int s = 16; s >= 1; s >>= 1) {
        __syncthreads();
        if (L < s) {
            int la = (L * 16 + row) * LSTR;
            int lb = ((L + s) * 16 + row) * LSTR;
            float ov[TOPK]; uint16_t oi[TOPK];
            int ia = 0, ib = 0;
            #pragma unroll
            for (int k = 0; k < TOPK; ++k) {
                float va = sval[la + ia], vb = sval[lb + ib];
                uint16_t xa = sidx[la + ia], xb = sidx[lb + ib];
                bool takeA = (va > vb) || (va == vb && xa < xb);
                if (takeA) { ov[k] = va; oi[k] = xa; ++ia; }
                else       { ov[k] = vb; oi[k] = xb; ++ib; }
            }
            #pragma unroll
            for (int k = 0; k < TOPK; ++k) { sval[la + k] = ov[k]; sidx[la + k] = oi[k]; }
        }
    }
    __syncthreads();
    if (t < 16) {
        size_t gi = (size_t)(part * N_NODES + i0 + t) * TOPK;
        #pragma unroll
        for (int k = 0; k < TOPK; ++k) {
            topv[gi + k] = sval[t * LSTR + k];
            topi[gi + k] = (int)sidx[t * LSTR + k];
        }
    }
}

// ---- fused: merge topk lists locally + masked-mean MFMA (K split x4) ------
// grid (256, 4). Mask window staged in LDS [16][33] (conflict-free); topk
// bits OR'd locally; deg = degpre + new-bit count (part 0 writes).
__launch_bounds__(512, 4)
__global__ void fused_kernel(const uint32_t* __restrict__ Mbits,
                             const uint16_t* __restrict__ aggTb,
                             const float* __restrict__ topv,
                             const int* __restrict__ topi,
                             const int* __restrict__ degpre,
                             float* __restrict__ fpart,
                             float* __restrict__ deg) {
    int i0 = blockIdx.x * 16;
    int part = blockIdx.y;               // 0..3
    int t = threadIdx.x;
    int w = t >> 6;
    int lane = t & 63;
    int col = lane & 15;
    int quad = lane >> 4;

    __shared__ uint32_t smask[16][33];   // padded: bank = (col+w)%32
    smask[t >> 5][t & 31] =
        Mbits[(size_t)(i0 + (t >> 5)) * WPR + part * 32 + (t & 31)];
    __syncthreads();

    if (t < 16) {
        int i = i0 + t;
        const float* v[JSPLIT]; const int* x[JSPLIT]; int ix[JSPLIT];
        #pragma unroll
        for (int q = 0; q < JSPLIT; ++q) {
            v[q] = topv + (size_t)(q * N_NODES + i) * TOPK;
            x[q] = topi + (size_t)(q * N_NODES + i) * TOPK;
            ix[q] = 0;
        }
        int newc = 0;
        int kw0 = part * 1024;
        #pragma unroll
        for (int k = 0; k < TOPK; ++k) {
            float bestv = -1e38f; int bestj = 0x7fffffff; int bestq = 0;
            #pragma unroll
            for (int q = 0; q < JSPLIT; ++q) {
                bool ok = ix[q] < TOPK;
                float fv = ok ? v[q][ix[q]] : -1e38f;
                int   jj = ok ? x[q][ix[q]] : 0x7fffffff;
                if (fv > bestv || (fv == bestv && jj < bestj)) {
                    bestv = fv; bestj = jj; bestq = q;
                }
            }
            ++ix[bestq];
            uint32_t mw = Mbits[(size_t)i * WPR + (bestj >> 5)];
            newc += (int)(((mw >> (bestj & 31)) & 1u) == 0u);
            int rel = bestj - kw0;
            if (rel >= 0 && rel < 1024)
                smask[t][rel >> 5] |= 1u << (bestj & 31);
        }
        if (part == 0) deg[i] = (float)(degpre[i] + newc);
    }
    __syncthreads();

    const uint16_t* brow = aggTb + (size_t)(w * 16 + col) * N_NODES;
    int kbase = part * 1024;
    f32x4 acc[4];
    #pragma unroll
    for (int u = 0; u < 4; ++u) acc[u] = (f32x4){0.f, 0.f, 0.f, 0.f};

    for (int k0 = 0; k0 < 1024; k0 += 128) {
        #pragma unroll
        for (int u = 0; u < 4; ++u) {
            uint32_t mw = smask[col][(k0 >> 5) + u];
            uint32_t byte = (mw >> (quad * 8)) & 0xFFu;
            union { uint32_t uu[4]; bf16x8 v; } a;
            #pragma unroll
            for (int pp = 0; pp < 4; ++pp) {
                uint32_t lo = (byte >> (2 * pp)) & 1u;
                uint32_t hi = (byte >> (2 * pp + 1)) & 1u;
                a.uu[pp] = (lo ? 0x3F80u : 0u) | (hi ? 0x3F800000u : 0u);
            }
            bf16x8 b = *(const bf16x8*)&brow[kbase + k0 + u * 32 + quad * 8];
            acc[u] = __builtin_amdgcn_mfma_f32_16x16x32_bf16(a.v, b, acc[u], 0, 0, 0);
        }
    }
    #pragma unroll
    for (int r = 0; r < 4; ++r) {
        int il = quad * 4 + r;
        float s = (acc[0][r] + acc[1][r]) + (acc[2][r] + acc[3][r]);
        fpart[(size_t)part * (N_NODES * C_DIM)
              + (size_t)(i0 + il) * C_DIM + w * 16 + col] = s;
    }
}

// ---- fused MLP: h=[x,fused]@fW+fB; h1=relu(h@l0W+l0B); out=lsm(h1@l1W+l1B)
__global__ void mlp_kernel(const float* __restrict__ xf,
                           const float* __restrict__ fpart,
                           const float* __restrict__ deg,
                           const float* __restrict__ fW, const float* __restrict__ fB,
                           const float* __restrict__ l0W, const float* __restrict__ l0B,
                           const float* __restrict__ l1W, const float* __restrict__ l1B,
                           float* __restrict__ out) {
    int i0 = blockIdx.x * 4;
    int t = threadIdx.x;                 // 128
    __shared__ float lx[4][256];
    __shared__ float hb[4][128];
    const float* f0 = fpart;
    const float* f1 = fpart + (size_t)N_NODES * C_DIM;
    const float* f2 = fpart + (size_t)2 * N_NODES * C_DIM;
    const float* f3 = fpart + (size_t)3 * N_NODES * C_DIM;
    for (int r = t; r < 4 * 128; r += 128) {
        int row = r >> 7, c = r & 127;
        size_t idx = (size_t)(i0 + row) * C_DIM + c;
        lx[row][c] = xf[idx];
        lx[row][128 + c] = ((f0[idx] + f1[idx]) + (f2[idx] + f3[idx]))
                           / (deg[i0 + row] + 1e-6f);
    }
    __syncthreads();
    float acc[4];
    #pragma unroll
    for (int r = 0; r < 4; ++r) acc[r] = fB[t];
    for (int k = 0; k < 256; ++k) {
        float wv = fW[k * 128 + t];
        #pragma unroll
        for (int r = 0; r < 4; ++r) acc[r] = fmaf(lx[r][k], wv, acc[r]);
    }
    #pragma unroll
    for (int r = 0; r < 4; ++r) hb[r][t] = acc[r];
    __syncthreads();
    #pragma unroll
    for (int r = 0; r < 4; ++r) acc[r] = l0B[t];
    for (int k = 0; k < 128; ++k) {
        float wv = l0W[k * 128 + t];
        #pragma unroll
        for (int r = 0; r < 4; ++r) acc[r] = fmaf(hb[r][k], wv, acc[r]);
    }
    __syncthreads();
    #pragma unroll
    for (int r = 0; r < 4; ++r) lx[r][t] = fmaxf(acc[r], 0.f);   // h1
    __syncthreads();
    int o = t & 63, pr = t >> 6;
    #pragma unroll
    for (int rr = 0; rr < 2; ++rr) {
        int r = pr + 2 * rr;
        float a = l1B[o];
        for (int k = 0; k < 128; ++k)
            a = fmaf(lx[r][k], l1W[k * 64 + o], a);
        float m = a;
        #pragma unroll
        for (int off = 32; off >= 1; off >>= 1) m = fmaxf(m, __shfl_xor(m, off));
        float e = expf(a - m);
        float s = e;
        #pragma unroll
        for (int off = 32; off >= 1; off >>= 1) s += __shfl_xor(s, off);
        out[(size_t)(i0 + r) * 64 + o] = a - m - logf(s);
    }
}

extern "C" void kernel_launch(void* const* d_in, const int* in_sizes, int n_in,
                              void* d_out, int out_size, void* d_ws, size_t ws_size,
                              hipStream_t stream) {
    const float* xf    = (const float*)d_in[0];
    const int*   ei    = (const int*)d_in[1];
    const float* alpha = (const float*)d_in[2];
    const float* fW    = (const float*)d_in[3];
    const float* fB    = (const float*)d_in[4];
    const float* l0W   = (const float*)d_in[5];
    const float* l0B   = (const float*)d_in[6];
    const float* l1W   = (const float*)d_in[7];
    const float* l1B   = (const float*)d_in[8];
    float* out = (float*)d_out;
    const int E  = in_sizes[1] / 2;     // 65536
    const int NC = N_NODES * C_DIM;     // 524288

    char* p = (char*)d_ws;
    const size_t SZ = (size_t)NC * 4;   // 2 MB
    uint32_t* Abits  = (uint32_t*)p; p += SZ;
    int*      degpre = (int*)p;      p += N_NODES * 4;   // contiguous w/ Abits
    float*    hop1   = (float*)p;    p += SZ;
    float*    agg    = (float*)p;    p += SZ;
    uint32_t* Mbits  = (uint32_t*)p; p += SZ;
    float*    fpart  = (float*)p;    p += 4 * SZ;        // four K-quarter partials
    uint16_t* xnb    = (uint16_t*)p; p += SZ / 2;
    uint16_t* aggTb  = (uint16_t*)p; p += SZ / 2;
    float*    deg    = (float*)p;    p += N_NODES * 4;
    float*    topv   = (float*)p;    p += (size_t)JSPLIT * N_NODES * TOPK * 4;
    int*      topi   = (int*)p;      p += (size_t)JSPLIT * N_NODES * TOPK * 4;

    hipMemsetAsync(Abits, 0, SZ + N_NODES * 4, stream);  // Abits + degpre
    scatter_kernel<<<(E + 255) / 256, 256, 0, stream>>>(ei, E, Abits);
    spmm_kernel<<<N_NODES, 128, 0, stream>>>(Abits, xf, hop1);
    spmm2_combo_kernel<<<N_NODES, 128, 0, stream>>>(Abits, hop1, xf, alpha,
                                                    agg, aggTb, xnb, Mbits, degpre);
    topk_kernel<<<dim3(N_NODES / 16, JSPLIT), 512, 0, stream>>>(xnb, topv, topi);
    fused_kernel<<<dim3(N_NODES / 16, 4), 512, 0, stream>>>(Mbits, aggTb,
                                                            topv, topi, degpre,
                                                            fpart, deg);
    mlp_kernel<<<N_NODES / 4, 128, 0, stream>>>(xf, fpart, deg,
                                                fW, fB, l0W, l0B, l1W, l1B, out);
}

// Round 13
// 240.387 us; speedup vs baseline: 5.7637x; 1.0195x over previous
//
#include <hip/hip_runtime.h>
#include <hip/hip_bf16.h>
#include <stdint.h>

// ScaleGNN on MI355X (gfx950). fp32 in / fp32 out. edge_index int32/int64
// auto-detect (in scatter). Mask = JAX threefry2x32 key(42) bit-exact.
// R13: fused_kernel prologue fixed — topv/topi staged to LDS by 64 parallel
//      threads (no dependent global chain), newc counted against LDS mask
//      window, deg accumulated via atomicAdd into degInt (int, pre-filled by
//      combo). 6 dispatches total; topk unchanged (48 us).

#define N_NODES 4096
#define C_DIM   128
#define WPR     128        // bitmask words per row (4096/32)
#define HALF_P  8388608u   // N*N/2
#define TOPK    10
#define LSTR    13         // topk list stride; (16L+13c) mod 32 covers banks
#define JSPLIT  4          // topk j-split and fused K-split

typedef __attribute__((ext_vector_type(8))) short bf16x8;   // 8 bf16 = 4 VGPRs
typedef __attribute__((ext_vector_type(4))) float f32x4;    // MFMA C/D

__device__ __forceinline__ uint16_t f2bf(float f) {         // RNE fp32->bf16
    uint32_t u = __float_as_uint(f);
    return (uint16_t)((u + 0x7FFFu + ((u >> 16) & 1u)) >> 16);
}

__device__ __forceinline__ uint32_t rotl32(uint32_t v, int r) {
    return (v << r) | (v >> (32 - r));
}

__device__ __forceinline__ void threefry2x32(uint32_t k0, uint32_t k1,
                                             uint32_t x0, uint32_t x1,
                                             uint32_t& o0, uint32_t& o1) {
    uint32_t ks2 = k0 ^ k1 ^ 0x1BD11BDAu;
    x0 += k0; x1 += k1;
#define TF_ROUND(r) { x0 += x1; x1 = rotl32(x1, (r)); x1 ^= x0; }
    TF_ROUND(13) TF_ROUND(15) TF_ROUND(26) TF_ROUND(6)
    x0 += k1;  x1 += ks2 + 1u;
    TF_ROUND(17) TF_ROUND(29) TF_ROUND(16) TF_ROUND(24)
    x0 += ks2; x1 += k0 + 2u;
    TF_ROUND(13) TF_ROUND(15) TF_ROUND(26) TF_ROUND(6)
    x0 += k0;  x1 += k1 + 3u;
    TF_ROUND(17) TF_ROUND(29) TF_ROUND(16) TF_ROUND(24)
    x0 += k1;  x1 += ks2 + 4u;
    TF_ROUND(13) TF_ROUND(15) TF_ROUND(26) TF_ROUND(6)
    x0 += ks2; x1 += k0 + 5u;
#undef TF_ROUND
    o0 = x0; o1 = x1;
}

// ---- scatter edges (int64/int32 detected per block) -----------------------
__global__ void scatter_kernel(const int* __restrict__ ei, int E,
                               uint32_t* __restrict__ Abits) {
    __shared__ int cnt_oddnz;
    int t = threadIdx.x;
    if (t == 0) cnt_oddnz = 0;
    __syncthreads();
    if (((const uint32_t*)ei)[2 * t + 1] != 0u) atomicAdd(&cnt_oddnz, 1);
    __syncthreads();
    bool is64 = (cnt_oddnz <= 8);        // int64 => high words all zero
    int e = blockIdx.x * blockDim.x + t;
    if (e >= E) return;
    int src, dst;
    if (is64) { src = ei[2 * e]; dst = ei[2 * (E + e)]; }
    else      { src = ei[e];     dst = ei[E + e]; }
    src &= (N_NODES - 1);
    dst &= (N_NODES - 1);
    atomicOr(&Abits[src * WPR + (dst >> 5)], 1u << (dst & 31));
}

// ---- SpMM: hop1[i,:] = sum_{j in bits(i)} x[j,:] --------------------------
__global__ void spmm_kernel(const uint32_t* __restrict__ Abits,
                            const float* __restrict__ in,
                            float* __restrict__ out) {
    int i = blockIdx.x;
    int c = threadIdx.x;                 // 128
    __shared__ uint32_t wbits[WPR];
    wbits[c] = Abits[i * WPR + c];
    __syncthreads();
    float acc = 0.f;
    for (int w = 0; w < WPR; ++w) {
        uint32_t bits = wbits[w];
        while (bits) {
            int b = __ffs(bits) - 1;
            bits &= bits - 1;
            acc += in[(w * 32 + b) * C_DIM + c];
        }
    }
    out[i * C_DIM + c] = acc;
}

// ---- combo: spmm2+agg, norm->xnb, aggT bf16 store, threefry mask, degInt --
__global__ void spmm2_combo_kernel(const uint32_t* __restrict__ Abits,
                                   const float* __restrict__ hop1,
                                   const float* __restrict__ xf,
                                   const float* __restrict__ alpha,
                                   float* __restrict__ agg,
                                   uint16_t* __restrict__ aggTb,
                                   uint16_t* __restrict__ xnb,
                                   uint32_t* __restrict__ Mbits,
                                   int* __restrict__ degInt) {
    int i = blockIdx.x;
    int c = threadIdx.x;                 // 128
    __shared__ uint32_t wbits[WPR];
    __shared__ float ws[2];
    wbits[c] = Abits[i * WPR + c];
    __syncthreads();
    float acc = 0.f;
    for (int w = 0; w < WPR; ++w) {
        uint32_t bits = wbits[w];
        while (bits) {
            int b = __ffs(bits) - 1;
            bits &= bits - 1;
            acc += hop1[(w * 32 + b) * C_DIM + c];
        }
    }
    float xv  = xf[i * C_DIM + c];
    float h1v = hop1[i * C_DIM + c];
    float a = alpha[0] * xv + alpha[1] * h1v + alpha[2] * acc;
    agg[i * C_DIM + c] = a;
    aggTb[(size_t)c * N_NODES + i] = f2bf(a);   // transposed bf16 (scattered)

    // norm of row i -> xnb
    float sq = xv * xv;
    #pragma unroll
    for (int off = 32; off >= 1; off >>= 1) sq += __shfl_xor(sq, off);
    if ((c & 63) == 0) ws[c >> 6] = sq;
    __syncthreads();
    float tot = ws[0] + ws[1];
    xnb[i * C_DIM + c] = f2bf(xv / (sqrtf(tot) + 1e-8f));

    // threefry mask: job u covers half of word tid = u>>1
    uint32_t u = (uint32_t)(i * 128 + c);
    uint32_t tid = u >> 1;
    uint32_t halfb = u & 1u;
    uint32_t base = tid * 32u + halfb * 16u;
    uint32_t w0 = 0u, w1 = 0u;
    for (int k = 0; k < 16; ++k) {
        uint32_t o0, o1;
        threefry2x32(0u, 42u, base + k, HALF_P + base + k, o0, o1);
        w0 |= (uint32_t)((o0 >> 31) ^ 1u) << k;
        w1 |= (uint32_t)((o1 >> 31) ^ 1u) << k;
    }
    uint32_t w0o = (uint32_t)__shfl_xor((int)w0, 1);
    uint32_t w1o = (uint32_t)__shfl_xor((int)w1, 1);
    int p0 = 0, p1 = 0;
    if (halfb == 0u) {
        uint32_t W0 = w0 | (w0o << 16);
        uint32_t W1 = w1 | (w1o << 16);
        Mbits[tid] = W0;
        Mbits[(HALF_P >> 5) + tid] = W1;
        p0 = __popc(W0); p1 = __popc(W1);
    }
    #pragma unroll
    for (int off = 32; off >= 1; off >>= 1) {
        p0 += __shfl_xor(p0, off);
        p1 += __shfl_xor(p1, off);
    }
    if ((c & 63) == 0) {
        int row0 = i >> 1;               // wave-uniform
        atomicAdd(&degInt[row0], p0);
        atomicAdd(&degInt[2048 + row0], p1);
    }
}

// ---- topk via MFMA (R11, unchanged) ---------------------------------------
__launch_bounds__(512, 4)
__global__ void topk_kernel(const uint16_t* __restrict__ xnb,
                            float* __restrict__ topv,
                            int* __restrict__ topi) {
    int i0 = blockIdx.x * 16;
    int part = blockIdx.y;               // 0..3
    int t = threadIdx.x;
    int w = t >> 6;
    int lane = t & 63;
    int col = lane & 15;
    int quad = lane >> 4;

    __shared__ float    sval[32 * 16 * LSTR];
    __shared__ uint16_t sidx[32 * 16 * LSTR];

    bf16x8 bfi[4];
    #pragma unroll
    for (int s = 0; s < 4; ++s)
        bfi[s] = *(const bf16x8*)&xnb[(size_t)(i0 + col) * C_DIM + s * 32 + quad * 8];

    float tv[TOPK]; int ti[TOPK];
    #pragma unroll
    for (int k = 0; k < TOPK; ++k) { tv[k] = -1e30f; ti[k] = 0xFFFF; }

    int jt0 = part * 64 + w * 8;
    for (int p = 0; p < 8; ++p) {
        int j0 = (jt0 + p) * 16;
        f32x4 acc = {0.f, 0.f, 0.f, 0.f};
        #pragma unroll
        for (int s = 0; s < 4; ++s) {
            bf16x8 aj = *(const bf16x8*)&xnb[(size_t)(j0 + col) * C_DIM + s * 32 + quad * 8];
            acc = __builtin_amdgcn_mfma_f32_16x16x32_bf16(aj, bfi[s], acc, 0, 0, 0);
        }
        float m4 = fmaxf(fmaxf(acc[0], acc[1]), fmaxf(acc[2], acc[3]));
        if (m4 > tv[TOPK-1]) {
            #pragma unroll
            for (int r = 0; r < 4; ++r) {
                float d = acc[r];
                if (d > tv[TOPK-1]) {    // strict > keeps earliest j
                    int j = j0 + quad * 4 + r;
                    tv[TOPK-1] = d; ti[TOPK-1] = j;
                    #pragma unroll
                    for (int q = TOPK - 2; q >= 0; --q) {
                        if (tv[q+1] > tv[q]) {
                            float fv = tv[q]; tv[q] = tv[q+1]; tv[q+1] = fv;
                            int iv = ti[q];  ti[q] = ti[q+1];  ti[q+1] = iv;
                        }
                    }
                }
            }
        }
    }

    int base = ((w * 4 + quad) * 16 + col) * LSTR;
    #pragma unroll
    for (int k = 0; k < TOPK; ++k) {
        sval[base + k] = tv[k];
        sidx[base + k] = (uint16_t)ti[k];
    }

    int row = t & 15, L = t >> 4;
    for (int s = 16; s >= 1; s >>= 1) {
        __syncthreads();
        if (L < s) {
            int la = (L * 16 + row) * LSTR;
            int lb = ((L + s) * 16 + row) * LSTR;
            float ov[TOPK]; uint16_t oi[TOPK];
            int ia = 0, ib = 0;
            #pragma unroll
            for (int k = 0; k < TOPK; ++k) {
                float va = sval[la + ia], vb = sval[lb + ib];
                uint16_t xa = sidx[la + ia], xb = sidx[lb + ib];
                bool takeA = (va > vb) || (va == vb && xa < xb);
                if (takeA) { ov[k] = va; oi[k] = xa; ++ia; }
                else       { ov[k] = vb; oi[k] = xb; ++ib; }
            }
            #pragma unroll
            for (int k = 0; k < TOPK; ++k) { sval[la + k] = ov[k]; sidx[la + k] = oi[k]; }
        }
    }
    __syncthreads();
    if (t < 16) {
        size_t gi = (size_t)(part * N_NODES + i0 + t) * TOPK;
        #pragma unroll
        for (int k = 0; k < TOPK; ++k) {
            topv[gi + k] = sval[t * LSTR + k];
            topi[gi + k] = (int)sidx[t * LSTR + k];
        }
    }
}

// ---- fused: LDS-staged merge + masked-mean MFMA (K split x4) --------------
// grid (256, 4). topv/topi staged by 64 parallel threads; merge is pure-LDS.
// newc counted in-window vs staged smask; deg via atomicAdd to degInt.
__launch_bounds__(512, 4)
__global__ void fused_kernel(const uint32_t* __restrict__ Mbits,
                             const uint16_t* __restrict__ aggTb,
                             const float* __restrict__ topv,
                             const int* __restrict__ topi,
                             int* __restrict__ degInt,
                             float* __restrict__ fpart) {
    int i0 = blockIdx.x * 16;
    int part = blockIdx.y;               // 0..3
    int t = threadIdx.x;
    int w = t >> 6;
    int lane = t & 63;
    int col = lane & 15;
    int quad = lane >> 4;

    __shared__ uint32_t smask[16][33];   // padded mask window
    __shared__ float    lv[16][JSPLIT][TOPK];
    __shared__ uint16_t li[16][JSPLIT][TOPK];
    smask[t >> 5][t & 31] =
        Mbits[(size_t)(i0 + (t >> 5)) * WPR + part * 32 + (t & 31)];
    if (t < 16 * JSPLIT) {               // 64 threads, independent loads
        int row = t & 15, q = t >> 4;
        size_t gi = (size_t)(q * N_NODES + i0 + row) * TOPK;
        #pragma unroll
        for (int k = 0; k < TOPK; ++k) {
            lv[row][q][k] = topv[gi + k];
            li[row][q][k] = (uint16_t)topi[gi + k];
        }
    }
    __syncthreads();

    if (t < 16) {                        // pure-LDS 4-way merge
        int ix[JSPLIT] = {0, 0, 0, 0};
        int newc = 0;
        int kw0 = part * 1024;
        #pragma unroll
        for (int k = 0; k < TOPK; ++k) {
            float bestv = -1e38f; int bestj = 0x7fffffff; int bestq = 0;
            #pragma unroll
            for (int q = 0; q < JSPLIT; ++q) {
                bool ok = ix[q] < TOPK;
                float fv = ok ? lv[t][q][ix[q]] : -1e38f;
                int   jj = ok ? (int)li[t][q][ix[q]] : 0x7fffffff;
                if (fv > bestv || (fv == bestv && jj < bestj)) {
                    bestv = fv; bestj = jj; bestq = q;
                }
            }
            ++ix[bestq];
            int rel = bestj - kw0;
            if (rel >= 0 && rel < 1024) {
                uint32_t* wp = &smask[t][rel >> 5];
                uint32_t old = *wp, bit = 1u << (bestj & 31);
                newc += (int)((old & bit) == 0u);
                *wp = old | bit;
            }
        }
        if (newc) atomicAdd(&degInt[i0 + t], newc);
    }
    __syncthreads();

    const uint16_t* brow = aggTb + (size_t)(w * 16 + col) * N_NODES;
    int kbase = part * 1024;
    f32x4 acc[4];
    #pragma unroll
    for (int u = 0; u < 4; ++u) acc[u] = (f32x4){0.f, 0.f, 0.f, 0.f};

    for (int k0 = 0; k0 < 1024; k0 += 128) {
        #pragma unroll
        for (int u = 0; u < 4; ++u) {
            uint32_t mw = smask[col][(k0 >> 5) + u];
            uint32_t byte = (mw >> (quad * 8)) & 0xFFu;
            union { uint32_t uu[4]; bf16x8 v; } a;
            #pragma unroll
            for (int pp = 0; pp < 4; ++pp) {
                uint32_t lo = (byte >> (2 * pp)) & 1u;
                uint32_t hi = (byte >> (2 * pp + 1)) & 1u;
                a.uu[pp] = (lo ? 0x3F80u : 0u) | (hi ? 0x3F800000u : 0u);
            }
            bf16x8 b = *(const bf16x8*)&brow[kbase + k0 + u * 32 + quad * 8];
            acc[u] = __builtin_amdgcn_mfma_f32_16x16x32_bf16(a.v, b, acc[u], 0, 0, 0);
        }
    }
    #pragma unroll
    for (int r = 0; r < 4; ++r) {
        int il = quad * 4 + r;
        float s = (acc[0][r] + acc[1][r]) + (acc[2][r] + acc[3][r]);
        fpart[(size_t)part * (N_NODES * C_DIM)
              + (size_t)(i0 + il) * C_DIM + w * 16 + col] = s;
    }
}

// ---- fused MLP: h=[x,fused]@fW+fB; h1=relu(h@l0W+l0B); out=lsm(h1@l1W+l1B)
__global__ void mlp_kernel(const float* __restrict__ xf,
                           const float* __restrict__ fpart,
                           const int* __restrict__ degInt,
                           const float* __restrict__ fW, const float* __restrict__ fB,
                           const float* __restrict__ l0W, const float* __restrict__ l0B,
                           const float* __restrict__ l1W, const float* __restrict__ l1B,
                           float* __restrict__ out) {
    int i0 = blockIdx.x * 4;
    int t = threadIdx.x;                 // 128
    __shared__ float lx[4][256];
    __shared__ float hb[4][128];
    const float* f0 = fpart;
    const float* f1 = fpart + (size_t)N_NODES * C_DIM;
    const float* f2 = fpart + (size_t)2 * N_NODES * C_DIM;
    const float* f3 = fpart + (size_t)3 * N_NODES * C_DIM;
    for (int r = t; r < 4 * 128; r += 128) {
        int row = r >> 7, c = r & 127;
        size_t idx = (size_t)(i0 + row) * C_DIM + c;
        lx[row][c] = xf[idx];
        lx[row][128 + c] = ((f0[idx] + f1[idx]) + (f2[idx] + f3[idx]))
                           / ((float)degInt[i0 + row] + 1e-6f);
    }
    __syncthreads();
    float acc[4];
    #pragma unroll
    for (int r = 0; r < 4; ++r) acc[r] = fB[t];
    for (int k = 0; k < 256; ++k) {
        float wv = fW[k * 128 + t];
        #pragma unroll
        for (int r = 0; r < 4; ++r) acc[r] = fmaf(lx[r][k], wv, acc[r]);
    }
    #pragma unroll
    for (int r = 0; r < 4; ++r) hb[r][t] = acc[r];
    __syncthreads();
    #pragma unroll
    for (int r = 0; r < 4; ++r) acc[r] = l0B[t];
    for (int k = 0; k < 128; ++k) {
        float wv = l0W[k * 128 + t];
        #pragma unroll
        for (int r = 0; r < 4; ++r) acc[r] = fmaf(hb[r][k], wv, acc[r]);
    }
    __syncthreads();
    #pragma unroll
    for (int r = 0; r < 4; ++r) lx[r][t] = fmaxf(acc[r], 0.f);   // h1
    __syncthreads();
    int o = t & 63, pr = t >> 6;
    #pragma unroll
    for (int rr = 0; rr < 2; ++rr) {
        int r = pr + 2 * rr;
        float a = l1B[o];
        for (int k = 0; k < 128; ++k)
            a = fmaf(lx[r][k], l1W[k * 64 + o], a);
        float m = a;
        #pragma unroll
        for (int off = 32; off >= 1; off >>= 1) m = fmaxf(m, __shfl_xor(m, off));
        float e = expf(a - m);
        float s = e;
        #pragma unroll
        for (int off = 32; off >= 1; off >>= 1) s += __shfl_xor(s, off);
        out[(size_t)(i0 + r) * 64 + o] = a - m - logf(s);
    }
}

extern "C" void kernel_launch(void* const* d_in, const int* in_sizes, int n_in,
                              void* d_out, int out_size, void* d_ws, size_t ws_size,
                              hipStream_t stream) {
    const float* xf    = (const float*)d_in[0];
    const int*   ei    = (const int*)d_in[1];
    const float* alpha = (const float*)d_in[2];
    const float* fW    = (const float*)d_in[3];
    const float* fB    = (const float*)d_in[4];
    const float* l0W   = (const float*)d_in[5];
    const float* l0B   = (const float*)d_in[6];
    const float* l1W   = (const float*)d_in[7];
    const float* l1B   = (const float*)d_in[8];
    float* out = (float*)d_out;
    const int E  = in_sizes[1] / 2;     // 65536
    const int NC = N_NODES * C_DIM;     // 524288

    char* p = (char*)d_ws;
    const size_t SZ = (size_t)NC * 4;   // 2 MB
    uint32_t* Abits  = (uint32_t*)p; p += SZ;
    int*      degInt = (int*)p;      p += N_NODES * 4;   // contiguous w/ Abits
    float*    hop1   = (float*)p;    p += SZ;
    float*    agg    = (float*)p;    p += SZ;
    uint32_t* Mbits  = (uint32_t*)p; p += SZ;
    float*    fpart  = (float*)p;    p += 4 * SZ;        // four K-quarter partials
    uint16_t* xnb    = (uint16_t*)p; p += SZ / 2;
    uint16_t* aggTb  = (uint16_t*)p; p += SZ / 2;
    float*    topv   = (float*)p;    p += (size_t)JSPLIT * N_NODES * TOPK * 4;
    int*      topi   = (int*)p;      p += (size_t)JSPLIT * N_NODES * TOPK * 4;

    hipMemsetAsync(Abits, 0, SZ + N_NODES * 4, stream);  // Abits + degInt
    scatter_kernel<<<(E + 255) / 256, 256, 0, stream>>>(ei, E, Abits);
    spmm_kernel<<<N_NODES, 128, 0, stream>>>(Abits, xf, hop1);
    spmm2_combo_kernel<<<N_NODES, 128, 0, stream>>>(Abits, hop1, xf, alpha,
                                                    agg, aggTb, xnb, Mbits, degInt);
    topk_kernel<<<dim3(N_NODES / 16, JSPLIT), 512, 0, stream>>>(xnb, topv, topi);
    fused_kernel<<<dim3(N_NODES / 16, 4), 512, 0, stream>>>(Mbits, aggTb,
                                                            topv, topi, degInt, fpart);
    mlp_kernel<<<N_NODES / 4, 128, 0, stream>>>(xf, fpart, degInt,
                                                fW, fB, l0W, l0B, l1W, l1B, out);
}

// Round 14
// 229.210 us; speedup vs baseline: 6.0448x; 1.0488x over previous
//
#include <hip/hip_runtime.h>
#include <hip/hip_bf16.h>
#include <stdint.h>

// ScaleGNN on MI355X (gfx950). fp32 in / fp32 out. edge_index int32/int64
// auto-detect (in scatter). Mask = JAX threefry2x32 key(42) bit-exact.
// R14: fused K-split 4 -> 2 (512 blocks, 2/CU): halves redundant stage/merge
//      and fpart HBM traffic (8MB->4MB each way); keeps R13 LDS-staged merge.
//      topk / combo / spmm / mlp structure unchanged.

#define N_NODES 4096
#define C_DIM   128
#define WPR     128        // bitmask words per row (4096/32)
#define HALF_P  8388608u   // N*N/2
#define TOPK    10
#define LSTR    13         // topk list stride; (16L+13c) mod 32 covers banks
#define JSPLIT  4          // topk j-split
#define KSPLIT  2          // fused K-split

typedef __attribute__((ext_vector_type(8))) short bf16x8;   // 8 bf16 = 4 VGPRs
typedef __attribute__((ext_vector_type(4))) float f32x4;    // MFMA C/D

__device__ __forceinline__ uint16_t f2bf(float f) {         // RNE fp32->bf16
    uint32_t u = __float_as_uint(f);
    return (uint16_t)((u + 0x7FFFu + ((u >> 16) & 1u)) >> 16);
}

__device__ __forceinline__ uint32_t rotl32(uint32_t v, int r) {
    return (v << r) | (v >> (32 - r));
}

__device__ __forceinline__ void threefry2x32(uint32_t k0, uint32_t k1,
                                             uint32_t x0, uint32_t x1,
                                             uint32_t& o0, uint32_t& o1) {
    uint32_t ks2 = k0 ^ k1 ^ 0x1BD11BDAu;
    x0 += k0; x1 += k1;
#define TF_ROUND(r) { x0 += x1; x1 = rotl32(x1, (r)); x1 ^= x0; }
    TF_ROUND(13) TF_ROUND(15) TF_ROUND(26) TF_ROUND(6)
    x0 += k1;  x1 += ks2 + 1u;
    TF_ROUND(17) TF_ROUND(29) TF_ROUND(16) TF_ROUND(24)
    x0 += ks2; x1 += k0 + 2u;
    TF_ROUND(13) TF_ROUND(15) TF_ROUND(26) TF_ROUND(6)
    x0 += k0;  x1 += k1 + 3u;
    TF_ROUND(17) TF_ROUND(29) TF_ROUND(16) TF_ROUND(24)
    x0 += k1;  x1 += ks2 + 4u;
    TF_ROUND(13) TF_ROUND(15) TF_ROUND(26) TF_ROUND(6)
    x0 += ks2; x1 += k0 + 5u;
#undef TF_ROUND
    o0 = x0; o1 = x1;
}

// ---- scatter edges (int64/int32 detected per block) -----------------------
__global__ void scatter_kernel(const int* __restrict__ ei, int E,
                               uint32_t* __restrict__ Abits) {
    __shared__ int cnt_oddnz;
    int t = threadIdx.x;
    if (t == 0) cnt_oddnz = 0;
    __syncthreads();
    if (((const uint32_t*)ei)[2 * t + 1] != 0u) atomicAdd(&cnt_oddnz, 1);
    __syncthreads();
    bool is64 = (cnt_oddnz <= 8);        // int64 => high words all zero
    int e = blockIdx.x * blockDim.x + t;
    if (e >= E) return;
    int src, dst;
    if (is64) { src = ei[2 * e]; dst = ei[2 * (E + e)]; }
    else      { src = ei[e];     dst = ei[E + e]; }
    src &= (N_NODES - 1);
    dst &= (N_NODES - 1);
    atomicOr(&Abits[src * WPR + (dst >> 5)], 1u << (dst & 31));
}

// ---- SpMM: hop1[i,:] = sum_{j in bits(i)} x[j,:] --------------------------
__global__ void spmm_kernel(const uint32_t* __restrict__ Abits,
                            const float* __restrict__ in,
                            float* __restrict__ out) {
    int i = blockIdx.x;
    int c = threadIdx.x;                 // 128
    __shared__ uint32_t wbits[WPR];
    wbits[c] = Abits[i * WPR + c];
    __syncthreads();
    float acc = 0.f;
    for (int w = 0; w < WPR; ++w) {
        uint32_t bits = wbits[w];
        while (bits) {
            int b = __ffs(bits) - 1;
            bits &= bits - 1;
            acc += in[(w * 32 + b) * C_DIM + c];
        }
    }
    out[i * C_DIM + c] = acc;
}

// ---- combo: spmm2+agg, norm->xnb, aggT bf16 store, threefry mask, degInt --
__global__ void spmm2_combo_kernel(const uint32_t* __restrict__ Abits,
                                   const float* __restrict__ hop1,
                                   const float* __restrict__ xf,
                                   const float* __restrict__ alpha,
                                   float* __restrict__ agg,
                                   uint16_t* __restrict__ aggTb,
                                   uint16_t* __restrict__ xnb,
                                   uint32_t* __restrict__ Mbits,
                                   int* __restrict__ degInt) {
    int i = blockIdx.x;
    int c = threadIdx.x;                 // 128
    __shared__ uint32_t wbits[WPR];
    __shared__ float ws[2];
    wbits[c] = Abits[i * WPR + c];
    __syncthreads();
    float acc = 0.f;
    for (int w = 0; w < WPR; ++w) {
        uint32_t bits = wbits[w];
        while (bits) {
            int b = __ffs(bits) - 1;
            bits &= bits - 1;
            acc += hop1[(w * 32 + b) * C_DIM + c];
        }
    }
    float xv  = xf[i * C_DIM + c];
    float h1v = hop1[i * C_DIM + c];
    float a = alpha[0] * xv + alpha[1] * h1v + alpha[2] * acc;
    agg[i * C_DIM + c] = a;
    aggTb[(size_t)c * N_NODES + i] = f2bf(a);   // transposed bf16 (scattered)

    // norm of row i -> xnb
    float sq = xv * xv;
    #pragma unroll
    for (int off = 32; off >= 1; off >>= 1) sq += __shfl_xor(sq, off);
    if ((c & 63) == 0) ws[c >> 6] = sq;
    __syncthreads();
    float tot = ws[0] + ws[1];
    xnb[i * C_DIM + c] = f2bf(xv / (sqrtf(tot) + 1e-8f));

    // threefry mask: job u covers half of word tid = u>>1
    uint32_t u = (uint32_t)(i * 128 + c);
    uint32_t tid = u >> 1;
    uint32_t halfb = u & 1u;
    uint32_t base = tid * 32u + halfb * 16u;
    uint32_t w0 = 0u, w1 = 0u;
    for (int k = 0; k < 16; ++k) {
        uint32_t o0, o1;
        threefry2x32(0u, 42u, base + k, HALF_P + base + k, o0, o1);
        w0 |= (uint32_t)((o0 >> 31) ^ 1u) << k;
        w1 |= (uint32_t)((o1 >> 31) ^ 1u) << k;
    }
    uint32_t w0o = (uint32_t)__shfl_xor((int)w0, 1);
    uint32_t w1o = (uint32_t)__shfl_xor((int)w1, 1);
    int p0 = 0, p1 = 0;
    if (halfb == 0u) {
        uint32_t W0 = w0 | (w0o << 16);
        uint32_t W1 = w1 | (w1o << 16);
        Mbits[tid] = W0;
        Mbits[(HALF_P >> 5) + tid] = W1;
        p0 = __popc(W0); p1 = __popc(W1);
    }
    #pragma unroll
    for (int off = 32; off >= 1; off >>= 1) {
        p0 += __shfl_xor(p0, off);
        p1 += __shfl_xor(p1, off);
    }
    if ((c & 63) == 0) {
        int row0 = i >> 1;               // wave-uniform
        atomicAdd(&degInt[row0], p0);
        atomicAdd(&degInt[2048 + row0], p1);
    }
}

// ---- topk via MFMA (R11, unchanged) ---------------------------------------
__launch_bounds__(512, 4)
__global__ void topk_kernel(const uint16_t* __restrict__ xnb,
                            float* __restrict__ topv,
                            int* __restrict__ topi) {
    int i0 = blockIdx.x * 16;
    int part = blockIdx.y;               // 0..3
    int t = threadIdx.x;
    int w = t >> 6;
    int lane = t & 63;
    int col = lane & 15;
    int quad = lane >> 4;

    __shared__ float    sval[32 * 16 * LSTR];
    __shared__ uint16_t sidx[32 * 16 * LSTR];

    bf16x8 bfi[4];
    #pragma unroll
    for (int s = 0; s < 4; ++s)
        bfi[s] = *(const bf16x8*)&xnb[(size_t)(i0 + col) * C_DIM + s * 32 + quad * 8];

    float tv[TOPK]; int ti[TOPK];
    #pragma unroll
    for (int k = 0; k < TOPK; ++k) { tv[k] = -1e30f; ti[k] = 0xFFFF; }

    int jt0 = part * 64 + w * 8;
    for (int p = 0; p < 8; ++p) {
        int j0 = (jt0 + p) * 16;
        f32x4 acc = {0.f, 0.f, 0.f, 0.f};
        #pragma unroll
        for (int s = 0; s < 4; ++s) {
            bf16x8 aj = *(const bf16x8*)&xnb[(size_t)(j0 + col) * C_DIM + s * 32 + quad * 8];
            acc = __builtin_amdgcn_mfma_f32_16x16x32_bf16(aj, bfi[s], acc, 0, 0, 0);
        }
        float m4 = fmaxf(fmaxf(acc[0], acc[1]), fmaxf(acc[2], acc[3]));
        if (m4 > tv[TOPK-1]) {
            #pragma unroll
            for (int r = 0; r < 4; ++r) {
                float d = acc[r];
                if (d > tv[TOPK-1]) {    // strict > keeps earliest j
                    int j = j0 + quad * 4 + r;
                    tv[TOPK-1] = d; ti[TOPK-1] = j;
                    #pragma unroll
                    for (int q = TOPK - 2; q >= 0; --q) {
                        if (tv[q+1] > tv[q]) {
                            float fv = tv[q]; tv[q] = tv[q+1]; tv[q+1] = fv;
                            int iv = ti[q];  ti[q] = ti[q+1];  ti[q+1] = iv;
                        }
                    }
                }
            }
        }
    }

    int base = ((w * 4 + quad) * 16 + col) * LSTR;
    #pragma unroll
    for (int k = 0; k < TOPK; ++k) {
        sval[base + k] = tv[k];
        sidx[base + k] = (uint16_t)ti[k];
    }

    int row = t & 15, L = t >> 4;
    for (int s = 16; s >= 1; s >>= 1) {
        __syncthreads();
        if (L < s) {
            int la = (L * 16 + row) * LSTR;
            int lb = ((L + s) * 16 + row) * LSTR;
            float ov[TOPK]; uint16_t oi[TOPK];
            int ia = 0, ib = 0;
            #pragma unroll
            for (int k = 0; k < TOPK; ++k) {
                float va = sval[la + ia], vb = sval[lb + ib];
                uint16_t xa = sidx[la + ia], xb = sidx[lb + ib];
                bool takeA = (va > vb) || (va == vb && xa < xb);
                if (takeA) { ov[k] = va; oi[k] = xa; ++ia; }
                else       { ov[k] = vb; oi[k] = xb; ++ib; }
            }
            #pragma unroll
            for (int k = 0; k < TOPK; ++k) { sval[la + k] = ov[k]; sidx[la + k] = oi[k]; }
        }
    }
    __syncthreads();
    if (t < 16) {
        size_t gi = (size_t)(part * N_NODES + i0 + t) * TOPK;
        #pragma unroll
        for (int k = 0; k < TOPK; ++k) {
            topv[gi + k] = sval[t * LSTR + k];
            topi[gi + k] = (int)sidx[t * LSTR + k];
        }
    }
}

// ---- fused: LDS-staged merge + masked-mean MFMA (K split x2) --------------
// grid (256, 2). Window = 2048 k (64 words/row). topv/topi staged by 64
// parallel threads; merge pure-LDS; deg via atomicAdd to degInt.
__launch_bounds__(512, 4)
__global__ void fused_kernel(const uint32_t* __restrict__ Mbits,
                             const uint16_t* __restrict__ aggTb,
                             const float* __restrict__ topv,
                             const int* __restrict__ topi,
                             int* __restrict__ degInt,
                             float* __restrict__ fpart) {
    int i0 = blockIdx.x * 16;
    int part = blockIdx.y;               // 0..1
    int t = threadIdx.x;
    int w = t >> 6;
    int lane = t & 63;
    int col = lane & 15;
    int quad = lane >> 4;

    __shared__ uint32_t smask[16][65];   // 64-word window + pad
    __shared__ float    lv[16][JSPLIT][TOPK];
    __shared__ uint16_t li[16][JSPLIT][TOPK];
    for (int r = t; r < 16 * 64; r += 512)
        smask[r >> 6][r & 63] =
            Mbits[(size_t)(i0 + (r >> 6)) * WPR + part * 64 + (r & 63)];
    if (t < 16 * JSPLIT) {               // 64 threads, independent loads
        int row = t & 15, q = t >> 4;
        size_t gi = (size_t)(q * N_NODES + i0 + row) * TOPK;
        #pragma unroll
        for (int k = 0; k < TOPK; ++k) {
            lv[row][q][k] = topv[gi + k];
            li[row][q][k] = (uint16_t)topi[gi + k];
        }
    }
    __syncthreads();

    if (t < 16) {                        // pure-LDS 4-way merge
        int ix[JSPLIT] = {0, 0, 0, 0};
        int newc = 0;
        int kw0 = part * 2048;
        #pragma unroll
        for (int k = 0; k < TOPK; ++k) {
            float bestv = -1e38f; int bestj = 0x7fffffff; int bestq = 0;
            #pragma unroll
            for (int q = 0; q < JSPLIT; ++q) {
                bool ok = ix[q] < TOPK;
                float fv = ok ? lv[t][q][ix[q]] : -1e38f;
                int   jj = ok ? (int)li[t][q][ix[q]] : 0x7fffffff;
                if (fv > bestv || (fv == bestv && jj < bestj)) {
                    bestv = fv; bestj = jj; bestq = q;
                }
            }
            ++ix[bestq];
            int rel = bestj - kw0;
            if (rel >= 0 && rel < 2048) {
                uint32_t* wp = &smask[t][rel >> 5];
                uint32_t old = *wp, bit = 1u << (bestj & 31);
                newc += (int)((old & bit) == 0u);
                *wp = old | bit;
            }
        }
        if (newc) atomicAdd(&degInt[i0 + t], newc);
    }
    __syncthreads();

    const uint16_t* brow = aggTb + (size_t)(w * 16 + col) * N_NODES;
    int kbase = part * 2048;
    f32x4 acc[4];
    #pragma unroll
    for (int u = 0; u < 4; ++u) acc[u] = (f32x4){0.f, 0.f, 0.f, 0.f};

    for (int k0 = 0; k0 < 2048; k0 += 128) {
        #pragma unroll
        for (int u = 0; u < 4; ++u) {
            uint32_t mw = smask[col][(k0 >> 5) + u];
            uint32_t byte = (mw >> (quad * 8)) & 0xFFu;
            union { uint32_t uu[4]; bf16x8 v; } a;
            #pragma unroll
            for (int pp = 0; pp < 4; ++pp) {
                uint32_t lo = (byte >> (2 * pp)) & 1u;
                uint32_t hi = (byte >> (2 * pp + 1)) & 1u;
                a.uu[pp] = (lo ? 0x3F80u : 0u) | (hi ? 0x3F800000u : 0u);
            }
            bf16x8 b = *(const bf16x8*)&brow[kbase + k0 + u * 32 + quad * 8];
            acc[u] = __builtin_amdgcn_mfma_f32_16x16x32_bf16(a.v, b, acc[u], 0, 0, 0);
        }
    }
    #pragma unroll
    for (int r = 0; r < 4; ++r) {
        int il = quad * 4 + r;
        float s = (acc[0][r] + acc[1][r]) + (acc[2][r] + acc[3][r]);
        fpart[(size_t)part * (N_NODES * C_DIM)
              + (size_t)(i0 + il) * C_DIM + w * 16 + col] = s;
    }
}

// ---- fused MLP: h=[x,fused]@fW+fB; h1=relu(h@l0W+l0B); out=lsm(h1@l1W+l1B)
__global__ void mlp_kernel(const float* __restrict__ xf,
                           const float* __restrict__ fpart,
                           const int* __restrict__ degInt,
                           const float* __restrict__ fW, const float* __restrict__ fB,
                           const float* __restrict__ l0W, const float* __restrict__ l0B,
                           const float* __restrict__ l1W, const float* __restrict__ l1B,
                           float* __restrict__ out) {
    int i0 = blockIdx.x * 4;
    int t = threadIdx.x;                 // 128
    __shared__ float lx[4][256];
    __shared__ float hb[4][128];
    const float* f0 = fpart;
    const float* f1 = fpart + (size_t)N_NODES * C_DIM;
    for (int r = t; r < 4 * 128; r += 128) {
        int row = r >> 7, c = r & 127;
        size_t idx = (size_t)(i0 + row) * C_DIM + c;
        lx[row][c] = xf[idx];
        lx[row][128 + c] = (f0[idx] + f1[idx])
                           / ((float)degInt[i0 + row] + 1e-6f);
    }
    __syncthreads();
    float acc[4];
    #pragma unroll
    for (int r = 0; r < 4; ++r) acc[r] = fB[t];
    for (int k = 0; k < 256; ++k) {
        float wv = fW[k * 128 + t];
        #pragma unroll
        for (int r = 0; r < 4; ++r) acc[r] = fmaf(lx[r][k], wv, acc[r]);
    }
    #pragma unroll
    for (int r = 0; r < 4; ++r) hb[r][t] = acc[r];
    __syncthreads();
    #pragma unroll
    for (int r = 0; r < 4; ++r) acc[r] = l0B[t];
    for (int k = 0; k < 128; ++k) {
        float wv = l0W[k * 128 + t];
        #pragma unroll
        for (int r = 0; r < 4; ++r) acc[r] = fmaf(hb[r][k], wv, acc[r]);
    }
    __syncthreads();
    #pragma unroll
    for (int r = 0; r < 4; ++r) lx[r][t] = fmaxf(acc[r], 0.f);   // h1
    __syncthreads();
    int o = t & 63, pr = t >> 6;
    #pragma unroll
    for (int rr = 0; rr < 2; ++rr) {
        int r = pr + 2 * rr;
        float a = l1B[o];
        for (int k = 0; k < 128; ++k)
            a = fmaf(lx[r][k], l1W[k * 64 + o], a);
        float m = a;
        #pragma unroll
        for (int off = 32; off >= 1; off >>= 1) m = fmaxf(m, __shfl_xor(m, off));
        float e = expf(a - m);
        float s = e;
        #pragma unroll
        for (int off = 32; off >= 1; off >>= 1) s += __shfl_xor(s, off);
        out[(size_t)(i0 + r) * 64 + o] = a - m - logf(s);
    }
}

extern "C" void kernel_launch(void* const* d_in, const int* in_sizes, int n_in,
                              void* d_out, int out_size, void* d_ws, size_t ws_size,
                              hipStream_t stream) {
    const float* xf    = (const float*)d_in[0];
    const int*   ei    = (const int*)d_in[1];
    const float* alpha = (const float*)d_in[2];
    const float* fW    = (const float*)d_in[3];
    const float* fB    = (const float*)d_in[4];
    const float* l0W   = (const float*)d_in[5];
    const float* l0B   = (const float*)d_in[6];
    const float* l1W   = (const float*)d_in[7];
    const float* l1B   = (const float*)d_in[8];
    float* out = (float*)d_out;
    const int E  = in_sizes[1] / 2;     // 65536
    const int NC = N_NODES * C_DIM;     // 524288

    char* p = (char*)d_ws;
    const size_t SZ = (size_t)NC * 4;   // 2 MB
    uint32_t* Abits  = (uint32_t*)p; p += SZ;
    int*      degInt = (int*)p;      p += N_NODES * 4;   // contiguous w/ Abits
    float*    hop1   = (float*)p;    p += SZ;
    float*    agg    = (float*)p;    p += SZ;
    uint32_t* Mbits  = (uint32_t*)p; p += SZ;
    float*    fpart  = (float*)p;    p += KSPLIT * SZ;   // two K-half partials
    uint16_t* xnb    = (uint16_t*)p; p += SZ / 2;
    uint16_t* aggTb  = (uint16_t*)p; p += SZ / 2;
    float*    topv   = (float*)p;    p += (size_t)JSPLIT * N_NODES * TOPK * 4;
    int*      topi   = (int*)p;      p += (size_t)JSPLIT * N_NODES * TOPK * 4;

    hipMemsetAsync(Abits, 0, SZ + N_NODES * 4, stream);  // Abits + degInt
    scatter_kernel<<<(E + 255) / 256, 256, 0, stream>>>(ei, E, Abits);
    spmm_kernel<<<N_NODES, 128, 0, stream>>>(Abits, xf, hop1);
    spmm2_combo_kernel<<<N_NODES, 128, 0, stream>>>(Abits, hop1, xf, alpha,
                                                    agg, aggTb, xnb, Mbits, degInt);
    topk_kernel<<<dim3(N_NODES / 16, JSPLIT), 512, 0, stream>>>(xnb, topv, topi);
    fused_kernel<<<dim3(N_NODES / 16, KSPLIT), 512, 0, stream>>>(Mbits, aggTb,
                                                                 topv, topi,
                                                                 degInt, fpart);
    mlp_kernel<<<N_NODES / 4, 128, 0, stream>>>(xf, fpart, degInt,
                                                fW, fB, l0W, l0B, l1W, l1B, out);
}

// Round 15
// 226.861 us; speedup vs baseline: 6.1074x; 1.0104x over previous
//
#include <hip/hip_runtime.h>
#include <hip/hip_bf16.h>
#include <stdint.h>

// ScaleGNN on MI355X (gfx950). fp32 in / fp32 out. edge_index int32/int64
// auto-detect (in scatter). Mask = JAX threefry2x32 key(42) bit-exact.
// R15: heterogeneous dispatch — topk (blocks 0..1023) and combo (1024..2047)
//      run in ONE launch (independent work; combo's latency stalls hide under
//      topk's VALU). norm moved into spmm so xnb is ready one step earlier.
//      6 dispatches: memset, scatter, spmm+norm, [topk|combo], fused, mlp.

#define N_NODES 4096
#define C_DIM   128
#define WPR     128        // bitmask words per row (4096/32)
#define HALF_P  8388608u   // N*N/2
#define TOPK    10
#define LSTR    13         // topk list stride; (16L+13c) mod 32 covers banks
#define JSPLIT  4          // topk j-split
#define KSPLIT  2          // fused K-split

typedef __attribute__((ext_vector_type(8))) short bf16x8;   // 8 bf16 = 4 VGPRs
typedef __attribute__((ext_vector_type(4))) float f32x4;    // MFMA C/D

__device__ __forceinline__ uint16_t f2bf(float f) {         // RNE fp32->bf16
    uint32_t u = __float_as_uint(f);
    return (uint16_t)((u + 0x7FFFu + ((u >> 16) & 1u)) >> 16);
}

__device__ __forceinline__ uint32_t rotl32(uint32_t v, int r) {
    return (v << r) | (v >> (32 - r));
}

__device__ __forceinline__ void threefry2x32(uint32_t k0, uint32_t k1,
                                             uint32_t x0, uint32_t x1,
                                             uint32_t& o0, uint32_t& o1) {
    uint32_t ks2 = k0 ^ k1 ^ 0x1BD11BDAu;
    x0 += k0; x1 += k1;
#define TF_ROUND(r) { x0 += x1; x1 = rotl32(x1, (r)); x1 ^= x0; }
    TF_ROUND(13) TF_ROUND(15) TF_ROUND(26) TF_ROUND(6)
    x0 += k1;  x1 += ks2 + 1u;
    TF_ROUND(17) TF_ROUND(29) TF_ROUND(16) TF_ROUND(24)
    x0 += ks2; x1 += k0 + 2u;
    TF_ROUND(13) TF_ROUND(15) TF_ROUND(26) TF_ROUND(6)
    x0 += k0;  x1 += k1 + 3u;
    TF_ROUND(17) TF_ROUND(29) TF_ROUND(16) TF_ROUND(24)
    x0 += k1;  x1 += ks2 + 4u;
    TF_ROUND(13) TF_ROUND(15) TF_ROUND(26) TF_ROUND(6)
    x0 += ks2; x1 += k0 + 5u;
#undef TF_ROUND
    o0 = x0; o1 = x1;
}

// ---- scatter edges (int64/int32 detected per block) -----------------------
__global__ void scatter_kernel(const int* __restrict__ ei, int E,
                               uint32_t* __restrict__ Abits) {
    __shared__ int cnt_oddnz;
    int t = threadIdx.x;
    if (t == 0) cnt_oddnz = 0;
    __syncthreads();
    if (((const uint32_t*)ei)[2 * t + 1] != 0u) atomicAdd(&cnt_oddnz, 1);
    __syncthreads();
    bool is64 = (cnt_oddnz <= 8);        // int64 => high words all zero
    int e = blockIdx.x * blockDim.x + t;
    if (e >= E) return;
    int src, dst;
    if (is64) { src = ei[2 * e]; dst = ei[2 * (E + e)]; }
    else      { src = ei[e];     dst = ei[E + e]; }
    src &= (N_NODES - 1);
    dst &= (N_NODES - 1);
    atomicOr(&Abits[src * WPR + (dst >> 5)], 1u << (dst & 31));
}

// ---- SpMM + norm: hop1 = A@x; xnb = bf16(x/(||x||+1e-8)) ------------------
__global__ void spmm_norm_kernel(const uint32_t* __restrict__ Abits,
                                 const float* __restrict__ xf,
                                 float* __restrict__ hop1,
                                 uint16_t* __restrict__ xnb) {
    int i = blockIdx.x;
    int c = threadIdx.x;                 // 128
    __shared__ uint32_t wbits[WPR];
    __shared__ float ws[2];
    wbits[c] = Abits[i * WPR + c];
    __syncthreads();
    float acc = 0.f;
    for (int w = 0; w < WPR; ++w) {
        uint32_t bits = wbits[w];
        while (bits) {
            int b = __ffs(bits) - 1;
            bits &= bits - 1;
            acc += xf[(w * 32 + b) * C_DIM + c];
        }
    }
    hop1[i * C_DIM + c] = acc;
    // norm of row i
    float v = xf[i * C_DIM + c];
    float sq = v * v;
    #pragma unroll
    for (int off = 32; off >= 1; off >>= 1) sq += __shfl_xor(sq, off);
    if ((c & 63) == 0) ws[c >> 6] = sq;
    __syncthreads();
    float tot = ws[0] + ws[1];
    xnb[i * C_DIM + c] = f2bf(v / (sqrtf(tot) + 1e-8f));
}

// ---- heterogeneous: blocks 0..1023 = topk; 1024..2047 = combo -------------
// topk: sim = xn@xn^T via MFMA, register scan, 4-way j-split (R11 verified).
// combo: spmm2+agg + aggT bf16 + threefry mask + degInt (4 rows / 512 thr).
__launch_bounds__(512, 4)
__global__ void combo_topk_kernel(const uint32_t* __restrict__ Abits,
                                  const float* __restrict__ hop1,
                                  const float* __restrict__ xf,
                                  const float* __restrict__ alpha,
                                  float* __restrict__ agg,
                                  uint16_t* __restrict__ aggTb,
                                  const uint16_t* __restrict__ xnb,
                                  uint32_t* __restrict__ Mbits,
                                  int* __restrict__ degInt,
                                  float* __restrict__ topv,
                                  int* __restrict__ topi) {
    __shared__ uint8_t smem[32 * 16 * LSTR * 6];   // 39936 B overlay
    int t = threadIdx.x;

    if (blockIdx.x < 1024) {
        // ================= topk =================
        float*    sval = (float*)smem;                      // 26624 B
        uint16_t* sidx = (uint16_t*)(smem + 32 * 16 * LSTR * 4);
        int it   = blockIdx.x & 255;
        int part = blockIdx.x >> 8;      // 0..3
        int i0 = it * 16;
        int w = t >> 6;
        int lane = t & 63;
        int col = lane & 15;
        int quad = lane >> 4;

        bf16x8 bfi[4];
        #pragma unroll
        for (int s = 0; s < 4; ++s)
            bfi[s] = *(const bf16x8*)&xnb[(size_t)(i0 + col) * C_DIM + s * 32 + quad * 8];

        float tv[TOPK]; int ti[TOPK];
        #pragma unroll
        for (int k = 0; k < TOPK; ++k) { tv[k] = -1e30f; ti[k] = 0xFFFF; }

        int jt0 = part * 64 + w * 8;
        for (int p = 0; p < 8; ++p) {
            int j0 = (jt0 + p) * 16;
            f32x4 acc = {0.f, 0.f, 0.f, 0.f};
            #pragma unroll
            for (int s = 0; s < 4; ++s) {
                bf16x8 aj = *(const bf16x8*)&xnb[(size_t)(j0 + col) * C_DIM + s * 32 + quad * 8];
                acc = __builtin_amdgcn_mfma_f32_16x16x32_bf16(aj, bfi[s], acc, 0, 0, 0);
            }
            float m4 = fmaxf(fmaxf(acc[0], acc[1]), fmaxf(acc[2], acc[3]));
            if (m4 > tv[TOPK-1]) {
                #pragma unroll
                for (int r = 0; r < 4; ++r) {
                    float d = acc[r];
                    if (d > tv[TOPK-1]) {    // strict > keeps earliest j
                        int j = j0 + quad * 4 + r;
                        tv[TOPK-1] = d; ti[TOPK-1] = j;
                        #pragma unroll
                        for (int q = TOPK - 2; q >= 0; --q) {
                            if (tv[q+1] > tv[q]) {
                                float fv = tv[q]; tv[q] = tv[q+1]; tv[q+1] = fv;
                                int iv = ti[q];  ti[q] = ti[q+1];  ti[q+1] = iv;
                            }
                        }
                    }
                }
            }
        }

        int base = ((w * 4 + quad) * 16 + col) * LSTR;
        #pragma unroll
        for (int k = 0; k < TOPK; ++k) {
            sval[base + k] = tv[k];
            sidx[base + k] = (uint16_t)ti[k];
        }

        int row = t & 15, L = t >> 4;
        for (int s = 16; s >= 1; s >>= 1) {
            __syncthreads();
            if (L < s) {
                int la = (L * 16 + row) * LSTR;
                int lb = ((L + s) * 16 + row) * LSTR;
                float ov[TOPK]; uint16_t oi[TOPK];
                int ia = 0, ib = 0;
                #pragma unroll
                for (int k = 0; k < TOPK; ++k) {
                    float va = sval[la + ia], vb = sval[lb + ib];
                    uint16_t xa = sidx[la + ia], xb = sidx[lb + ib];
                    bool takeA = (va > vb) || (va == vb && xa < xb);
                    if (takeA) { ov[k] = va; oi[k] = xa; ++ia; }
                    else       { ov[k] = vb; oi[k] = xb; ++ib; }
                }
                #pragma unroll
                for (int k = 0; k < TOPK; ++k) { sval[la + k] = ov[k]; sidx[la + k] = oi[k]; }
            }
        }
        __syncthreads();
        if (t < 16) {
            size_t gi = (size_t)(part * N_NODES + i0 + t) * TOPK;
            #pragma unroll
            for (int k = 0; k < TOPK; ++k) {
                topv[gi + k] = sval[t * LSTR + k];
                topi[gi + k] = (int)sidx[t * LSTR + k];
            }
        }
    } else {
        // ================= combo (4 rows per block) =================
        uint32_t* wb = (uint32_t*)smem;  // [4][128] = 2048 B
        int bid = blockIdx.x - 1024;
        int sg = t >> 7;                 // 0..3
        int c  = t & 127;
        int i  = bid * 4 + sg;
        wb[sg * 128 + c] = Abits[i * WPR + c];
        __syncthreads();
        float acc = 0.f;
        for (int w = 0; w < WPR; ++w) {
            uint32_t bits = wb[sg * 128 + w];
            while (bits) {
                int b = __ffs(bits) - 1;
                bits &= bits - 1;
                acc += hop1[(w * 32 + b) * C_DIM + c];
            }
        }
        float xv  = xf[i * C_DIM + c];
        float h1v = hop1[i * C_DIM + c];
        float a = alpha[0] * xv + alpha[1] * h1v + alpha[2] * acc;
        agg[i * C_DIM + c] = a;
        aggTb[(size_t)c * N_NODES + i] = f2bf(a);

        // threefry mask: job u = i*128 + c (bit-exact original mapping)
        uint32_t u = (uint32_t)(i * 128 + c);
        uint32_t tid = u >> 1;
        uint32_t halfb = u & 1u;
        uint32_t base = tid * 32u + halfb * 16u;
        uint32_t w0 = 0u, w1 = 0u;
        for (int k = 0; k < 16; ++k) {
            uint32_t o0, o1;
            threefry2x32(0u, 42u, base + k, HALF_P + base + k, o0, o1);
            w0 |= (uint32_t)((o0 >> 31) ^ 1u) << k;
            w1 |= (uint32_t)((o1 >> 31) ^ 1u) << k;
        }
        uint32_t w0o = (uint32_t)__shfl_xor((int)w0, 1);
        uint32_t w1o = (uint32_t)__shfl_xor((int)w1, 1);
        int p0 = 0, p1 = 0;
        if (halfb == 0u) {
            uint32_t W0 = w0 | (w0o << 16);
            uint32_t W1 = w1 | (w1o << 16);
            Mbits[tid] = W0;
            Mbits[(HALF_P >> 5) + tid] = W1;
            p0 = __popc(W0); p1 = __popc(W1);
        }
        #pragma unroll
        for (int off = 32; off >= 1; off >>= 1) {
            p0 += __shfl_xor(p0, off);
            p1 += __shfl_xor(p1, off);
        }
        if ((t & 63) == 0) {
            int row0 = i >> 1;           // wave-uniform
            atomicAdd(&degInt[row0], p0);
            atomicAdd(&degInt[2048 + row0], p1);
        }
    }
}

// ---- fused: LDS-staged merge + masked-mean MFMA (K split x2) --------------
__launch_bounds__(512, 4)
__global__ void fused_kernel(const uint32_t* __restrict__ Mbits,
                             const uint16_t* __restrict__ aggTb,
                             const float* __restrict__ topv,
                             const int* __restrict__ topi,
                             int* __restrict__ degInt,
                             float* __restrict__ fpart) {
    int i0 = blockIdx.x * 16;
    int part = blockIdx.y;               // 0..1
    int t = threadIdx.x;
    int w = t >> 6;
    int lane = t & 63;
    int col = lane & 15;
    int quad = lane >> 4;

    __shared__ uint32_t smask[16][65];   // 64-word window + pad
    __shared__ float    lv[16][JSPLIT][TOPK];
    __shared__ uint16_t li[16][JSPLIT][TOPK];
    for (int r = t; r < 16 * 64; r += 512)
        smask[r >> 6][r & 63] =
            Mbits[(size_t)(i0 + (r >> 6)) * WPR + part * 64 + (r & 63)];
    if (t < 16 * JSPLIT) {               // 64 threads, independent loads
        int row = t & 15, q = t >> 4;
        size_t gi = (size_t)(q * N_NODES + i0 + row) * TOPK;
        #pragma unroll
        for (int k = 0; k < TOPK; ++k) {
            lv[row][q][k] = topv[gi + k];
            li[row][q][k] = (uint16_t)topi[gi + k];
        }
    }
    __syncthreads();

    if (t < 16) {                        // pure-LDS 4-way merge
        int ix[JSPLIT] = {0, 0, 0, 0};
        int newc = 0;
        int kw0 = part * 2048;
        #pragma unroll
        for (int k = 0; k < TOPK; ++k) {
            float bestv = -1e38f; int bestj = 0x7fffffff; int bestq = 0;
            #pragma unroll
            for (int q = 0; q < JSPLIT; ++q) {
                bool ok = ix[q] < TOPK;
                float fv = ok ? lv[t][q][ix[q]] : -1e38f;
                int   jj = ok ? (int)li[t][q][ix[q]] : 0x7fffffff;
                if (fv > bestv || (fv == bestv && jj < bestj)) {
                    bestv = fv; bestj = jj; bestq = q;
                }
            }
            ++ix[bestq];
            int rel = bestj - kw0;
            if (rel >= 0 && rel < 2048) {
                uint32_t* wp = &smask[t][rel >> 5];
                uint32_t old = *wp, bit = 1u << (bestj & 31);
                newc += (int)((old & bit) == 0u);
                *wp = old | bit;
            }
        }
        if (newc) atomicAdd(&degInt[i0 + t], newc);
    }
    __syncthreads();

    const uint16_t* brow = aggTb + (size_t)(w * 16 + col) * N_NODES;
    int kbase = part * 2048;
    f32x4 acc[4];
    #pragma unroll
    for (int u = 0; u < 4; ++u) acc[u] = (f32x4){0.f, 0.f, 0.f, 0.f};

    for (int k0 = 0; k0 < 2048; k0 += 128) {
        #pragma unroll
        for (int u = 0; u < 4; ++u) {
            uint32_t mw = smask[col][(k0 >> 5) + u];
            uint32_t byte = (mw >> (quad * 8)) & 0xFFu;
            union { uint32_t uu[4]; bf16x8 v; } a;
            #pragma unroll
            for (int pp = 0; pp < 4; ++pp) {
                uint32_t lo = (byte >> (2 * pp)) & 1u;
                uint32_t hi = (byte >> (2 * pp + 1)) & 1u;
                a.uu[pp] = (lo ? 0x3F80u : 0u) | (hi ? 0x3F800000u : 0u);
            }
            bf16x8 b = *(const bf16x8*)&brow[kbase + k0 + u * 32 + quad * 8];
            acc[u] = __builtin_amdgcn_mfma_f32_16x16x32_bf16(a.v, b, acc[u], 0, 0, 0);
        }
    }
    #pragma unroll
    for (int r = 0; r < 4; ++r) {
        int il = quad * 4 + r;
        float s = (acc[0][r] + acc[1][r]) + (acc[2][r] + acc[3][r]);
        fpart[(size_t)part * (N_NODES * C_DIM)
              + (size_t)(i0 + il) * C_DIM + w * 16 + col] = s;
    }
}

// ---- fused MLP: h=[x,fused]@fW+fB; h1=relu(h@l0W+l0B); out=lsm(h1@l1W+l1B)
__global__ void mlp_kernel(const float* __restrict__ xf,
                           const float* __restrict__ fpart,
                           const int* __restrict__ degInt,
                           const float* __restrict__ fW, const float* __restrict__ fB,
                           const float* __restrict__ l0W, const float* __restrict__ l0B,
                           const float* __restrict__ l1W, const float* __restrict__ l1B,
                           float* __restrict__ out) {
    int i0 = blockIdx.x * 4;
    int t = threadIdx.x;                 // 128
    __shared__ float lx[4][256];
    __shared__ float hb[4][128];
    const float* f0 = fpart;
    const float* f1 = fpart + (size_t)N_NODES * C_DIM;
    for (int r = t; r < 4 * 128; r += 128) {
        int row = r >> 7, c = r & 127;
        size_t idx = (size_t)(i0 + row) * C_DIM + c;
        lx[row][c] = xf[idx];
        lx[row][128 + c] = (f0[idx] + f1[idx])
                           / ((float)degInt[i0 + row] + 1e-6f);
    }
    __syncthreads();
    float acc[4];
    #pragma unroll
    for (int r = 0; r < 4; ++r) acc[r] = fB[t];
    for (int k = 0; k < 256; ++k) {
        float wv = fW[k * 128 + t];
        #pragma unroll
        for (int r = 0; r < 4; ++r) acc[r] = fmaf(lx[r][k], wv, acc[r]);
    }
    #pragma unroll
    for (int r = 0; r < 4; ++r) hb[r][t] = acc[r];
    __syncthreads();
    #pragma unroll
    for (int r = 0; r < 4; ++r) acc[r] = l0B[t];
    for (int k = 0; k < 128; ++k) {
        float wv = l0W[k * 128 + t];
        #pragma unroll
        for (int r = 0; r < 4; ++r) acc[r] = fmaf(hb[r][k], wv, acc[r]);
    }
    __syncthreads();
    #pragma unroll
    for (int r = 0; r < 4; ++r) lx[r][t] = fmaxf(acc[r], 0.f);   // h1
    __syncthreads();
    int o = t & 63, pr = t >> 6;
    #pragma unroll
    for (int rr = 0; rr < 2; ++rr) {
        int r = pr + 2 * rr;
        float a = l1B[o];
        for (int k = 0; k < 128; ++k)
            a = fmaf(lx[r][k], l1W[k * 64 + o], a);
        float m = a;
        #pragma unroll
        for (int off = 32; off >= 1; off >>= 1) m = fmaxf(m, __shfl_xor(m, off));
        float e = expf(a - m);
        float s = e;
        #pragma unroll
        for (int off = 32; off >= 1; off >>= 1) s += __shfl_xor(s, off);
        out[(size_t)(i0 + r) * 64 + o] = a - m - logf(s);
    }
}

extern "C" void kernel_launch(void* const* d_in, const int* in_sizes, int n_in,
                              void* d_out, int out_size, void* d_ws, size_t ws_size,
                              hipStream_t stream) {
    const float* xf    = (const float*)d_in[0];
    const int*   ei    = (const int*)d_in[1];
    const float* alpha = (const float*)d_in[2];
    const float* fW    = (const float*)d_in[3];
    const float* fB    = (const float*)d_in[4];
    const float* l0W   = (const float*)d_in[5];
    const float* l0B   = (const float*)d_in[6];
    const float* l1W   = (const float*)d_in[7];
    const float* l1B   = (const float*)d_in[8];
    float* out = (float*)d_out;
    const int E  = in_sizes[1] / 2;     // 65536
    const int NC = N_NODES * C_DIM;     // 524288

    char* p = (char*)d_ws;
    const size_t SZ = (size_t)NC * 4;   // 2 MB
    uint32_t* Abits  = (uint32_t*)p; p += SZ;
    int*      degInt = (int*)p;      p += N_NODES * 4;   // contiguous w/ Abits
    float*    hop1   = (float*)p;    p += SZ;
    float*    agg    = (float*)p;    p += SZ;
    uint32_t* Mbits  = (uint32_t*)p; p += SZ;
    float*    fpart  = (float*)p;    p += KSPLIT * SZ;   // two K-half partials
    uint16_t* xnb    = (uint16_t*)p; p += SZ / 2;
    uint16_t* aggTb  = (uint16_t*)p; p += SZ / 2;
    float*    topv   = (float*)p;    p += (size_t)JSPLIT * N_NODES * TOPK * 4;
    int*      topi   = (int*)p;      p += (size_t)JSPLIT * N_NODES * TOPK * 4;

    hipMemsetAsync(Abits, 0, SZ + N_NODES * 4, stream);  // Abits + degInt
    scatter_kernel<<<(E + 255) / 256, 256, 0, stream>>>(ei, E, Abits);
    spmm_norm_kernel<<<N_NODES, 128, 0, stream>>>(Abits, xf, hop1, xnb);
    combo_topk_kernel<<<2048, 512, 0, stream>>>(Abits, hop1, xf, alpha,
                                                agg, aggTb, xnb, Mbits, degInt,
                                                topv, topi);
    fused_kernel<<<dim3(N_NODES / 16, KSPLIT), 512, 0, stream>>>(Mbits, aggTb,
                                                                 topv, topi,
                                                                 degInt, fpart);
    mlp_kernel<<<N_NODES / 4, 128, 0, stream>>>(xf, fpart, degInt,
                                                fW, fB, l0W, l0B, l1W, l1B, out);
}